// Round 1
// baseline (6884.915 us; speedup 1.0000x reference)
//
#include <hip/hip_runtime.h>
#include <hip/hip_bf16.h>

// TransMIL forward. All fp32 this round (correctness baseline).
// Dims: N_PATCH=16384, SIZE=1024, DIM=512, HEADS=8, DH=64, LANDMARKS=256,
// tokens NT=16385 (cls+16384), padded NP=16640 (front pad 255), l=65.

#define NT 16385
#define NP 16640
#define PADR 255
#define DIMF 512
#define QKVW 1536
#define NHEAD 8
#define DH 64
#define NLM 256
#define LSEG 65
#define A3V_TC 10   // t-chunks for flash split (260 tiles / 10 = 26 each)

// ---------------- generic tiled fp32 GEMM: C = beta*C + A@B + bias, opt relu
__global__ __launch_bounds__(256) void gemm_k(
    const float* __restrict__ A, const float* __restrict__ B,
    const float* __restrict__ bias, float* __restrict__ C,
    int M, int N, int K, int lda, int ldb, int ldc, float beta, int relu)
{
    __shared__ float As[16][65];
    __shared__ float Bs[16][64];
    int tx = threadIdx.x & 15, ty = threadIdx.x >> 4;
    int m0 = blockIdx.y << 6, n0 = blockIdx.x << 6;
    int la_k = tx, la_m = ty;                 // A: k fastest for coalescing
    int lb_n = threadIdx.x & 63, lb_k = threadIdx.x >> 6;
    float acc[4][4] = {};
    for (int kt = 0; kt < K; kt += 16) {
#pragma unroll
        for (int i = 0; i < 4; ++i) {
            int gm = m0 + la_m + 16 * i;
            float v = (gm < M) ? A[(size_t)gm * lda + kt + la_k] : 0.f;
            As[la_k][la_m + 16 * i] = v;
        }
#pragma unroll
        for (int i = 0; i < 4; ++i)
            Bs[lb_k + 4 * i][lb_n] = B[(size_t)(kt + lb_k + 4 * i) * ldb + n0 + lb_n];
        __syncthreads();
#pragma unroll
        for (int kk = 0; kk < 16; ++kk) {
            float a_[4], b_[4];
#pragma unroll
            for (int i = 0; i < 4; ++i) a_[i] = As[kk][ty * 4 + i];
#pragma unroll
            for (int j = 0; j < 4; ++j) b_[j] = Bs[kk][tx * 4 + j];
#pragma unroll
            for (int i = 0; i < 4; ++i)
#pragma unroll
                for (int j = 0; j < 4; ++j) acc[i][j] += a_[i] * b_[j];
        }
        __syncthreads();
    }
#pragma unroll
    for (int i = 0; i < 4; ++i) {
        int gm = m0 + ty * 4 + i;
        if (gm >= M) continue;
#pragma unroll
        for (int j = 0; j < 4; ++j) {
            int gn = n0 + tx * 4 + j;
            float c = acc[i][j];
            if (bias) c += bias[gn];
            if (beta != 0.f) c += beta * C[(size_t)gm * ldc + gn];
            if (relu) c = fmaxf(c, 0.f);
            C[(size_t)gm * ldc + gn] = c;
        }
    }
}

// ---------------- batched per-head 256xK GEMM: D = alpha*(A@B) + delta*I
__global__ __launch_bounds__(256) void mm256_k(
    const float* __restrict__ A, const float* __restrict__ B, float* __restrict__ D,
    int N, float alpha, float delta)
{
    __shared__ float As[16][65];
    __shared__ float Bs[16][64];
    int h = blockIdx.z;
    const float* Ah = A + ((size_t)h << 16);
    const float* Bh = B + (size_t)h * 256 * N;
    float* Dh = D + (size_t)h * 256 * N;
    int tx = threadIdx.x & 15, ty = threadIdx.x >> 4;
    int m0 = blockIdx.y << 6, n0 = blockIdx.x << 6;
    int lb_n = threadIdx.x & 63, lb_k = threadIdx.x >> 6;
    float acc[4][4] = {};
    for (int kt = 0; kt < 256; kt += 16) {
#pragma unroll
        for (int i = 0; i < 4; ++i)
            As[tx][ty + 16 * i] = Ah[(size_t)(m0 + ty + 16 * i) * 256 + kt + tx];
#pragma unroll
        for (int i = 0; i < 4; ++i)
            Bs[lb_k + 4 * i][lb_n] = Bh[(size_t)(kt + lb_k + 4 * i) * N + n0 + lb_n];
        __syncthreads();
#pragma unroll
        for (int kk = 0; kk < 16; ++kk) {
            float a_[4], b_[4];
#pragma unroll
            for (int i = 0; i < 4; ++i) a_[i] = As[kk][ty * 4 + i];
#pragma unroll
            for (int j = 0; j < 4; ++j) b_[j] = Bs[kk][tx * 4 + j];
#pragma unroll
            for (int i = 0; i < 4; ++i)
#pragma unroll
                for (int j = 0; j < 4; ++j) acc[i][j] += a_[i] * b_[j];
        }
        __syncthreads();
    }
#pragma unroll
    for (int i = 0; i < 4; ++i)
#pragma unroll
        for (int j = 0; j < 4; ++j) {
            int gr = m0 + ty * 4 + i, gc = n0 + tx * 4 + j;
            float cv = alpha * acc[i][j];
            if (gr == gc) cv += delta;
            Dh[(size_t)gr * N + gc] = cv;
        }
}

// ---------------- LayerNorm per row (512), one wave per row
__global__ __launch_bounds__(64) void ln_k(const float* __restrict__ in,
    const float* __restrict__ g, const float* __restrict__ b,
    float* __restrict__ out, int rows)
{
    int r = blockIdx.x;
    if (r >= rows) return;
    int lane = threadIdx.x;
    const float* xr = in + (size_t)r * DIMF;
    float v[8], s = 0.f;
#pragma unroll
    for (int i = 0; i < 8; ++i) { v[i] = xr[i * 64 + lane]; s += v[i]; }
#pragma unroll
    for (int off = 32; off; off >>= 1) s += __shfl_xor(s, off);
    float mu = s * (1.f / 512.f);
    float vs = 0.f;
#pragma unroll
    for (int i = 0; i < 8; ++i) { float d = v[i] - mu; vs += d * d; }
#pragma unroll
    for (int off = 32; off; off >>= 1) vs += __shfl_xor(vs, off);
    float rstd = rsqrtf(vs * (1.f / 512.f) + 1e-5f);
    float* orow = out + (size_t)r * DIMF;
#pragma unroll
    for (int i = 0; i < 8; ++i) {
        int d = i * 64 + lane;
        orow[d] = (v[i] - mu) * rstd * g[d] + b[d];
    }
}

// ---------------- scale q part of qkv by DH^-0.5
__global__ void scaleq_k(float* __restrict__ qkvb)
{
    int i = blockIdx.x * 256 + threadIdx.x;
    if (i >= NP * DIMF) return;
    int t = i >> 9, c = i & 511;
    qkvb[(size_t)t * QKVW + c] *= 0.125f;
}

// ---------------- landmark means (q_l from scaled q, k_l from k)
__global__ __launch_bounds__(64) void landmark_k(const float* __restrict__ qkvb,
    float* __restrict__ ql, float* __restrict__ kl)
{
    int bx = blockIdx.x;            // h*256 + j
    int h = bx >> 8, j = bx & 255;
    int d = threadIdx.x;
    float qs = 0.f, ks = 0.f;
    for (int u = 0; u < LSEG; ++u) {
        size_t addr = (size_t)(j * LSEG + u) * QKVW + (h << 6) + d;
        qs += qkvb[addr];
        ks += qkvb[addr + 512];
    }
    ql[(size_t)bx * 64 + d] = qs * (1.f / 65.f);
    kl[(size_t)bx * 64 + d] = ks * (1.f / 65.f);
}

// ---------------- a2 = softmax(q_l @ k_l^T) rows; block per (h,i)
__global__ __launch_bounds__(256) void a2_k(const float* __restrict__ ql,
    const float* __restrict__ kl, float* __restrict__ a2)
{
    int h = blockIdx.x >> 8, i = blockIdx.x & 255;
    int j = threadIdx.x;
    __shared__ float qs[64];
    __shared__ float red[256];
    if (j < 64) qs[j] = ql[((size_t)(h << 8) + i) * 64 + j];
    __syncthreads();
    const float* kr = kl + ((size_t)(h << 8) + j) * 64;
    float s = 0.f;
#pragma unroll 8
    for (int d = 0; d < 64; ++d) s += qs[d] * kr[d];
    red[j] = s; __syncthreads();
    for (int st = 128; st; st >>= 1) { if (j < st) red[j] = fmaxf(red[j], red[j + st]); __syncthreads(); }
    float mx = red[0]; __syncthreads();
    float p = __expf(s - mx);
    red[j] = p; __syncthreads();
    for (int st = 128; st; st >>= 1) { if (j < st) red[j] += red[j + st]; __syncthreads(); }
    a2[((size_t)h << 16) + i * 256 + j] = p / red[0];
}

// ---------------- pinv init: z = a2^T / (max_rowsum * max_colsum), per head
__global__ __launch_bounds__(256) void zinit_k(const float* __restrict__ a2, float* __restrict__ z)
{
    int h = blockIdx.x, t = threadIdx.x;
    const float* X = a2 + ((size_t)h << 16);
    __shared__ float red[256];
    float rs = 0.f;
    for (int j = 0; j < 256; ++j) rs += fabsf(X[t * 256 + j]);
    red[t] = rs; __syncthreads();
    for (int st = 128; st; st >>= 1) { if (t < st) red[t] = fmaxf(red[t], red[t + st]); __syncthreads(); }
    float colv = red[0]; __syncthreads();
    float cs = 0.f;
    for (int i = 0; i < 256; ++i) cs += fabsf(X[i * 256 + t]);
    red[t] = cs; __syncthreads();
    for (int st = 128; st; st >>= 1) { if (t < st) red[t] = fmaxf(red[t], red[t + st]); __syncthreads(); }
    float rowv = red[0];
    float inv = 1.f / (colv * rowv);
    for (int e = t; e < 65536; e += 256) {
        int i = e >> 8, j = e & 255;
        z[((size_t)h << 16) + e] = X[j * 256 + i] * inv;
    }
}

// ---------------- elementwise T = alpha*A + delta*I (8 heads of 256x256)
__global__ void ewi_k(const float* __restrict__ A, float* __restrict__ T, float alpha, float delta)
{
    int e = blockIdx.x * 256 + threadIdx.x;
    if (e >= 8 * 65536) return;
    int ij = e & 65535;
    T[e] = alpha * A[e] + (((ij >> 8) == (ij & 255)) ? delta : 0.f);
}

// ---------------- flash-style a3v partials: per (h, 32-landmark block, t-chunk)
__global__ __launch_bounds__(256) void a3v_part_k(
    const float* __restrict__ ql, const float* __restrict__ qkvb,
    float* __restrict__ opart, float* __restrict__ mpart, float* __restrict__ lpart)
{
    int pb = blockIdx.x;            // h*8+ib
    int h = pb >> 3, ib = pb & 7;
    int tc = blockIdx.y;
    __shared__ __align__(16) float qc[32][66];
    __shared__ __align__(16) float ktT[64][68];   // [d][tt]
    __shared__ __align__(16) float vt[64][68];    // [tt][d]
    __shared__ float sb[32][65];
    __shared__ float pm[32][8];
    __shared__ float mrow[32], lrow[32], fac[32];
    int tid = threadIdx.x;
    for (int e = tid; e < 2048; e += 256) {
        int r = e >> 6, d = e & 63;
        qc[r][d] = ql[((size_t)(h << 8) + (ib << 5) + r) * 64 + d];
    }
    if (tid < 32) { mrow[tid] = -3e38f; lrow[tid] = 0.f; }
    int tx = tid & 15, ty = tid >> 4;
    int m0 = ty * 2, n0 = tx * 4;
    float oa0[4] = {}, oa1[4] = {};
    __syncthreads();
    for (int tile = tc * 26; tile < tc * 26 + 26; ++tile) {
        int t0 = tile * 64;
        for (int e = tid; e < 4096; e += 256) {
            int tt = e >> 6, d = e & 63;
            size_t ga = (size_t)(t0 + tt) * QKVW + 512 + (h << 6) + d;
            ktT[d][tt] = qkvb[ga];          // k
            vt[tt][d] = qkvb[ga + 512];     // v
        }
        __syncthreads();
        // scores: sb[m][n] = sum_d qc[m][d]*ktT[d][n]
        {
            float c0[4] = {}, c1[4] = {};
#pragma unroll 16
            for (int kk = 0; kk < 64; ++kk) {
                float a0 = qc[m0][kk], a1 = qc[m0 + 1][kk];
                float4 b4 = *(const float4*)&ktT[kk][n0];
                c0[0] += a0 * b4.x; c0[1] += a0 * b4.y; c0[2] += a0 * b4.z; c0[3] += a0 * b4.w;
                c1[0] += a1 * b4.x; c1[1] += a1 * b4.y; c1[2] += a1 * b4.z; c1[3] += a1 * b4.w;
            }
#pragma unroll
            for (int j = 0; j < 4; ++j) { sb[m0][n0 + j] = c0[j]; sb[m0 + 1][n0 + j] = c1[j]; }
        }
        __syncthreads();
        int r_ = tid >> 3, seg = tid & 7;
        float lmax = -3e38f;
#pragma unroll
        for (int q = 0; q < 8; ++q) lmax = fmaxf(lmax, sb[r_][seg * 8 + q]);
        pm[r_][seg] = lmax;
        __syncthreads();
        if (tid < 32) {
            float mt = pm[tid][0];
#pragma unroll
            for (int s2 = 1; s2 < 8; ++s2) mt = fmaxf(mt, pm[tid][s2]);
            float mn = fmaxf(mrow[tid], mt);
            fac[tid] = __expf(mrow[tid] - mn);
            mrow[tid] = mn;
        }
        __syncthreads();
        float lsum = 0.f;
#pragma unroll
        for (int q = 0; q < 8; ++q) {
            float p = __expf(sb[r_][seg * 8 + q] - mrow[r_]);
            sb[r_][seg * 8 + q] = p;
            lsum += p;
        }
        pm[r_][seg] = lsum;
        __syncthreads();
        if (tid < 32) {
            float s_ = 0.f;
#pragma unroll
            for (int s2 = 0; s2 < 8; ++s2) s_ += pm[tid][s2];
            lrow[tid] = lrow[tid] * fac[tid] + s_;
        }
        float f0 = fac[m0], f1 = fac[m0 + 1];
#pragma unroll
        for (int j = 0; j < 4; ++j) { oa0[j] *= f0; oa1[j] *= f1; }
        // oa += sb(32x64) @ vt(64x64)
#pragma unroll 16
        for (int kk = 0; kk < 64; ++kk) {
            float a0 = sb[m0][kk], a1 = sb[m0 + 1][kk];
            float4 b4 = *(const float4*)&vt[kk][n0];
            oa0[0] += a0 * b4.x; oa0[1] += a0 * b4.y; oa0[2] += a0 * b4.z; oa0[3] += a0 * b4.w;
            oa1[0] += a1 * b4.x; oa1[1] += a1 * b4.y; oa1[2] += a1 * b4.z; oa1[3] += a1 * b4.w;
        }
        __syncthreads();
    }
    size_t base = ((size_t)pb * A3V_TC + tc) * 2048;
    *(float4*)&opart[base + (size_t)m0 * 64 + n0] = make_float4(oa0[0], oa0[1], oa0[2], oa0[3]);
    *(float4*)&opart[base + (size_t)(m0 + 1) * 64 + n0] = make_float4(oa1[0], oa1[1], oa1[2], oa1[3]);
    if (tid < 32) {
        mpart[((size_t)pb * A3V_TC + tc) * 32 + tid] = mrow[tid];
        lpart[((size_t)pb * A3V_TC + tc) * 32 + tid] = lrow[tid];
    }
}

__global__ __launch_bounds__(64) void a3v_comb_k(const float* __restrict__ opart,
    const float* __restrict__ mpart, const float* __restrict__ lpart, float* __restrict__ a3v)
{
    int pb = blockIdx.x, d = threadIdx.x;
    for (int r = 0; r < 32; ++r) {
        float M = -3e38f;
        for (int tc = 0; tc < A3V_TC; ++tc)
            M = fmaxf(M, mpart[((size_t)pb * A3V_TC + tc) * 32 + r]);
        float L = 0.f, od = 0.f;
        for (int tc = 0; tc < A3V_TC; ++tc) {
            float w = __expf(mpart[((size_t)pb * A3V_TC + tc) * 32 + r] - M);
            L += lpart[((size_t)pb * A3V_TC + tc) * 32 + r] * w;
            od += w * opart[((size_t)pb * A3V_TC + tc) * 2048 + (size_t)r * 64 + d];
        }
        a3v[((size_t)pb * 32 + r) * 64 + d] = od / L;
    }
}

// ---------------- fused: o[t, h*64+d] = softmax_j(q[t]·k_l[j]) @ Wm[h]
__global__ __launch_bounds__(256) void attnout_k(const float* __restrict__ qkvb,
    const float* __restrict__ kl, const float* __restrict__ wm, float* __restrict__ o)
{
    int h = blockIdx.x & 7;
    int rb = blockIdx.x >> 3;
    __shared__ float klds[256 * 65];
    __shared__ float qlds[4][64];
    __shared__ float alds[4][256];
    int tid = threadIdx.x;
    int w = tid >> 6, lane = tid & 63;
    for (int e = tid; e < 16384; e += 256) {
        int j = e >> 6, d = e & 63;
        klds[j * 65 + d] = kl[((size_t)h << 14) + e];
    }
    __syncthreads();
    const float* Wh = wm + ((size_t)h << 14);
    for (int rr = 0; rr < 8; ++rr) {
        int t = (rb << 5) + (w << 3) + rr;
        qlds[w][lane] = qkvb[(size_t)t * QKVW + (h << 6) + lane];
        __syncthreads();
        float s0 = 0.f, s1 = 0.f, s2 = 0.f, s3 = 0.f;
#pragma unroll 8
        for (int d = 0; d < 64; ++d) {
            float qb = qlds[w][d];
            s0 += qb * klds[lane * 65 + d];
            s1 += qb * klds[(lane + 64) * 65 + d];
            s2 += qb * klds[(lane + 128) * 65 + d];
            s3 += qb * klds[(lane + 192) * 65 + d];
        }
        float mx = fmaxf(fmaxf(s0, s1), fmaxf(s2, s3));
#pragma unroll
        for (int off = 32; off; off >>= 1) mx = fmaxf(mx, __shfl_xor(mx, off));
        float p0 = __expf(s0 - mx), p1 = __expf(s1 - mx), p2 = __expf(s2 - mx), p3 = __expf(s3 - mx);
        float sum = p0 + p1 + p2 + p3;
#pragma unroll
        for (int off = 32; off; off >>= 1) sum += __shfl_xor(sum, off);
        float inv = 1.f / sum;
        alds[w][lane] = p0 * inv;
        alds[w][lane + 64] = p1 * inv;
        alds[w][lane + 128] = p2 * inv;
        alds[w][lane + 192] = p3 * inv;
        __syncthreads();
        float od = 0.f;
#pragma unroll 4
        for (int j = 0; j < 256; ++j) od += alds[w][j] * Wh[(j << 6) + lane];
        o[(size_t)t * DIMF + (h << 6) + lane] = od;
        __syncthreads();
    }
}

// ---------------- depthwise residual conv (kernel 33 along seq) added into o
__global__ void resconv_k(const float* __restrict__ qkvb, const float* __restrict__ rw,
                          float* __restrict__ o)
{
    int idx = blockIdx.x * 256 + threadIdx.x;
    if (idx >= NP * DIMF) return;
    int t = idx >> 9, c = idx & 511;
    int h = c >> 6;
    float s = 0.f;
#pragma unroll
    for (int ky = 0; ky < 33; ++ky) {
        int tr = t + ky - 16;
        if ((unsigned)tr < (unsigned)NP)
            s += rw[h * 33 + ky] * qkvb[(size_t)tr * QKVW + 1024 + c];
    }
    o[idx] += s;
}

// ---------------- PPEG: 7x7 + 5x5 + 3x3 depthwise + identity on 128x128 grid
__global__ __launch_bounds__(256) void ppeg_k(const float* __restrict__ x,
    const float* __restrict__ w7, const float* __restrict__ b7,
    const float* __restrict__ w5, const float* __restrict__ b5,
    const float* __restrict__ w3, const float* __restrict__ b3,
    float* __restrict__ tmp)
{
    int c = ((blockIdx.x & 1) << 8) + threadIdx.x;
    int sp = blockIdx.x >> 1;
    int y = sp >> 7, xx = sp & 127;
    const float* feat = x + DIMF;   // skip cls row
    float acc = feat[(size_t)sp * DIMF + c] + b7[c] + b5[c] + b3[c];
#pragma unroll
    for (int ky = 0; ky < 7; ++ky) {
        int yy = y + ky - 3;
        if ((unsigned)yy >= 128u) continue;
#pragma unroll
        for (int kx = 0; kx < 7; ++kx) {
            int xc = xx + kx - 3;
            if ((unsigned)xc >= 128u) continue;
            acc += w7[c * 49 + ky * 7 + kx] * feat[(size_t)(yy * 128 + xc) * DIMF + c];
        }
    }
#pragma unroll
    for (int ky = 0; ky < 5; ++ky) {
        int yy = y + ky - 2;
        if ((unsigned)yy >= 128u) continue;
#pragma unroll
        for (int kx = 0; kx < 5; ++kx) {
            int xc = xx + kx - 2;
            if ((unsigned)xc >= 128u) continue;
            acc += w5[c * 25 + ky * 5 + kx] * feat[(size_t)(yy * 128 + xc) * DIMF + c];
        }
    }
#pragma unroll
    for (int ky = 0; ky < 3; ++ky) {
        int yy = y + ky - 1;
        if ((unsigned)yy >= 128u) continue;
#pragma unroll
        for (int kx = 0; kx < 3; ++kx) {
            int xc = xx + kx - 1;
            if ((unsigned)xc >= 128u) continue;
            acc += w3[c * 9 + ky * 3 + kx] * feat[(size_t)(yy * 128 + xc) * DIMF + c];
        }
    }
    tmp[(size_t)sp * DIMF + c] = acc;
}

// ---------------- final LN(row0) + 2-class head + softmax + argmax
__global__ __launch_bounds__(64) void head_k(const float* __restrict__ x,
    const float* __restrict__ g, const float* __restrict__ b,
    const float* __restrict__ w, const float* __restrict__ bias, float* __restrict__ out)
{
    int lane = threadIdx.x;
    float v[8], s = 0.f;
#pragma unroll
    for (int i = 0; i < 8; ++i) { v[i] = x[i * 64 + lane]; s += v[i]; }
#pragma unroll
    for (int off = 32; off; off >>= 1) s += __shfl_xor(s, off);
    float mu = s * (1.f / 512.f);
    float vs = 0.f;
#pragma unroll
    for (int i = 0; i < 8; ++i) { float d = v[i] - mu; vs += d * d; }
#pragma unroll
    for (int off = 32; off; off >>= 1) vs += __shfl_xor(vs, off);
    float rstd = rsqrtf(vs * (1.f / 512.f) + 1e-5f);
    float l0 = 0.f, l1 = 0.f;
#pragma unroll
    for (int i = 0; i < 8; ++i) {
        int d = i * 64 + lane;
        float hn = (v[i] - mu) * rstd * g[d] + b[d];
        l0 += hn * w[d * 2];
        l1 += hn * w[d * 2 + 1];
    }
#pragma unroll
    for (int off = 32; off; off >>= 1) { l0 += __shfl_xor(l0, off); l1 += __shfl_xor(l1, off); }
    if (lane == 0) {
        l0 += bias[0]; l1 += bias[1];
        float m = fmaxf(l0, l1);
        float e0 = __expf(l0 - m), e1 = __expf(l1 - m);
        float ss = e0 + e1;
        out[0] = l0; out[1] = l1;
        out[2] = e0 / ss; out[3] = e1 / ss;
        out[4] = (l1 > l0) ? 1.f : 0.f;
    }
}

extern "C" void kernel_launch(void* const* d_in, const int* in_sizes, int n_in,
                              void* d_out, int out_size, void* d_ws, size_t ws_size,
                              hipStream_t stream)
{
    (void)in_sizes; (void)n_in; (void)out_size; (void)ws_size;
    const float* data   = (const float*)d_in[0];
    const float* fc1_w  = (const float*)d_in[1];
    const float* fc1_b  = (const float*)d_in[2];
    const float* cls    = (const float*)d_in[3];
    const float* l1_ng  = (const float*)d_in[4];
    const float* l1_nb  = (const float*)d_in[5];
    const float* l1_qkv = (const float*)d_in[6];
    const float* l1_ow  = (const float*)d_in[7];
    const float* l1_ob  = (const float*)d_in[8];
    const float* l1_rw  = (const float*)d_in[9];
    const float* l2_ng  = (const float*)d_in[10];
    const float* l2_nb  = (const float*)d_in[11];
    const float* l2_qkv = (const float*)d_in[12];
    const float* l2_ow  = (const float*)d_in[13];
    const float* l2_ob  = (const float*)d_in[14];
    const float* l2_rw  = (const float*)d_in[15];
    const float* p_w7   = (const float*)d_in[16];
    const float* p_b7   = (const float*)d_in[17];
    const float* p_w5   = (const float*)d_in[18];
    const float* p_b5   = (const float*)d_in[19];
    const float* p_w3   = (const float*)d_in[20];
    const float* p_b3   = (const float*)d_in[21];
    const float* n_g    = (const float*)d_in[22];
    const float* n_b    = (const float*)d_in[23];
    const float* fc2_w  = (const float*)d_in[24];
    const float* fc2_b  = (const float*)d_in[25];

    float* ws = (float*)d_ws;
    float* x     = ws;                                   // 16385*512
    float* xp    = x + (size_t)NT * DIMF;                // 16640*512
    float* qkvb  = xp + (size_t)NP * DIMF;               // 16640*1536
    float* obuf  = qkvb + (size_t)NP * QKVW;             // 16640*512 (also ppeg tmp)
    float* ql    = obuf + (size_t)NP * DIMF;             // 8*256*64
    float* kl    = ql + 131072;
    float* a2    = kl + 131072;                          // 8*256*256
    float* zb    = a2 + 524288;
    float* z2    = zb + 524288;
    float* xz    = z2 + 524288;
    float* ta    = xz + 524288;
    float* tb    = ta + 524288;
    float* a3v   = tb + 524288;                          // 8*256*64
    float* wm    = a3v + 131072;
    float* opart = wm + 131072;                          // 64*10*2048
    float* mpart = opart + (size_t)64 * A3V_TC * 2048;
    float* lpart = mpart + (size_t)64 * A3V_TC * 32;

    // ---- stem: x[0]=cls; x[1..] = relu(data @ fc1_w + fc1_b)
    hipMemcpyAsync(x, cls, DIMF * sizeof(float), hipMemcpyDeviceToDevice, stream);
    gemm_k<<<dim3(DIMF / 64, 16384 / 64), 256, 0, stream>>>(
        data, fc1_w, fc1_b, x + DIMF, 16384, DIMF, 1024, 1024, DIMF, DIMF, 0.f, 1);

    auto layer = [&](const float* ng, const float* nb, const float* qw,
                     const float* ow, const float* ob, const float* rw) {
        hipMemsetAsync(xp, 0, (size_t)PADR * DIMF * sizeof(float), stream);
        ln_k<<<NT, 64, 0, stream>>>(x, ng, nb, xp + (size_t)PADR * DIMF, NT);
        gemm_k<<<dim3(QKVW / 64, NP / 64), 256, 0, stream>>>(
            xp, qw, nullptr, qkvb, NP, QKVW, DIMF, DIMF, QKVW, QKVW, 0.f, 0);
        scaleq_k<<<(NP * DIMF + 255) / 256, 256, 0, stream>>>(qkvb);
        landmark_k<<<NHEAD * NLM, 64, 0, stream>>>(qkvb, ql, kl);
        a2_k<<<NHEAD * NLM, 256, 0, stream>>>(ql, kl, a2);
        zinit_k<<<NHEAD, 256, 0, stream>>>(a2, zb);
        float* zc = zb; float* zn = z2;
        for (int it = 0; it < 6; ++it) {
            mm256_k<<<dim3(4, 4, NHEAD), 256, 0, stream>>>(a2, zc, xz, 256, 1.f, 0.f);
            ewi_k<<<2048, 256, 0, stream>>>(xz, ta, -1.f, 7.f);
            mm256_k<<<dim3(4, 4, NHEAD), 256, 0, stream>>>(xz, ta, tb, 256, -1.f, 15.f);
            mm256_k<<<dim3(4, 4, NHEAD), 256, 0, stream>>>(xz, tb, ta, 256, -1.f, 13.f);
            mm256_k<<<dim3(4, 4, NHEAD), 256, 0, stream>>>(zc, ta, zn, 256, 0.25f, 0.f);
            float* sw = zc; zc = zn; zn = sw;
        }
        a3v_part_k<<<dim3(64, A3V_TC), 256, 0, stream>>>(ql, qkvb, opart, mpart, lpart);
        a3v_comb_k<<<64, 64, 0, stream>>>(opart, mpart, lpart, a3v);
        mm256_k<<<dim3(1, 4, NHEAD), 256, 0, stream>>>(zc, a3v, wm, 64, 1.f, 0.f);
        attnout_k<<<520 * NHEAD, 256, 0, stream>>>(qkvb, kl, wm, obuf);
        resconv_k<<<(NP * DIMF + 255) / 256, 256, 0, stream>>>(qkvb, rw, obuf);
        // x += o[255..] @ out_w + out_b
        gemm_k<<<dim3(DIMF / 64, (NT + 63) / 64), 256, 0, stream>>>(
            obuf + (size_t)PADR * DIMF, ow, ob, x, NT, DIMF, DIMF, DIMF, DIMF, DIMF, 1.f, 0);
    };

    layer(l1_ng, l1_nb, l1_qkv, l1_ow, l1_ob, l1_rw);

    ppeg_k<<<16384 * 2, 256, 0, stream>>>(x, p_w7, p_b7, p_w5, p_b5, p_w3, p_b3, obuf);
    hipMemcpyAsync(x + DIMF, obuf, (size_t)16384 * DIMF * sizeof(float),
                   hipMemcpyDeviceToDevice, stream);

    layer(l2_ng, l2_nb, l2_qkv, l2_ow, l2_ob, l2_rw);

    head_k<<<1, 64, 0, stream>>>(x, n_g, n_b, fc2_w, fc2_b, (float*)d_out);
}

// Round 2
// 4267.886 us; speedup vs baseline: 1.6132x; 1.6132x over previous
//
#include <hip/hip_runtime.h>
#include <hip/hip_bf16.h>

// TransMIL forward, fp32. Round 2: LDS-tiled ppeg/resconv, restructured attnout.
// Dims: N_PATCH=16384, SIZE=1024, DIM=512, HEADS=8, DH=64, LANDMARKS=256,
// tokens NT=16385 (cls+16384), padded NP=16640 (front pad 255), l=65.

#define NT 16385
#define NP 16640
#define PADR 255
#define DIMF 512
#define QKVW 1536
#define NHEAD 8
#define DH 64
#define NLM 256
#define LSEG 65
#define A3V_TC 10   // t-chunks for flash split (260 tiles / 10 = 26 each)

// ---------------- generic tiled fp32 GEMM: C = beta*C + A@B + bias, opt relu
__global__ __launch_bounds__(256) void gemm_k(
    const float* __restrict__ A, const float* __restrict__ B,
    const float* __restrict__ bias, float* __restrict__ C,
    int M, int N, int K, int lda, int ldb, int ldc, float beta, int relu)
{
    __shared__ float As[16][65];
    __shared__ float Bs[16][64];
    int tx = threadIdx.x & 15, ty = threadIdx.x >> 4;
    int m0 = blockIdx.y << 6, n0 = blockIdx.x << 6;
    int la_k = tx, la_m = ty;
    int lb_n = threadIdx.x & 63, lb_k = threadIdx.x >> 6;
    float acc[4][4] = {};
    for (int kt = 0; kt < K; kt += 16) {
#pragma unroll
        for (int i = 0; i < 4; ++i) {
            int gm = m0 + la_m + 16 * i;
            float v = (gm < M) ? A[(size_t)gm * lda + kt + la_k] : 0.f;
            As[la_k][la_m + 16 * i] = v;
        }
#pragma unroll
        for (int i = 0; i < 4; ++i)
            Bs[lb_k + 4 * i][lb_n] = B[(size_t)(kt + lb_k + 4 * i) * ldb + n0 + lb_n];
        __syncthreads();
#pragma unroll
        for (int kk = 0; kk < 16; ++kk) {
            float a_[4], b_[4];
#pragma unroll
            for (int i = 0; i < 4; ++i) a_[i] = As[kk][ty * 4 + i];
#pragma unroll
            for (int j = 0; j < 4; ++j) b_[j] = Bs[kk][tx * 4 + j];
#pragma unroll
            for (int i = 0; i < 4; ++i)
#pragma unroll
                for (int j = 0; j < 4; ++j) acc[i][j] += a_[i] * b_[j];
        }
        __syncthreads();
    }
#pragma unroll
    for (int i = 0; i < 4; ++i) {
        int gm = m0 + ty * 4 + i;
        if (gm >= M) continue;
#pragma unroll
        for (int j = 0; j < 4; ++j) {
            int gn = n0 + tx * 4 + j;
            float c = acc[i][j];
            if (bias) c += bias[gn];
            if (beta != 0.f) c += beta * C[(size_t)gm * ldc + gn];
            if (relu) c = fmaxf(c, 0.f);
            C[(size_t)gm * ldc + gn] = c;
        }
    }
}

// ---------------- batched per-head GEMM: D = alpha*(c1*A - A@B) + delta*I
// (A is [256x256] per head; B is [256xN]; used for the pinv Newton chain)
__global__ __launch_bounds__(256) void mm256_k(
    const float* __restrict__ A, const float* __restrict__ B, float* __restrict__ D,
    int N, float c1, float alpha, float delta)
{
    __shared__ float As[16][65];
    __shared__ float Bs[16][64];
    int h = blockIdx.z;
    const float* Ah = A + ((size_t)h << 16);
    const float* Bh = B + (size_t)h * 256 * N;
    float* Dh = D + (size_t)h * 256 * N;
    int tx = threadIdx.x & 15, ty = threadIdx.x >> 4;
    int m0 = blockIdx.y << 6, n0 = blockIdx.x << 6;
    int lb_n = threadIdx.x & 63, lb_k = threadIdx.x >> 6;
    float acc[4][4] = {};
    for (int kt = 0; kt < 256; kt += 16) {
#pragma unroll
        for (int i = 0; i < 4; ++i)
            As[tx][ty + 16 * i] = Ah[(size_t)(m0 + ty + 16 * i) * 256 + kt + tx];
#pragma unroll
        for (int i = 0; i < 4; ++i)
            Bs[lb_k + 4 * i][lb_n] = Bh[(size_t)(kt + lb_k + 4 * i) * N + n0 + lb_n];
        __syncthreads();
#pragma unroll
        for (int kk = 0; kk < 16; ++kk) {
            float a_[4], b_[4];
#pragma unroll
            for (int i = 0; i < 4; ++i) a_[i] = As[kk][ty * 4 + i];
#pragma unroll
            for (int j = 0; j < 4; ++j) b_[j] = Bs[kk][tx * 4 + j];
#pragma unroll
            for (int i = 0; i < 4; ++i)
#pragma unroll
                for (int j = 0; j < 4; ++j) acc[i][j] += a_[i] * b_[j];
        }
        __syncthreads();
    }
#pragma unroll
    for (int i = 0; i < 4; ++i)
#pragma unroll
        for (int j = 0; j < 4; ++j) {
            int gr = m0 + ty * 4 + i, gc = n0 + tx * 4 + j;
            float cv = -alpha * acc[i][j];
            if (c1 != 0.f) cv += alpha * c1 * Ah[(size_t)gr * 256 + gc];
            if (gr == gc) cv += delta;
            Dh[(size_t)gr * N + gc] = cv;
        }
}

// ---------------- LayerNorm per row (512), one wave per row
__global__ __launch_bounds__(64) void ln_k(const float* __restrict__ in,
    const float* __restrict__ g, const float* __restrict__ b,
    float* __restrict__ out, int rows)
{
    int r = blockIdx.x;
    if (r >= rows) return;
    int lane = threadIdx.x;
    const float* xr = in + (size_t)r * DIMF;
    float v[8], s = 0.f;
#pragma unroll
    for (int i = 0; i < 8; ++i) { v[i] = xr[i * 64 + lane]; s += v[i]; }
#pragma unroll
    for (int off = 32; off; off >>= 1) s += __shfl_xor(s, off);
    float mu = s * (1.f / 512.f);
    float vs = 0.f;
#pragma unroll
    for (int i = 0; i < 8; ++i) { float d = v[i] - mu; vs += d * d; }
#pragma unroll
    for (int off = 32; off; off >>= 1) vs += __shfl_xor(vs, off);
    float rstd = rsqrtf(vs * (1.f / 512.f) + 1e-5f);
    float* orow = out + (size_t)r * DIMF;
#pragma unroll
    for (int i = 0; i < 8; ++i) {
        int d = i * 64 + lane;
        orow[d] = (v[i] - mu) * rstd * g[d] + b[d];
    }
}

// ---------------- landmark means; ql scaled by DH^-0.5; also writes klT [h][d][j]
__global__ __launch_bounds__(64) void landmark_k(const float* __restrict__ qkvb,
    float* __restrict__ ql, float* __restrict__ kl, float* __restrict__ klT)
{
    int bx = blockIdx.x;            // h*256 + j
    int h = bx >> 8, j = bx & 255;
    int d = threadIdx.x;
    float qs = 0.f, ks = 0.f;
    for (int u = 0; u < LSEG; ++u) {
        size_t addr = (size_t)(j * LSEG + u) * QKVW + (h << 6) + d;
        qs += qkvb[addr];
        ks += qkvb[addr + 512];
    }
    float qm = qs * (1.f / 65.f) * 0.125f;
    float km = ks * (1.f / 65.f);
    ql[(size_t)bx * 64 + d] = qm;
    kl[(size_t)bx * 64 + d] = km;
    klT[((size_t)h << 14) + (d << 8) + j] = km;
}

// ---------------- a2 = softmax(q_l @ k_l^T) rows; block per (h,i)
__global__ __launch_bounds__(256) void a2_k(const float* __restrict__ ql,
    const float* __restrict__ kl, float* __restrict__ a2)
{
    int h = blockIdx.x >> 8, i = blockIdx.x & 255;
    int j = threadIdx.x;
    __shared__ float qs[64];
    __shared__ float red[256];
    if (j < 64) qs[j] = ql[((size_t)(h << 8) + i) * 64 + j];
    __syncthreads();
    const float* kr = kl + ((size_t)(h << 8) + j) * 64;
    float s = 0.f;
#pragma unroll 8
    for (int d = 0; d < 64; ++d) s += qs[d] * kr[d];
    red[j] = s; __syncthreads();
    for (int st = 128; st; st >>= 1) { if (j < st) red[j] = fmaxf(red[j], red[j + st]); __syncthreads(); }
    float mx = red[0]; __syncthreads();
    float p = __expf(s - mx);
    red[j] = p; __syncthreads();
    for (int st = 128; st; st >>= 1) { if (j < st) red[j] += red[j + st]; __syncthreads(); }
    a2[((size_t)h << 16) + i * 256 + j] = p / red[0];
}

// ---------------- pinv init: z = a2^T / (max_rowsum * max_colsum), per head
__global__ __launch_bounds__(256) void zinit_k(const float* __restrict__ a2, float* __restrict__ z)
{
    int h = blockIdx.x, t = threadIdx.x;
    const float* X = a2 + ((size_t)h << 16);
    __shared__ float red[256];
    float rs = 0.f;
    for (int j = 0; j < 256; ++j) rs += fabsf(X[t * 256 + j]);
    red[t] = rs; __syncthreads();
    for (int st = 128; st; st >>= 1) { if (t < st) red[t] = fmaxf(red[t], red[t + st]); __syncthreads(); }
    float colv = red[0]; __syncthreads();
    float cs = 0.f;
    for (int i = 0; i < 256; ++i) cs += fabsf(X[i * 256 + t]);
    red[t] = cs; __syncthreads();
    for (int st = 128; st; st >>= 1) { if (t < st) red[t] = fmaxf(red[t], red[t + st]); __syncthreads(); }
    float rowv = red[0];
    float inv = 1.f / (colv * rowv);
    for (int e = t; e < 65536; e += 256) {
        int i = e >> 8, j = e & 255;
        z[((size_t)h << 16) + e] = X[j * 256 + i] * inv;
    }
}

// ---------------- flash-style a3v partials: per (h, 32-landmark block, t-chunk)
__global__ __launch_bounds__(256) void a3v_part_k(
    const float* __restrict__ ql, const float* __restrict__ qkvb,
    float* __restrict__ opart, float* __restrict__ mpart, float* __restrict__ lpart)
{
    int pb = blockIdx.x;            // h*8+ib
    int h = pb >> 3, ib = pb & 7;
    int tc = blockIdx.y;
    __shared__ __align__(16) float qc[32][66];
    __shared__ __align__(16) float ktT[64][68];   // [d][tt]
    __shared__ __align__(16) float vt[64][68];    // [tt][d]
    __shared__ float sb[32][65];
    __shared__ float pm[32][8];
    __shared__ float mrow[32], lrow[32], fac[32];
    int tid = threadIdx.x;
    for (int e = tid; e < 2048; e += 256) {
        int r = e >> 6, d = e & 63;
        qc[r][d] = ql[((size_t)(h << 8) + (ib << 5) + r) * 64 + d];
    }
    if (tid < 32) { mrow[tid] = -3e38f; lrow[tid] = 0.f; }
    int tx = tid & 15, ty = tid >> 4;
    int m0 = ty * 2, n0 = tx * 4;
    float oa0[4] = {}, oa1[4] = {};
    __syncthreads();
    for (int tile = tc * 26; tile < tc * 26 + 26; ++tile) {
        int t0 = tile * 64;
        for (int e = tid; e < 4096; e += 256) {
            int tt = e >> 6, d = e & 63;
            size_t ga = (size_t)(t0 + tt) * QKVW + 512 + (h << 6) + d;
            ktT[d][tt] = qkvb[ga];          // k
            vt[tt][d] = qkvb[ga + 512];     // v
        }
        __syncthreads();
        {
            float c0[4] = {}, c1[4] = {};
#pragma unroll 16
            for (int kk = 0; kk < 64; ++kk) {
                float a0 = qc[m0][kk], a1 = qc[m0 + 1][kk];
                float4 b4 = *(const float4*)&ktT[kk][n0];
                c0[0] += a0 * b4.x; c0[1] += a0 * b4.y; c0[2] += a0 * b4.z; c0[3] += a0 * b4.w;
                c1[0] += a1 * b4.x; c1[1] += a1 * b4.y; c1[2] += a1 * b4.z; c1[3] += a1 * b4.w;
            }
#pragma unroll
            for (int j = 0; j < 4; ++j) { sb[m0][n0 + j] = c0[j]; sb[m0 + 1][n0 + j] = c1[j]; }
        }
        __syncthreads();
        int r_ = tid >> 3, seg = tid & 7;
        float lmax = -3e38f;
#pragma unroll
        for (int q = 0; q < 8; ++q) lmax = fmaxf(lmax, sb[r_][seg * 8 + q]);
        pm[r_][seg] = lmax;
        __syncthreads();
        if (tid < 32) {
            float mt = pm[tid][0];
#pragma unroll
            for (int s2 = 1; s2 < 8; ++s2) mt = fmaxf(mt, pm[tid][s2]);
            float mn = fmaxf(mrow[tid], mt);
            fac[tid] = __expf(mrow[tid] - mn);
            mrow[tid] = mn;
        }
        __syncthreads();
        float lsum = 0.f;
#pragma unroll
        for (int q = 0; q < 8; ++q) {
            float p = __expf(sb[r_][seg * 8 + q] - mrow[r_]);
            sb[r_][seg * 8 + q] = p;
            lsum += p;
        }
        pm[r_][seg] = lsum;
        __syncthreads();
        if (tid < 32) {
            float s_ = 0.f;
#pragma unroll
            for (int s2 = 0; s2 < 8; ++s2) s_ += pm[tid][s2];
            lrow[tid] = lrow[tid] * fac[tid] + s_;
        }
        float f0 = fac[m0], f1 = fac[m0 + 1];
#pragma unroll
        for (int j = 0; j < 4; ++j) { oa0[j] *= f0; oa1[j] *= f1; }
#pragma unroll 16
        for (int kk = 0; kk < 64; ++kk) {
            float a0 = sb[m0][kk], a1 = sb[m0 + 1][kk];
            float4 b4 = *(const float4*)&vt[kk][n0];
            oa0[0] += a0 * b4.x; oa0[1] += a0 * b4.y; oa0[2] += a0 * b4.z; oa0[3] += a0 * b4.w;
            oa1[0] += a1 * b4.x; oa1[1] += a1 * b4.y; oa1[2] += a1 * b4.z; oa1[3] += a1 * b4.w;
        }
        __syncthreads();
    }
    size_t base = ((size_t)pb * A3V_TC + tc) * 2048;
    *(float4*)&opart[base + (size_t)m0 * 64 + n0] = make_float4(oa0[0], oa0[1], oa0[2], oa0[3]);
    *(float4*)&opart[base + (size_t)(m0 + 1) * 64 + n0] = make_float4(oa1[0], oa1[1], oa1[2], oa1[3]);
    if (tid < 32) {
        mpart[((size_t)pb * A3V_TC + tc) * 32 + tid] = mrow[tid];
        lpart[((size_t)pb * A3V_TC + tc) * 32 + tid] = lrow[tid];
    }
}

__global__ __launch_bounds__(64) void a3v_comb_k(const float* __restrict__ opart,
    const float* __restrict__ mpart, const float* __restrict__ lpart, float* __restrict__ a3v)
{
    int pb = blockIdx.x, d = threadIdx.x;
    for (int r = 0; r < 32; ++r) {
        float M = -3e38f;
        for (int tc = 0; tc < A3V_TC; ++tc)
            M = fmaxf(M, mpart[((size_t)pb * A3V_TC + tc) * 32 + r]);
        float L = 0.f, od = 0.f;
        for (int tc = 0; tc < A3V_TC; ++tc) {
            float w = __expf(mpart[((size_t)pb * A3V_TC + tc) * 32 + r] - M);
            L += lpart[((size_t)pb * A3V_TC + tc) * 32 + r] * w;
            od += w * opart[((size_t)pb * A3V_TC + tc) * 2048 + (size_t)r * 64 + d];
        }
        a3v[((size_t)pb * 32 + r) * 64 + d] = od / L;
    }
}

// ---------------- fused sim1-softmax @ Wm: 32 rows per block, 8 rows/wave,
// 2-chunk online softmax over the 256 landmarks (LDS < 64KB, 2 blocks/CU)
__global__ __launch_bounds__(256) void attnout_k(const float* __restrict__ qkvb,
    const float* __restrict__ klT, const float* __restrict__ wm, float* __restrict__ o)
{
    int h = blockIdx.x & 7;
    int rb = blockIdx.x >> 3;
    __shared__ float klds[64][128];     // [d][j_local]
    __shared__ float alds[32][128];     // unnormalized P per row (wave-private rows)
    __shared__ float qs[4][8][64];      // per-wave q rows
    int tid = threadIdx.x, w = tid >> 6, lane = tid & 63;
    int tbase = (rb << 5) + (w << 3);
#pragma unroll
    for (int r = 0; r < 8; ++r)
        qs[w][r][lane] = qkvb[(size_t)(tbase + r) * QKVW + (h << 6) + lane] * 0.125f;
    float m_[8], l_[8], acc[8];
#pragma unroll
    for (int r = 0; r < 8; ++r) { m_[r] = -3e38f; l_[r] = 0.f; acc[r] = 0.f; }
    for (int ch = 0; ch < 2; ++ch) {
        __syncthreads();                // all waves done with previous klds
        for (int e = tid; e < 8192; e += 256)
            (&klds[0][0])[e] = klT[((size_t)h << 14) + (size_t)((e >> 7) << 8) + (ch << 7) + (e & 127)];
        __syncthreads();
        float s[8][2];
#pragma unroll
        for (int r = 0; r < 8; ++r) { s[r][0] = 0.f; s[r][1] = 0.f; }
#pragma unroll 8
        for (int d = 0; d < 64; ++d) {
            float k0 = klds[d][lane], k1 = klds[d][lane + 64];
#pragma unroll
            for (int r = 0; r < 8; ++r) {
                float qb = qs[w][r][d];
                s[r][0] += qb * k0; s[r][1] += qb * k1;
            }
        }
#pragma unroll
        for (int r = 0; r < 8; ++r) {
            float mx = fmaxf(s[r][0], s[r][1]);
#pragma unroll
            for (int off = 32; off; off >>= 1) mx = fmaxf(mx, __shfl_xor(mx, off));
            float mn = fmaxf(m_[r], mx);
            float f = __expf(m_[r] - mn);
            float p0 = __expf(s[r][0] - mn), p1 = __expf(s[r][1] - mn);
            float ps = p0 + p1;
#pragma unroll
            for (int off = 32; off; off >>= 1) ps += __shfl_xor(ps, off);
            l_[r] = l_[r] * f + ps;
            m_[r] = mn;
            acc[r] *= f;
            alds[(w << 3) + r][lane] = p0;
            alds[(w << 3) + r][lane + 64] = p1;
        }
        const float* Wh = wm + ((size_t)h << 14) + ((size_t)ch << 13);
#pragma unroll 2
        for (int j = 0; j < 128; ++j) {
            float whv = Wh[(j << 6) + lane];
#pragma unroll
            for (int r = 0; r < 8; ++r) acc[r] += alds[(w << 3) + r][j] * whv;
        }
    }
#pragma unroll
    for (int r = 0; r < 8; ++r)
        o[(size_t)(tbase + r) * DIMF + (h << 6) + lane] = acc[r] / l_[r];
}

// ---------------- LDS-tiled depthwise residual conv (33-tap along seq), += into o
__global__ __launch_bounds__(256) void resconv_tile_k(const float* __restrict__ qkvb,
    const float* __restrict__ rw, float* __restrict__ o)
{
    int cg = blockIdx.y;            // head == 64-channel group
    int t0 = blockIdx.x << 7;       // 128 t per block
    int tid = threadIdx.x;
    int lane = tid & 63, w = tid >> 6;
    __shared__ float vt[160][64];
    __shared__ float wr[33];
    if (tid < 33) wr[tid] = rw[cg * 33 + tid];
    for (int e = tid; e < 160 * 64; e += 256) {
        int tt = e >> 6, l = e & 63;
        int t = t0 - 16 + tt;
        vt[tt][l] = (t >= 0 && t < NP) ? qkvb[(size_t)t * QKVW + 1024 + (cg << 6) + l] : 0.f;
    }
    __syncthreads();
    for (int i = 0; i < 32; ++i) {
        int tl = (w << 5) + i;
        float acc = 0.f;
#pragma unroll
        for (int ky = 0; ky < 33; ++ky) acc += wr[ky] * vt[tl + ky][lane];
        o[(size_t)(t0 + tl) * DIMF + (cg << 6) + lane] += acc;
    }
}

// ---------------- LDS-tiled PPEG: 8x8 spatial x 32 ch per block, 14x14 halo tile
__global__ __launch_bounds__(256) void ppeg_tile_k(const float* __restrict__ x,
    const float* __restrict__ w7, const float* __restrict__ b7,
    const float* __restrict__ w5, const float* __restrict__ b5,
    const float* __restrict__ w3, const float* __restrict__ b3,
    float* __restrict__ tmp)
{
    int cg = blockIdx.y;                              // 0..15, 32 channels
    int ty0 = (blockIdx.x >> 4) << 3, tx0 = (blockIdx.x & 15) << 3;
    int tid = threadIdx.x;
    int lane = tid & 63, w = tid >> 6;
    int cl = lane & 31, xh = lane >> 5;
    int c = (cg << 5) + cl;
    const float* feat = x + DIMF;                     // skip cls row
    __shared__ float tile[196][32];
    __shared__ float w7s[49 * 32];
    __shared__ float w5s[25 * 32];
    __shared__ float w3s[9 * 32];
    for (int e = tid; e < 49 * 32; e += 256) w7s[e] = w7[cg * (49 * 32) + e];
    for (int e = tid; e < 25 * 32; e += 256) w5s[e] = w5[cg * (25 * 32) + e];
    for (int e = tid; e < 9 * 32; e += 256)  w3s[e] = w3[cg * (9 * 32) + e];
    for (int e = tid; e < 196 * 32; e += 256) {
        int sp = e >> 5, l = e & 31;
        int yy = ty0 - 3 + sp / 14, xc = tx0 - 3 + sp % 14;
        float v = 0.f;
        if ((unsigned)yy < 128u && (unsigned)xc < 128u)
            v = feat[(size_t)(yy * 128 + xc) * DIMF + (cg << 5) + l];
        tile[sp][l] = v;
    }
    __syncthreads();
    float bsum = b7[c] + b5[c] + b3[c];
    int xo = (w << 1) + xh;                           // 0..7
    for (int yb = 0; yb < 8; yb += 4) {
        float acc[4];
#pragma unroll
        for (int oidx = 0; oidx < 4; ++oidx)
            acc[oidx] = tile[(yb + oidx + 3) * 14 + xo + 3][cl] + bsum;
        // 7x7: tile row yb+r (r=o+ky), col xo+kx
#pragma unroll
        for (int kx = 0; kx < 7; ++kx) {
            float wc[7];
#pragma unroll
            for (int j = 0; j < 7; ++j) wc[j] = w7s[cl * 49 + j * 7 + kx];
#pragma unroll
            for (int r = 0; r < 10; ++r) {
                float v = tile[(yb + r) * 14 + xo + kx][cl];
#pragma unroll
                for (int oidx = 0; oidx < 4; ++oidx) {
                    int ky = r - oidx;
                    if (ky >= 0 && ky < 7) acc[oidx] += wc[ky] * v;
                }
            }
        }
        // 5x5: tile row yb+1+r, col xo+1+kx
#pragma unroll
        for (int kx = 0; kx < 5; ++kx) {
            float wc[5];
#pragma unroll
            for (int j = 0; j < 5; ++j) wc[j] = w5s[cl * 25 + j * 5 + kx];
#pragma unroll
            for (int r = 0; r < 8; ++r) {
                float v = tile[(yb + 1 + r) * 14 + xo + 1 + kx][cl];
#pragma unroll
                for (int oidx = 0; oidx < 4; ++oidx) {
                    int ky = r - oidx;
                    if (ky >= 0 && ky < 5) acc[oidx] += wc[ky] * v;
                }
            }
        }
        // 3x3: tile row yb+2+r, col xo+2+kx
#pragma unroll
        for (int kx = 0; kx < 3; ++kx) {
            float wc[3];
#pragma unroll
            for (int j = 0; j < 3; ++j) wc[j] = w3s[cl * 9 + j * 3 + kx];
#pragma unroll
            for (int r = 0; r < 6; ++r) {
                float v = tile[(yb + 2 + r) * 14 + xo + 2 + kx][cl];
#pragma unroll
                for (int oidx = 0; oidx < 4; ++oidx) {
                    int ky = r - oidx;
                    if (ky >= 0 && ky < 3) acc[oidx] += wc[ky] * v;
                }
            }
        }
#pragma unroll
        for (int oidx = 0; oidx < 4; ++oidx)
            tmp[(size_t)((ty0 + yb + oidx) * 128 + tx0 + xo) * DIMF + c] = acc[oidx];
    }
}

// ---------------- final LN(row0) + 2-class head + softmax + argmax
__global__ __launch_bounds__(64) void head_k(const float* __restrict__ x,
    const float* __restrict__ g, const float* __restrict__ b,
    const float* __restrict__ w, const float* __restrict__ bias, float* __restrict__ out)
{
    int lane = threadIdx.x;
    float v[8], s = 0.f;
#pragma unroll
    for (int i = 0; i < 8; ++i) { v[i] = x[i * 64 + lane]; s += v[i]; }
#pragma unroll
    for (int off = 32; off; off >>= 1) s += __shfl_xor(s, off);
    float mu = s * (1.f / 512.f);
    float vs = 0.f;
#pragma unroll
    for (int i = 0; i < 8; ++i) { float d = v[i] - mu; vs += d * d; }
#pragma unroll
    for (int off = 32; off; off >>= 1) vs += __shfl_xor(vs, off);
    float rstd = rsqrtf(vs * (1.f / 512.f) + 1e-5f);
    float l0 = 0.f, l1 = 0.f;
#pragma unroll
    for (int i = 0; i < 8; ++i) {
        int d = i * 64 + lane;
        float hn = (v[i] - mu) * rstd * g[d] + b[d];
        l0 += hn * w[d * 2];
        l1 += hn * w[d * 2 + 1];
    }
#pragma unroll
    for (int off = 32; off; off >>= 1) { l0 += __shfl_xor(l0, off); l1 += __shfl_xor(l1, off); }
    if (lane == 0) {
        l0 += bias[0]; l1 += bias[1];
        float m = fmaxf(l0, l1);
        float e0 = __expf(l0 - m), e1 = __expf(l1 - m);
        float ss = e0 + e1;
        out[0] = l0; out[1] = l1;
        out[2] = e0 / ss; out[3] = e1 / ss;
        out[4] = (l1 > l0) ? 1.f : 0.f;
    }
}

extern "C" void kernel_launch(void* const* d_in, const int* in_sizes, int n_in,
                              void* d_out, int out_size, void* d_ws, size_t ws_size,
                              hipStream_t stream)
{
    (void)in_sizes; (void)n_in; (void)out_size; (void)ws_size;
    const float* data   = (const float*)d_in[0];
    const float* fc1_w  = (const float*)d_in[1];
    const float* fc1_b  = (const float*)d_in[2];
    const float* cls    = (const float*)d_in[3];
    const float* l1_ng  = (const float*)d_in[4];
    const float* l1_nb  = (const float*)d_in[5];
    const float* l1_qkv = (const float*)d_in[6];
    const float* l1_ow  = (const float*)d_in[7];
    const float* l1_ob  = (const float*)d_in[8];
    const float* l1_rw  = (const float*)d_in[9];
    const float* l2_ng  = (const float*)d_in[10];
    const float* l2_nb  = (const float*)d_in[11];
    const float* l2_qkv = (const float*)d_in[12];
    const float* l2_ow  = (const float*)d_in[13];
    const float* l2_ob  = (const float*)d_in[14];
    const float* l2_rw  = (const float*)d_in[15];
    const float* p_w7   = (const float*)d_in[16];
    const float* p_b7   = (const float*)d_in[17];
    const float* p_w5   = (const float*)d_in[18];
    const float* p_b5   = (const float*)d_in[19];
    const float* p_w3   = (const float*)d_in[20];
    const float* p_b3   = (const float*)d_in[21];
    const float* n_g    = (const float*)d_in[22];
    const float* n_b    = (const float*)d_in[23];
    const float* fc2_w  = (const float*)d_in[24];
    const float* fc2_b  = (const float*)d_in[25];

    float* ws = (float*)d_ws;
    float* x     = ws;                                   // 16385*512
    float* xp    = x + (size_t)NT * DIMF;                // 16640*512
    float* qkvb  = xp + (size_t)NP * DIMF;               // 16640*1536
    float* obuf  = qkvb + (size_t)NP * QKVW;             // 16640*512 (also ppeg tmp)
    float* ql    = obuf + (size_t)NP * DIMF;             // 8*256*64
    float* kl    = ql + 131072;
    float* a2    = kl + 131072;                          // 8*256*256
    float* zb    = a2 + 524288;
    float* z2    = zb + 524288;
    float* xz    = z2 + 524288;
    float* ta    = xz + 524288;
    float* tb    = ta + 524288;
    float* a3v   = tb + 524288;                          // 8*256*64
    float* wm    = a3v + 131072;
    float* opart = wm + 131072;                          // 64*10*2048
    float* mpart = opart + (size_t)64 * A3V_TC * 2048;
    float* lpart = mpart + (size_t)64 * A3V_TC * 32;
    float* klT   = lpart + (size_t)64 * A3V_TC * 32;     // 8*64*256

    // ---- stem: x[0]=cls; x[1..] = relu(data @ fc1_w + fc1_b)
    hipMemcpyAsync(x, cls, DIMF * sizeof(float), hipMemcpyDeviceToDevice, stream);
    gemm_k<<<dim3(DIMF / 64, 16384 / 64), 256, 0, stream>>>(
        data, fc1_w, fc1_b, x + DIMF, 16384, DIMF, 1024, 1024, DIMF, DIMF, 0.f, 1);

    auto layer = [&](const float* ng, const float* nb, const float* qw,
                     const float* ow, const float* ob, const float* rw) {
        hipMemsetAsync(xp, 0, (size_t)PADR * DIMF * sizeof(float), stream);
        ln_k<<<NT, 64, 0, stream>>>(x, ng, nb, xp + (size_t)PADR * DIMF, NT);
        gemm_k<<<dim3(QKVW / 64, NP / 64), 256, 0, stream>>>(
            xp, qw, nullptr, qkvb, NP, QKVW, DIMF, DIMF, QKVW, QKVW, 0.f, 0);
        landmark_k<<<NHEAD * NLM, 64, 0, stream>>>(qkvb, ql, kl, klT);
        a2_k<<<NHEAD * NLM, 256, 0, stream>>>(ql, kl, a2);
        zinit_k<<<NHEAD, 256, 0, stream>>>(a2, zb);
        float* zc = zb; float* zn = z2;
        for (int it = 0; it < 6; ++it) {
            // xz = a2@zc
            mm256_k<<<dim3(4, 4, NHEAD), 256, 0, stream>>>(a2, zc, xz, 256, 0.f, -1.f, 0.f);
            // ta = 15I - xz@(7I - xz)
            mm256_k<<<dim3(4, 4, NHEAD), 256, 0, stream>>>(xz, xz, ta, 256, 7.f, -1.f, 15.f);
            // tb = 13I - xz@ta
            mm256_k<<<dim3(4, 4, NHEAD), 256, 0, stream>>>(xz, ta, tb, 256, 0.f, 1.f, 13.f);
            // zn = 0.25 * zc@tb
            mm256_k<<<dim3(4, 4, NHEAD), 256, 0, stream>>>(zc, tb, zn, 256, 0.f, -0.25f, 0.f);
            float* sw = zc; zc = zn; zn = sw;
        }
        a3v_part_k<<<dim3(64, A3V_TC), 256, 0, stream>>>(ql, qkvb, opart, mpart, lpart);
        a3v_comb_k<<<64, 64, 0, stream>>>(opart, mpart, lpart, a3v);
        // wm = pinv @ a3v
        mm256_k<<<dim3(1, 4, NHEAD), 256, 0, stream>>>(zc, a3v, wm, 64, 0.f, -1.f, 0.f);
        attnout_k<<<520 * NHEAD, 256, 0, stream>>>(qkvb, klT, wm, obuf);
        resconv_tile_k<<<dim3(NP / 128, NHEAD), 256, 0, stream>>>(qkvb, rw, obuf);
        // x += o[255..] @ out_w + out_b
        gemm_k<<<dim3(DIMF / 64, (NT + 63) / 64), 256, 0, stream>>>(
            obuf + (size_t)PADR * DIMF, ow, ob, x, NT, DIMF, DIMF, DIMF, DIMF, DIMF, 1.f, 0);
    };

    layer(l1_ng, l1_nb, l1_qkv, l1_ow, l1_ob, l1_rw);

    ppeg_tile_k<<<dim3(256, 16), 256, 0, stream>>>(x, p_w7, p_b7, p_w5, p_b5, p_w3, p_b3, obuf);
    hipMemcpyAsync(x + DIMF, obuf, (size_t)16384 * DIMF * sizeof(float),
                   hipMemcpyDeviceToDevice, stream);

    layer(l2_ng, l2_nb, l2_qkv, l2_ow, l2_ob, l2_rw);

    head_k<<<1, 64, 0, stream>>>(x, n_g, n_b, fc2_w, fc2_b, (float*)d_out);
}

// Round 3
// 2694.923 us; speedup vs baseline: 2.5548x; 1.5837x over previous
//
#include <hip/hip_runtime.h>
#include <hip/hip_bf16.h>

// TransMIL forward. Round 3: bf16 MFMA for the big GEMMs (m97 structure),
// fp32 everywhere else. Dims: N_PATCH=16384, SIZE=1024, DIM=512, HEADS=8,
// DH=64, LANDMARKS=256, NT=16385 (cls+patches), NP=16640 (front pad 255).

#define NT 16385
#define NP 16640
#define PADR 255
#define DIMF 512
#define QKVW 1536
#define NHEAD 8
#define DH 64
#define NLM 256
#define LSEG 65
#define A3V_TC 10

typedef short bf16x8 __attribute__((ext_vector_type(8)));
typedef float f32x4 __attribute__((ext_vector_type(4)));

__device__ __forceinline__ void gload_lds16(const void* g, void* l) {
    __builtin_amdgcn_global_load_lds(
        (const __attribute__((address_space(1))) void*)g,
        (__attribute__((address_space(3))) void*)l, 16, 0, 0);
}

// ---------------- bf16 MFMA GEMM: C[MxN] = A[MxK]@BT[NxK]^T + bias (+Cacc)(+relu)
// 128x128 tile, BK=64, 4 waves each 64x64. M-tail: staging row clamped to MA-1,
// store guarded by gm<M. N,K multiples of 128/64.
__global__ __launch_bounds__(256) void gemm_bf16_k(
    const __hip_bfloat16* __restrict__ A, const __hip_bfloat16* __restrict__ BT,
    const float* __restrict__ bias, const float* __restrict__ Cacc,
    float* __restrict__ C, int M, int N, int K, int MA, int relu)
{
    __shared__ __align__(16) __hip_bfloat16 Asl[128 * 64];
    __shared__ __align__(16) __hip_bfloat16 Bsl[128 * 64];
    int tid = threadIdx.x;
    int wid = tid >> 6, lane = tid & 63;
    int m0 = blockIdx.y << 7, n0 = blockIdx.x << 7;
    int wr = (wid >> 1) << 6, wc = (wid & 1) << 6;
    f32x4 acc[4][4] = {};
    int lr = lane >> 3, lk = (lane & 7) << 3;     // staging: row-in-chunk, k-elem
    for (int kt = 0; kt < K; kt += 64) {
#pragma unroll
        for (int i = 0; i < 4; ++i) {
            int ch = wid * 4 + i;
            int rowA = m0 + ch * 8 + lr;
            rowA = rowA < MA ? rowA : (MA - 1);
            gload_lds16(A + (size_t)rowA * K + kt + lk, &Asl[ch * 512]);
            int rowB = n0 + ch * 8 + lr;
            gload_lds16(BT + (size_t)rowB * K + kt + lk, &Bsl[ch * 512]);
        }
        __syncthreads();
#pragma unroll
        for (int ks = 0; ks < 2; ++ks) {
            int kb = ks * 32 + (lane >> 4) * 8;
            bf16x8 af[4], bfr[4];
#pragma unroll
            for (int m = 0; m < 4; ++m)
                af[m] = *(const bf16x8*)&Asl[(wr + m * 16 + (lane & 15)) * 64 + kb];
#pragma unroll
            for (int n = 0; n < 4; ++n)
                bfr[n] = *(const bf16x8*)&Bsl[(wc + n * 16 + (lane & 15)) * 64 + kb];
#pragma unroll
            for (int m = 0; m < 4; ++m)
#pragma unroll
                for (int n = 0; n < 4; ++n)
                    acc[m][n] = __builtin_amdgcn_mfma_f32_16x16x32_bf16(
                        af[m], bfr[n], acc[m][n], 0, 0, 0);
        }
        __syncthreads();
    }
    int cr = (lane >> 4) << 2, cc = lane & 15;
#pragma unroll
    for (int m = 0; m < 4; ++m) {
#pragma unroll
        for (int i = 0; i < 4; ++i) {
            int gm = m0 + wr + m * 16 + cr + i;
            if (gm >= M) continue;
#pragma unroll
            for (int n = 0; n < 4; ++n) {
                int gn = n0 + wc + n * 16 + cc;
                float v = acc[m][n][i];
                if (bias) v += bias[gn];
                if (Cacc) v += Cacc[(size_t)gm * N + gn];
                if (relu) v = fmaxf(v, 0.f);
                C[(size_t)gm * N + gn] = v;
            }
        }
    }
}

// ---------------- fp32 [KxN] -> bf16 [NxK] tiled transpose-convert
__global__ __launch_bounds__(256) void transcvt_k(const float* __restrict__ W,
    __hip_bfloat16* __restrict__ WT, int K, int N)
{
    __shared__ float t[32][33];
    int nt = N >> 5;
    int n0 = (blockIdx.x % nt) << 5, k0 = (blockIdx.x / nt) << 5;
    int tx = threadIdx.x & 31, ty = threadIdx.x >> 5;
    for (int r = ty; r < 32; r += 8) t[r][tx] = W[(size_t)(k0 + r) * N + n0 + tx];
    __syncthreads();
    for (int r = ty; r < 32; r += 8)
        WT[(size_t)(n0 + r) * K + k0 + tx] = __float2bfloat16(t[tx][r]);
}

// ---------------- fp32 -> bf16 convert (vectorized)
__global__ __launch_bounds__(256) void cvt_k(const float4* __restrict__ in,
    ushort4* __restrict__ out, int n4)
{
    int i = blockIdx.x * 256 + threadIdx.x;
    if (i >= n4) return;
    float4 v = in[i];
    union { __hip_bfloat16 h[4]; ushort4 u; } cv;
    cv.h[0] = __float2bfloat16(v.x); cv.h[1] = __float2bfloat16(v.y);
    cv.h[2] = __float2bfloat16(v.z); cv.h[3] = __float2bfloat16(v.w);
    out[i] = cv.u;
}

// ---------------- batched per-head GEMM: D = alpha*(c1*A - A@B) + delta*I
__global__ __launch_bounds__(256) void mm256_k(
    const float* __restrict__ A, const float* __restrict__ B, float* __restrict__ D,
    int N, float c1, float alpha, float delta)
{
    __shared__ __align__(16) float As[16][68];
    __shared__ __align__(16) float Bs[16][64];
    int h = blockIdx.z;
    const float* Ah = A + ((size_t)h << 16);
    const float* Bh = B + (size_t)h * 256 * N;
    float* Dh = D + (size_t)h * 256 * N;
    int tx = threadIdx.x & 15, ty = threadIdx.x >> 4;
    int m0 = blockIdx.y << 6, n0 = blockIdx.x << 6;
    int lb_n = threadIdx.x & 63, lb_k = threadIdx.x >> 6;
    float acc[4][4] = {};
    for (int kt = 0; kt < 256; kt += 16) {
#pragma unroll
        for (int i = 0; i < 4; ++i)
            As[tx][ty + 16 * i] = Ah[(size_t)(m0 + ty + 16 * i) * 256 + kt + tx];
#pragma unroll
        for (int i = 0; i < 4; ++i)
            Bs[lb_k + 4 * i][lb_n] = Bh[(size_t)(kt + lb_k + 4 * i) * N + n0 + lb_n];
        __syncthreads();
#pragma unroll
        for (int kk = 0; kk < 16; ++kk) {
            float4 av = *(const float4*)&As[kk][ty * 4];
            float4 bv = *(const float4*)&Bs[kk][tx * 4];
            float a_[4] = { av.x, av.y, av.z, av.w };
            float b_[4] = { bv.x, bv.y, bv.z, bv.w };
#pragma unroll
            for (int i = 0; i < 4; ++i)
#pragma unroll
                for (int j = 0; j < 4; ++j) acc[i][j] += a_[i] * b_[j];
        }
        __syncthreads();
    }
#pragma unroll
    for (int i = 0; i < 4; ++i)
#pragma unroll
        for (int j = 0; j < 4; ++j) {
            int gr = m0 + ty * 4 + i, gc = n0 + tx * 4 + j;
            float cv = -alpha * acc[i][j];
            if (c1 != 0.f) cv += alpha * c1 * Ah[(size_t)gr * 256 + gc];
            if (gr == gc) cv += delta;
            Dh[(size_t)gr * N + gc] = cv;
        }
}

// ---------------- LayerNorm per row (512) -> bf16 out, one wave per row
__global__ __launch_bounds__(64) void ln_k(const float* __restrict__ in,
    const float* __restrict__ g, const float* __restrict__ b,
    __hip_bfloat16* __restrict__ out, int rows)
{
    int r = blockIdx.x;
    if (r >= rows) return;
    int lane = threadIdx.x;
    const float* xr = in + (size_t)r * DIMF;
    float v[8], s = 0.f;
#pragma unroll
    for (int i = 0; i < 8; ++i) { v[i] = xr[i * 64 + lane]; s += v[i]; }
#pragma unroll
    for (int off = 32; off; off >>= 1) s += __shfl_xor(s, off);
    float mu = s * (1.f / 512.f);
    float vs = 0.f;
#pragma unroll
    for (int i = 0; i < 8; ++i) { float d = v[i] - mu; vs += d * d; }
#pragma unroll
    for (int off = 32; off; off >>= 1) vs += __shfl_xor(vs, off);
    float rstd = rsqrtf(vs * (1.f / 512.f) + 1e-5f);
    __hip_bfloat16* orow = out + (size_t)r * DIMF;
#pragma unroll
    for (int i = 0; i < 8; ++i) {
        int d = i * 64 + lane;
        orow[d] = __float2bfloat16((v[i] - mu) * rstd * g[d] + b[d]);
    }
}

// ---------------- landmark means; ql scaled by DH^-0.5; also writes klT [h][d][j]
__global__ __launch_bounds__(64) void landmark_k(const float* __restrict__ qkvb,
    float* __restrict__ ql, float* __restrict__ kl, float* __restrict__ klT)
{
    int bx = blockIdx.x;
    int h = bx >> 8, j = bx & 255;
    int d = threadIdx.x;
    float qs = 0.f, ks = 0.f;
    for (int u = 0; u < LSEG; ++u) {
        size_t addr = (size_t)(j * LSEG + u) * QKVW + (h << 6) + d;
        qs += qkvb[addr];
        ks += qkvb[addr + 512];
    }
    float qm = qs * (1.f / 65.f) * 0.125f;
    float km = ks * (1.f / 65.f);
    ql[(size_t)bx * 64 + d] = qm;
    kl[(size_t)bx * 64 + d] = km;
    klT[((size_t)h << 14) + (d << 8) + j] = km;
}

// ---------------- a2 = softmax(q_l @ k_l^T) rows; block per (h,i)
__global__ __launch_bounds__(256) void a2_k(const float* __restrict__ ql,
    const float* __restrict__ kl, float* __restrict__ a2)
{
    int h = blockIdx.x >> 8, i = blockIdx.x & 255;
    int j = threadIdx.x;
    __shared__ float qs[64];
    __shared__ float red[256];
    if (j < 64) qs[j] = ql[((size_t)(h << 8) + i) * 64 + j];
    __syncthreads();
    const float* kr = kl + ((size_t)(h << 8) + j) * 64;
    float s = 0.f;
#pragma unroll 8
    for (int d = 0; d < 64; ++d) s += qs[d] * kr[d];
    red[j] = s; __syncthreads();
    for (int st = 128; st; st >>= 1) { if (j < st) red[j] = fmaxf(red[j], red[j + st]); __syncthreads(); }
    float mx = red[0]; __syncthreads();
    float p = __expf(s - mx);
    red[j] = p; __syncthreads();
    for (int st = 128; st; st >>= 1) { if (j < st) red[j] += red[j + st]; __syncthreads(); }
    a2[((size_t)h << 16) + i * 256 + j] = p / red[0];
}

// ---------------- pinv init: z = a2^T / (max_rowsum * max_colsum), per head
__global__ __launch_bounds__(256) void zinit_k(const float* __restrict__ a2, float* __restrict__ z)
{
    int h = blockIdx.x, t = threadIdx.x;
    const float* X = a2 + ((size_t)h << 16);
    __shared__ float red[256];
    float rs = 0.f;
    for (int j = 0; j < 256; ++j) rs += fabsf(X[t * 256 + j]);
    red[t] = rs; __syncthreads();
    for (int st = 128; st; st >>= 1) { if (t < st) red[t] = fmaxf(red[t], red[t + st]); __syncthreads(); }
    float colv = red[0]; __syncthreads();
    float cs = 0.f;
    for (int i = 0; i < 256; ++i) cs += fabsf(X[i * 256 + t]);
    red[t] = cs; __syncthreads();
    for (int st = 128; st; st >>= 1) { if (t < st) red[t] = fmaxf(red[t], red[t + st]); __syncthreads(); }
    float rowv = red[0];
    float inv = 1.f / (colv * rowv);
    for (int e = t; e < 65536; e += 256) {
        int i = e >> 8, j = e & 255;
        z[((size_t)h << 16) + e] = X[j * 256 + i] * inv;
    }
}

// ---------------- flash-style a3v partials: per (h, 32-landmark block, t-chunk)
__global__ __launch_bounds__(256) void a3v_part_k(
    const float* __restrict__ ql, const float* __restrict__ qkvb,
    float* __restrict__ opart, float* __restrict__ mpart, float* __restrict__ lpart)
{
    int pb = blockIdx.x;
    int h = pb >> 3, ib = pb & 7;
    int tc = blockIdx.y;
    __shared__ __align__(16) float qc[32][66];
    __shared__ __align__(16) float ktT[64][68];
    __shared__ __align__(16) float vt[64][68];
    __shared__ float sb[32][65];
    __shared__ float pm[32][8];
    __shared__ float mrow[32], lrow[32], fac[32];
    int tid = threadIdx.x;
    for (int e = tid; e < 2048; e += 256) {
        int r = e >> 6, d = e & 63;
        qc[r][d] = ql[((size_t)(h << 8) + (ib << 5) + r) * 64 + d];
    }
    if (tid < 32) { mrow[tid] = -3e38f; lrow[tid] = 0.f; }
    int tx = tid & 15, ty = tid >> 4;
    int m0 = ty * 2, n0 = tx * 4;
    float oa0[4] = {}, oa1[4] = {};
    __syncthreads();
    for (int tile = tc * 26; tile < tc * 26 + 26; ++tile) {
        int t0 = tile * 64;
        for (int e = tid; e < 4096; e += 256) {
            int tt = e >> 6, d = e & 63;
            size_t ga = (size_t)(t0 + tt) * QKVW + 512 + (h << 6) + d;
            ktT[d][tt] = qkvb[ga];
            vt[tt][d] = qkvb[ga + 512];
        }
        __syncthreads();
        {
            float c0[4] = {}, c1[4] = {};
#pragma unroll 16
            for (int kk = 0; kk < 64; ++kk) {
                float a0 = qc[m0][kk], a1 = qc[m0 + 1][kk];
                float4 b4 = *(const float4*)&ktT[kk][n0];
                c0[0] += a0 * b4.x; c0[1] += a0 * b4.y; c0[2] += a0 * b4.z; c0[3] += a0 * b4.w;
                c1[0] += a1 * b4.x; c1[1] += a1 * b4.y; c1[2] += a1 * b4.z; c1[3] += a1 * b4.w;
            }
#pragma unroll
            for (int j = 0; j < 4; ++j) { sb[m0][n0 + j] = c0[j]; sb[m0 + 1][n0 + j] = c1[j]; }
        }
        __syncthreads();
        int r_ = tid >> 3, seg = tid & 7;
        float lmax = -3e38f;
#pragma unroll
        for (int q = 0; q < 8; ++q) lmax = fmaxf(lmax, sb[r_][seg * 8 + q]);
        pm[r_][seg] = lmax;
        __syncthreads();
        if (tid < 32) {
            float mt = pm[tid][0];
#pragma unroll
            for (int s2 = 1; s2 < 8; ++s2) mt = fmaxf(mt, pm[tid][s2]);
            float mn = fmaxf(mrow[tid], mt);
            fac[tid] = __expf(mrow[tid] - mn);
            mrow[tid] = mn;
        }
        __syncthreads();
        float lsum = 0.f;
#pragma unroll
        for (int q = 0; q < 8; ++q) {
            float p = __expf(sb[r_][seg * 8 + q] - mrow[r_]);
            sb[r_][seg * 8 + q] = p;
            lsum += p;
        }
        pm[r_][seg] = lsum;
        __syncthreads();
        if (tid < 32) {
            float s_ = 0.f;
#pragma unroll
            for (int s2 = 0; s2 < 8; ++s2) s_ += pm[tid][s2];
            lrow[tid] = lrow[tid] * fac[tid] + s_;
        }
        float f0 = fac[m0], f1 = fac[m0 + 1];
#pragma unroll
        for (int j = 0; j < 4; ++j) { oa0[j] *= f0; oa1[j] *= f1; }
#pragma unroll 16
        for (int kk = 0; kk < 64; ++kk) {
            float a0 = sb[m0][kk], a1 = sb[m0 + 1][kk];
            float4 b4 = *(const float4*)&vt[kk][n0];
            oa0[0] += a0 * b4.x; oa0[1] += a0 * b4.y; oa0[2] += a0 * b4.z; oa0[3] += a0 * b4.w;
            oa1[0] += a1 * b4.x; oa1[1] += a1 * b4.y; oa1[2] += a1 * b4.z; oa1[3] += a1 * b4.w;
        }
        __syncthreads();
    }
    size_t base = ((size_t)pb * A3V_TC + tc) * 2048;
    *(float4*)&opart[base + (size_t)m0 * 64 + n0] = make_float4(oa0[0], oa0[1], oa0[2], oa0[3]);
    *(float4*)&opart[base + (size_t)(m0 + 1) * 64 + n0] = make_float4(oa1[0], oa1[1], oa1[2], oa1[3]);
    if (tid < 32) {
        mpart[((size_t)pb * A3V_TC + tc) * 32 + tid] = mrow[tid];
        lpart[((size_t)pb * A3V_TC + tc) * 32 + tid] = lrow[tid];
    }
}

__global__ __launch_bounds__(64) void a3v_comb_k(const float* __restrict__ opart,
    const float* __restrict__ mpart, const float* __restrict__ lpart, float* __restrict__ a3v)
{
    int pb = blockIdx.x, d = threadIdx.x;
    for (int r = 0; r < 32; ++r) {
        float M = -3e38f;
        for (int tc = 0; tc < A3V_TC; ++tc)
            M = fmaxf(M, mpart[((size_t)pb * A3V_TC + tc) * 32 + r]);
        float L = 0.f, od = 0.f;
        for (int tc = 0; tc < A3V_TC; ++tc) {
            float w = __expf(mpart[((size_t)pb * A3V_TC + tc) * 32 + r] - M);
            L += lpart[((size_t)pb * A3V_TC + tc) * 32 + r] * w;
            od += w * opart[((size_t)pb * A3V_TC + tc) * 2048 + (size_t)r * 64 + d];
        }
        a3v[((size_t)pb * 32 + r) * 64 + d] = od / L;
    }
}

// ---------------- fused sim1-softmax @ Wm: 32 rows/block, 8 rows/wave
__global__ __launch_bounds__(256) void attnout_k(const float* __restrict__ qkvb,
    const float* __restrict__ klT, const float* __restrict__ wm, float* __restrict__ o)
{
    int h = blockIdx.x & 7;
    int rb = blockIdx.x >> 3;
    __shared__ float klds[64][128];
    __shared__ float alds[32][128];
    __shared__ float qs[4][8][64];
    int tid = threadIdx.x, w = tid >> 6, lane = tid & 63;
    int tbase = (rb << 5) + (w << 3);
#pragma unroll
    for (int r = 0; r < 8; ++r)
        qs[w][r][lane] = qkvb[(size_t)(tbase + r) * QKVW + (h << 6) + lane] * 0.125f;
    float m_[8], l_[8], acc[8];
#pragma unroll
    for (int r = 0; r < 8; ++r) { m_[r] = -3e38f; l_[r] = 0.f; acc[r] = 0.f; }
    for (int ch = 0; ch < 2; ++ch) {
        __syncthreads();
        for (int e = tid; e < 8192; e += 256)
            (&klds[0][0])[e] = klT[((size_t)h << 14) + (size_t)((e >> 7) << 8) + (ch << 7) + (e & 127)];
        __syncthreads();
        float s[8][2];
#pragma unroll
        for (int r = 0; r < 8; ++r) { s[r][0] = 0.f; s[r][1] = 0.f; }
#pragma unroll 8
        for (int d = 0; d < 64; ++d) {
            float k0 = klds[d][lane], k1 = klds[d][lane + 64];
#pragma unroll
            for (int r = 0; r < 8; ++r) {
                float qb = qs[w][r][d];
                s[r][0] += qb * k0; s[r][1] += qb * k1;
            }
        }
#pragma unroll
        for (int r = 0; r < 8; ++r) {
            float mx = fmaxf(s[r][0], s[r][1]);
#pragma unroll
            for (int off = 32; off; off >>= 1) mx = fmaxf(mx, __shfl_xor(mx, off));
            float mn = fmaxf(m_[r], mx);
            float f = __expf(m_[r] - mn);
            float p0 = __expf(s[r][0] - mn), p1 = __expf(s[r][1] - mn);
            float ps = p0 + p1;
#pragma unroll
            for (int off = 32; off; off >>= 1) ps += __shfl_xor(ps, off);
            l_[r] = l_[r] * f + ps;
            m_[r] = mn;
            acc[r] *= f;
            alds[(w << 3) + r][lane] = p0;
            alds[(w << 3) + r][lane + 64] = p1;
        }
        const float* Wh = wm + ((size_t)h << 14) + ((size_t)ch << 13);
#pragma unroll 2
        for (int j = 0; j < 128; ++j) {
            float whv = Wh[(j << 6) + lane];
#pragma unroll
            for (int r = 0; r < 8; ++r) acc[r] += alds[(w << 3) + r][j] * whv;
        }
    }
#pragma unroll
    for (int r = 0; r < 8; ++r)
        o[(size_t)(tbase + r) * DIMF + (h << 6) + lane] = acc[r] / l_[r];
}

// ---------------- resconv (33-tap along seq) + convert to bf16: out = oin + conv
__global__ __launch_bounds__(256) void resconv_tile_k(const float* __restrict__ qkvb,
    const float* __restrict__ rw, const float* __restrict__ oin,
    __hip_bfloat16* __restrict__ oout)
{
    int cg = blockIdx.y;
    int t0 = blockIdx.x << 7;
    int tid = threadIdx.x;
    int lane = tid & 63, w = tid >> 6;
    __shared__ float vt[160][64];
    __shared__ float wr[33];
    if (tid < 33) wr[tid] = rw[cg * 33 + tid];
    for (int e = tid; e < 160 * 64; e += 256) {
        int tt = e >> 6, l = e & 63;
        int t = t0 - 16 + tt;
        vt[tt][l] = (t >= 0 && t < NP) ? qkvb[(size_t)t * QKVW + 1024 + (cg << 6) + l] : 0.f;
    }
    __syncthreads();
    for (int i = 0; i < 32; ++i) {
        int tl = (w << 5) + i;
        float acc = 0.f;
#pragma unroll
        for (int ky = 0; ky < 33; ++ky) acc += wr[ky] * vt[tl + ky][lane];
        size_t oi = (size_t)(t0 + tl) * DIMF + (cg << 6) + lane;
        oout[oi] = __float2bfloat16(oin[oi] + acc);
    }
}

// ---------------- LDS-tiled PPEG
__global__ __launch_bounds__(256) void ppeg_tile_k(const float* __restrict__ x,
    const float* __restrict__ w7, const float* __restrict__ b7,
    const float* __restrict__ w5, const float* __restrict__ b5,
    const float* __restrict__ w3, const float* __restrict__ b3,
    float* __restrict__ tmp)
{
    int cg = blockIdx.y;
    int ty0 = (blockIdx.x >> 4) << 3, tx0 = (blockIdx.x & 15) << 3;
    int tid = threadIdx.x;
    int lane = tid & 63, w = tid >> 6;
    int cl = lane & 31, xh = lane >> 5;
    int c = (cg << 5) + cl;
    const float* feat = x + DIMF;
    __shared__ float tile[196][32];
    __shared__ float w7s[49 * 32];
    __shared__ float w5s[25 * 32];
    __shared__ float w3s[9 * 32];
    for (int e = tid; e < 49 * 32; e += 256) w7s[e] = w7[cg * (49 * 32) + e];
    for (int e = tid; e < 25 * 32; e += 256) w5s[e] = w5[cg * (25 * 32) + e];
    for (int e = tid; e < 9 * 32; e += 256)  w3s[e] = w3[cg * (9 * 32) + e];
    for (int e = tid; e < 196 * 32; e += 256) {
        int sp = e >> 5, l = e & 31;
        int yy = ty0 - 3 + sp / 14, xc = tx0 - 3 + sp % 14;
        float v = 0.f;
        if ((unsigned)yy < 128u && (unsigned)xc < 128u)
            v = feat[(size_t)(yy * 128 + xc) * DIMF + (cg << 5) + l];
        tile[sp][l] = v;
    }
    __syncthreads();
    float bsum = b7[c] + b5[c] + b3[c];
    int xo = (w << 1) + xh;
    for (int yb = 0; yb < 8; yb += 4) {
        float acc[4];
#pragma unroll
        for (int oidx = 0; oidx < 4; ++oidx)
            acc[oidx] = tile[(yb + oidx + 3) * 14 + xo + 3][cl] + bsum;
#pragma unroll
        for (int kx = 0; kx < 7; ++kx) {
            float wc[7];
#pragma unroll
            for (int j = 0; j < 7; ++j) wc[j] = w7s[cl * 49 + j * 7 + kx];
#pragma unroll
            for (int r = 0; r < 10; ++r) {
                float v = tile[(yb + r) * 14 + xo + kx][cl];
#pragma unroll
                for (int oidx = 0; oidx < 4; ++oidx) {
                    int ky = r - oidx;
                    if (ky >= 0 && ky < 7) acc[oidx] += wc[ky] * v;
                }
            }
        }
#pragma unroll
        for (int kx = 0; kx < 5; ++kx) {
            float wc[5];
#pragma unroll
            for (int j = 0; j < 5; ++j) wc[j] = w5s[cl * 25 + j * 5 + kx];
#pragma unroll
            for (int r = 0; r < 8; ++r) {
                float v = tile[(yb + 1 + r) * 14 + xo + 1 + kx][cl];
#pragma unroll
                for (int oidx = 0; oidx < 4; ++oidx) {
                    int ky = r - oidx;
                    if (ky >= 0 && ky < 5) acc[oidx] += wc[ky] * v;
                }
            }
        }
#pragma unroll
        for (int kx = 0; kx < 3; ++kx) {
            float wc[3];
#pragma unroll
            for (int j = 0; j < 3; ++j) wc[j] = w3s[cl * 9 + j * 3 + kx];
#pragma unroll
            for (int r = 0; r < 6; ++r) {
                float v = tile[(yb + 2 + r) * 14 + xo + 2 + kx][cl];
#pragma unroll
                for (int oidx = 0; oidx < 4; ++oidx) {
                    int ky = r - oidx;
                    if (ky >= 0 && ky < 3) acc[oidx] += wc[ky] * v;
                }
            }
        }
#pragma unroll
        for (int oidx = 0; oidx < 4; ++oidx)
            tmp[(size_t)((ty0 + yb + oidx) * 128 + tx0 + xo) * DIMF + c] = acc[oidx];
    }
}

// ---------------- final LN(row0) + 2-class head + softmax + argmax
__global__ __launch_bounds__(64) void head_k(const float* __restrict__ x,
    const float* __restrict__ g, const float* __restrict__ b,
    const float* __restrict__ w, const float* __restrict__ bias, float* __restrict__ out)
{
    int lane = threadIdx.x;
    float v[8], s = 0.f;
#pragma unroll
    for (int i = 0; i < 8; ++i) { v[i] = x[i * 64 + lane]; s += v[i]; }
#pragma unroll
    for (int off = 32; off; off >>= 1) s += __shfl_xor(s, off);
    float mu = s * (1.f / 512.f);
    float vs = 0.f;
#pragma unroll
    for (int i = 0; i < 8; ++i) { float d = v[i] - mu; vs += d * d; }
#pragma unroll
    for (int off = 32; off; off >>= 1) vs += __shfl_xor(vs, off);
    float rstd = rsqrtf(vs * (1.f / 512.f) + 1e-5f);
    float l0 = 0.f, l1 = 0.f;
#pragma unroll
    for (int i = 0; i < 8; ++i) {
        int d = i * 64 + lane;
        float hn = (v[i] - mu) * rstd * g[d] + b[d];
        l0 += hn * w[d * 2];
        l1 += hn * w[d * 2 + 1];
    }
#pragma unroll
    for (int off = 32; off; off >>= 1) { l0 += __shfl_xor(l0, off); l1 += __shfl_xor(l1, off); }
    if (lane == 0) {
        l0 += bias[0]; l1 += bias[1];
        float m = fmaxf(l0, l1);
        float e0 = __expf(l0 - m), e1 = __expf(l1 - m);
        float ss = e0 + e1;
        out[0] = l0; out[1] = l1;
        out[2] = e0 / ss; out[3] = e1 / ss;
        out[4] = (l1 > l0) ? 1.f : 0.f;
    }
}

extern "C" void kernel_launch(void* const* d_in, const int* in_sizes, int n_in,
                              void* d_out, int out_size, void* d_ws, size_t ws_size,
                              hipStream_t stream)
{
    (void)in_sizes; (void)n_in; (void)out_size; (void)ws_size;
    const float* data   = (const float*)d_in[0];
    const float* fc1_w  = (const float*)d_in[1];
    const float* fc1_b  = (const float*)d_in[2];
    const float* cls    = (const float*)d_in[3];
    const float* l1_ng  = (const float*)d_in[4];
    const float* l1_nb  = (const float*)d_in[5];
    const float* l1_qkv = (const float*)d_in[6];
    const float* l1_ow  = (const float*)d_in[7];
    const float* l1_ob  = (const float*)d_in[8];
    const float* l1_rw  = (const float*)d_in[9];
    const float* l2_ng  = (const float*)d_in[10];
    const float* l2_nb  = (const float*)d_in[11];
    const float* l2_qkv = (const float*)d_in[12];
    const float* l2_ow  = (const float*)d_in[13];
    const float* l2_ob  = (const float*)d_in[14];
    const float* l2_rw  = (const float*)d_in[15];
    const float* p_w7   = (const float*)d_in[16];
    const float* p_b7   = (const float*)d_in[17];
    const float* p_w5   = (const float*)d_in[18];
    const float* p_b5   = (const float*)d_in[19];
    const float* p_w3   = (const float*)d_in[20];
    const float* p_b3   = (const float*)d_in[21];
    const float* n_g    = (const float*)d_in[22];
    const float* n_b    = (const float*)d_in[23];
    const float* fc2_w  = (const float*)d_in[24];
    const float* fc2_b  = (const float*)d_in[25];

    char* base = (char*)d_ws;
    auto carve = [&](size_t bytes) { char* p = base; base += (bytes + 255) & ~(size_t)255; return p; };
    float* x              = (float*)carve((size_t)NT * DIMF * 4);
    __hip_bfloat16* xp16  = (__hip_bfloat16*)carve((size_t)NP * DIMF * 2);   // aliased as obuf2
    float* qkvb           = (float*)carve((size_t)NP * QKVW * 4);            // aliased as data16 in stem
    float* obuf           = (float*)carve((size_t)NP * DIMF * 4);
    __hip_bfloat16* wT    = (__hip_bfloat16*)carve((size_t)QKVW * DIMF * 2);
    float* ql    = (float*)carve(131072 * 4);
    float* kl    = (float*)carve(131072 * 4);
    float* klT   = (float*)carve(131072 * 4);
    float* a2    = (float*)carve(524288 * 4);
    float* zb    = (float*)carve(524288 * 4);
    float* z2    = (float*)carve(524288 * 4);
    float* xz    = (float*)carve(524288 * 4);
    float* ta    = (float*)carve(524288 * 4);
    float* tb    = (float*)carve(524288 * 4);
    float* a3v   = (float*)carve(131072 * 4);
    float* wm    = (float*)carve(131072 * 4);
    float* opart = (float*)carve((size_t)64 * A3V_TC * 2048 * 4);
    float* mpart = (float*)carve((size_t)64 * A3V_TC * 32 * 4);
    float* lpart = (float*)carve((size_t)64 * A3V_TC * 32 * 4);
    __hip_bfloat16* obuf2 = xp16;                     // lifetime-disjoint alias
    __hip_bfloat16* data16 = (__hip_bfloat16*)qkvb;   // stem-only alias

    // ---- stem: x[0]=cls; x[1..] = relu(data @ fc1_w + fc1_b), via bf16 MFMA
    cvt_k<<<(16384 * 1024 / 4 + 255) / 256, 256, 0, stream>>>(
        (const float4*)data, (ushort4*)data16, 16384 * 1024 / 4);
    transcvt_k<<<(DIMF / 32) * (1024 / 32), 256, 0, stream>>>(fc1_w, wT, 1024, DIMF);
    gemm_bf16_k<<<dim3(DIMF / 128, 16384 / 128), 256, 0, stream>>>(
        data16, wT, fc1_b, nullptr, x + DIMF, 16384, DIMF, 1024, 16384, 1);
    hipMemcpyAsync(x, cls, DIMF * sizeof(float), hipMemcpyDeviceToDevice, stream);

    auto layer = [&](const float* ng, const float* nb, const float* qw,
                     const float* ow, const float* ob, const float* rw) {
        hipMemsetAsync(xp16, 0, (size_t)PADR * DIMF * 2, stream);
        ln_k<<<NT, 64, 0, stream>>>(x, ng, nb, xp16 + (size_t)PADR * DIMF, NT);
        transcvt_k<<<(QKVW / 32) * (DIMF / 32), 256, 0, stream>>>(qw, wT, DIMF, QKVW);
        gemm_bf16_k<<<dim3(QKVW / 128, NP / 128), 256, 0, stream>>>(
            xp16, wT, nullptr, nullptr, qkvb, NP, QKVW, DIMF, NP, 0);
        landmark_k<<<NHEAD * NLM, 64, 0, stream>>>(qkvb, ql, kl, klT);
        a2_k<<<NHEAD * NLM, 256, 0, stream>>>(ql, kl, a2);
        zinit_k<<<NHEAD, 256, 0, stream>>>(a2, zb);
        float* zc = zb; float* zn = z2;
        for (int it = 0; it < 6; ++it) {
            mm256_k<<<dim3(4, 4, NHEAD), 256, 0, stream>>>(a2, zc, xz, 256, 0.f, -1.f, 0.f);
            mm256_k<<<dim3(4, 4, NHEAD), 256, 0, stream>>>(xz, xz, ta, 256, 7.f, -1.f, 15.f);
            mm256_k<<<dim3(4, 4, NHEAD), 256, 0, stream>>>(xz, ta, tb, 256, 0.f, 1.f, 13.f);
            mm256_k<<<dim3(4, 4, NHEAD), 256, 0, stream>>>(zc, tb, zn, 256, 0.f, -0.25f, 0.f);
            float* sw = zc; zc = zn; zn = sw;
        }
        a3v_part_k<<<dim3(64, A3V_TC), 256, 0, stream>>>(ql, qkvb, opart, mpart, lpart);
        a3v_comb_k<<<64, 64, 0, stream>>>(opart, mpart, lpart, a3v);
        mm256_k<<<dim3(1, 4, NHEAD), 256, 0, stream>>>(zc, a3v, wm, 64, 0.f, -1.f, 0.f);
        attnout_k<<<520 * NHEAD, 256, 0, stream>>>(qkvb, klT, wm, obuf);
        resconv_tile_k<<<dim3(NP / 128, NHEAD), 256, 0, stream>>>(qkvb, rw, obuf, obuf2);
        transcvt_k<<<(DIMF / 32) * (DIMF / 32), 256, 0, stream>>>(ow, wT, DIMF, DIMF);
        // x += obuf2[255..] @ owT + ob   (M=16385, staging rows clamped)
        gemm_bf16_k<<<dim3(DIMF / 128, (NT + 127) / 128), 256, 0, stream>>>(
            obuf2 + (size_t)PADR * DIMF, wT, ob, x, x, NT, DIMF, DIMF, NT, 0);
    };

    layer(l1_ng, l1_nb, l1_qkv, l1_ow, l1_ob, l1_rw);

    ppeg_tile_k<<<dim3(256, 16), 256, 0, stream>>>(x, p_w7, p_b7, p_w5, p_b5, p_w3, p_b3, obuf);
    hipMemcpyAsync(x + DIMF, obuf, (size_t)16384 * DIMF * sizeof(float),
                   hipMemcpyDeviceToDevice, stream);

    layer(l2_ng, l2_nb, l2_qkv, l2_ow, l2_ob, l2_rw);

    head_k<<<1, 64, 0, stream>>>(x, n_g, n_b, fc2_w, fc2_b, (float*)d_out);
}

// Round 4
// 2278.358 us; speedup vs baseline: 3.0219x; 1.1828x over previous
//
#include <hip/hip_runtime.h>
#include <hip/hip_bf16.h>

// TransMIL forward. Round 4: MFMA attnout (sim1-softmax @ Wm fused, bf16),
// bf16 MFMA big GEMMs, fp32 pinv chain. NT=16385, NP=16640 (front pad 255).

#define NT 16385
#define NP 16640
#define PADR 255
#define DIMF 512
#define QKVW 1536
#define NHEAD 8
#define DH 64
#define NLM 256
#define LSEG 65
#define A3V_TC 10

typedef short bf16x8 __attribute__((ext_vector_type(8)));
typedef float f32x4 __attribute__((ext_vector_type(4)));

__device__ __forceinline__ void gload_lds16(const void* g, void* l) {
    __builtin_amdgcn_global_load_lds(
        (const __attribute__((address_space(1))) void*)g,
        (__attribute__((address_space(3))) void*)l, 16, 0, 0);
}

// ---------------- bf16 MFMA GEMM: C[MxN] = A[MxK]@BT[NxK]^T + bias (+Cacc)(+relu)
__global__ __launch_bounds__(256) void gemm_bf16_k(
    const __hip_bfloat16* __restrict__ A, const __hip_bfloat16* __restrict__ BT,
    const float* __restrict__ bias, const float* __restrict__ Cacc,
    float* __restrict__ C, int M, int N, int K, int MA, int relu)
{
    __shared__ __align__(16) __hip_bfloat16 Asl[128 * 64];
    __shared__ __align__(16) __hip_bfloat16 Bsl[128 * 64];
    int tid = threadIdx.x;
    int wid = tid >> 6, lane = tid & 63;
    int m0 = blockIdx.y << 7, n0 = blockIdx.x << 7;
    int wr = (wid >> 1) << 6, wc = (wid & 1) << 6;
    f32x4 acc[4][4] = {};
    int lr = lane >> 3, lk = (lane & 7) << 3;
    for (int kt = 0; kt < K; kt += 64) {
#pragma unroll
        for (int i = 0; i < 4; ++i) {
            int ch = wid * 4 + i;
            int rowA = m0 + ch * 8 + lr;
            rowA = rowA < MA ? rowA : (MA - 1);
            gload_lds16(A + (size_t)rowA * K + kt + lk, &Asl[ch * 512]);
            int rowB = n0 + ch * 8 + lr;
            gload_lds16(BT + (size_t)rowB * K + kt + lk, &Bsl[ch * 512]);
        }
        __syncthreads();
#pragma unroll
        for (int ks = 0; ks < 2; ++ks) {
            int kb = ks * 32 + (lane >> 4) * 8;
            bf16x8 af[4], bfr[4];
#pragma unroll
            for (int m = 0; m < 4; ++m)
                af[m] = *(const bf16x8*)&Asl[(wr + m * 16 + (lane & 15)) * 64 + kb];
#pragma unroll
            for (int n = 0; n < 4; ++n)
                bfr[n] = *(const bf16x8*)&Bsl[(wc + n * 16 + (lane & 15)) * 64 + kb];
#pragma unroll
            for (int m = 0; m < 4; ++m)
#pragma unroll
                for (int n = 0; n < 4; ++n)
                    acc[m][n] = __builtin_amdgcn_mfma_f32_16x16x32_bf16(
                        af[m], bfr[n], acc[m][n], 0, 0, 0);
        }
        __syncthreads();
    }
    int cr = (lane >> 4) << 2, cc = lane & 15;
#pragma unroll
    for (int m = 0; m < 4; ++m) {
#pragma unroll
        for (int i = 0; i < 4; ++i) {
            int gm = m0 + wr + m * 16 + cr + i;
            if (gm >= M) continue;
#pragma unroll
            for (int n = 0; n < 4; ++n) {
                int gn = n0 + wc + n * 16 + cc;
                float v = acc[m][n][i];
                if (bias) v += bias[gn];
                if (Cacc) v += Cacc[(size_t)gm * N + gn];
                if (relu) v = fmaxf(v, 0.f);
                C[(size_t)gm * N + gn] = v;
            }
        }
    }
}

// ---------------- fp32 [KxN] -> bf16 [NxK] tiled transpose-convert
__global__ __launch_bounds__(256) void transcvt_k(const float* __restrict__ W,
    __hip_bfloat16* __restrict__ WT, int K, int N)
{
    __shared__ float t[32][33];
    int nt = N >> 5;
    int n0 = (blockIdx.x % nt) << 5, k0 = (blockIdx.x / nt) << 5;
    int tx = threadIdx.x & 31, ty = threadIdx.x >> 5;
    for (int r = ty; r < 32; r += 8) t[r][tx] = W[(size_t)(k0 + r) * N + n0 + tx];
    __syncthreads();
    for (int r = ty; r < 32; r += 8)
        WT[(size_t)(n0 + r) * K + k0 + tx] = __float2bfloat16(t[tx][r]);
}

// ---------------- fp32 -> bf16 convert (vectorized)
__global__ __launch_bounds__(256) void cvt_k(const float4* __restrict__ in,
    ushort4* __restrict__ out, int n4)
{
    int i = blockIdx.x * 256 + threadIdx.x;
    if (i >= n4) return;
    float4 v = in[i];
    union { __hip_bfloat16 h[4]; ushort4 u; } cv;
    cv.h[0] = __float2bfloat16(v.x); cv.h[1] = __float2bfloat16(v.y);
    cv.h[2] = __float2bfloat16(v.z); cv.h[3] = __float2bfloat16(v.w);
    out[i] = cv.u;
}

// ---------------- batched per-head GEMM: D = alpha*(c1*A - A@B) + delta*I
// If DT non-null: instead store bf16 transposed DT[h][gc*256+gr] (for wmT16).
__global__ __launch_bounds__(256) void mm256_k(
    const float* __restrict__ A, const float* __restrict__ B, float* __restrict__ D,
    __hip_bfloat16* __restrict__ DT, int N, float c1, float alpha, float delta)
{
    __shared__ __align__(16) float As[16][68];
    __shared__ __align__(16) float Bs[16][64];
    int h = blockIdx.z;
    const float* Ah = A + ((size_t)h << 16);
    const float* Bh = B + (size_t)h * 256 * N;
    float* Dh = D + (size_t)h * 256 * N;
    int tx = threadIdx.x & 15, ty = threadIdx.x >> 4;
    int m0 = blockIdx.y << 6, n0 = blockIdx.x << 6;
    int lb_n = threadIdx.x & 63, lb_k = threadIdx.x >> 6;
    float acc[4][4] = {};
    for (int kt = 0; kt < 256; kt += 16) {
#pragma unroll
        for (int i = 0; i < 4; ++i)
            As[tx][ty + 16 * i] = Ah[(size_t)(m0 + ty + 16 * i) * 256 + kt + tx];
#pragma unroll
        for (int i = 0; i < 4; ++i)
            Bs[lb_k + 4 * i][lb_n] = Bh[(size_t)(kt + lb_k + 4 * i) * N + n0 + lb_n];
        __syncthreads();
#pragma unroll
        for (int kk = 0; kk < 16; ++kk) {
            float4 av = *(const float4*)&As[kk][ty * 4];
            float4 bv = *(const float4*)&Bs[kk][tx * 4];
            float a_[4] = { av.x, av.y, av.z, av.w };
            float b_[4] = { bv.x, bv.y, bv.z, bv.w };
#pragma unroll
            for (int i = 0; i < 4; ++i)
#pragma unroll
                for (int j = 0; j < 4; ++j) acc[i][j] += a_[i] * b_[j];
        }
        __syncthreads();
    }
#pragma unroll
    for (int i = 0; i < 4; ++i)
#pragma unroll
        for (int j = 0; j < 4; ++j) {
            int gr = m0 + ty * 4 + i, gc = n0 + tx * 4 + j;
            float cv = -alpha * acc[i][j];
            if (c1 != 0.f) cv += alpha * c1 * Ah[(size_t)gr * 256 + gc];
            if (gr == gc) cv += delta;
            if (DT) DT[((size_t)h << 14) + (size_t)gc * 256 + gr] = __float2bfloat16(cv);
            else Dh[(size_t)gr * N + gc] = cv;
        }
}

// ---------------- LayerNorm per row (512) -> bf16 out, one wave per row
__global__ __launch_bounds__(64) void ln_k(const float* __restrict__ in,
    const float* __restrict__ g, const float* __restrict__ b,
    __hip_bfloat16* __restrict__ out, int rows)
{
    int r = blockIdx.x;
    if (r >= rows) return;
    int lane = threadIdx.x;
    const float* xr = in + (size_t)r * DIMF;
    float v[8], s = 0.f;
#pragma unroll
    for (int i = 0; i < 8; ++i) { v[i] = xr[i * 64 + lane]; s += v[i]; }
#pragma unroll
    for (int off = 32; off; off >>= 1) s += __shfl_xor(s, off);
    float mu = s * (1.f / 512.f);
    float vs = 0.f;
#pragma unroll
    for (int i = 0; i < 8; ++i) { float d = v[i] - mu; vs += d * d; }
#pragma unroll
    for (int off = 32; off; off >>= 1) vs += __shfl_xor(vs, off);
    float rstd = rsqrtf(vs * (1.f / 512.f) + 1e-5f);
    __hip_bfloat16* orow = out + (size_t)r * DIMF;
#pragma unroll
    for (int i = 0; i < 8; ++i) {
        int d = i * 64 + lane;
        orow[d] = __float2bfloat16((v[i] - mu) * rstd * g[d] + b[d]);
    }
}

// ---------------- landmark means; ql scaled by DH^-0.5; kl16 bf16 copy [h][j][d]
__global__ __launch_bounds__(64) void landmark_k(const float* __restrict__ qkvb,
    float* __restrict__ ql, float* __restrict__ kl, __hip_bfloat16* __restrict__ kl16)
{
    int bx = blockIdx.x;
    int h = bx >> 8, j = bx & 255;
    int d = threadIdx.x;
    float qs = 0.f, ks = 0.f;
    for (int u = 0; u < LSEG; ++u) {
        size_t addr = (size_t)(j * LSEG + u) * QKVW + (h << 6) + d;
        qs += qkvb[addr];
        ks += qkvb[addr + 512];
    }
    float qm = qs * (1.f / 65.f) * 0.125f;
    float km = ks * (1.f / 65.f);
    ql[(size_t)bx * 64 + d] = qm;
    kl[(size_t)bx * 64 + d] = km;
    kl16[(size_t)bx * 64 + d] = __float2bfloat16(km);
}

// ---------------- a2 = softmax(q_l @ k_l^T) rows; block per (h,i)
__global__ __launch_bounds__(256) void a2_k(const float* __restrict__ ql,
    const float* __restrict__ kl, float* __restrict__ a2)
{
    int h = blockIdx.x >> 8, i = blockIdx.x & 255;
    int j = threadIdx.x;
    __shared__ float qs[64];
    __shared__ float red[256];
    if (j < 64) qs[j] = ql[((size_t)(h << 8) + i) * 64 + j];
    __syncthreads();
    const float* kr = kl + ((size_t)(h << 8) + j) * 64;
    float s = 0.f;
#pragma unroll 8
    for (int d = 0; d < 64; ++d) s += qs[d] * kr[d];
    red[j] = s; __syncthreads();
    for (int st = 128; st; st >>= 1) { if (j < st) red[j] = fmaxf(red[j], red[j + st]); __syncthreads(); }
    float mx = red[0]; __syncthreads();
    float p = __expf(s - mx);
    red[j] = p; __syncthreads();
    for (int st = 128; st; st >>= 1) { if (j < st) red[j] += red[j + st]; __syncthreads(); }
    a2[((size_t)h << 16) + i * 256 + j] = p / red[0];
}

// ---------------- pinv init: z = a2^T / (max_rowsum * max_colsum), per head
__global__ __launch_bounds__(256) void zinit_k(const float* __restrict__ a2, float* __restrict__ z)
{
    int h = blockIdx.x, t = threadIdx.x;
    const float* X = a2 + ((size_t)h << 16);
    __shared__ float red[256];
    float rs = 0.f;
    for (int j = 0; j < 256; ++j) rs += fabsf(X[t * 256 + j]);
    red[t] = rs; __syncthreads();
    for (int st = 128; st; st >>= 1) { if (t < st) red[t] = fmaxf(red[t], red[t + st]); __syncthreads(); }
    float colv = red[0]; __syncthreads();
    float cs = 0.f;
    for (int i = 0; i < 256; ++i) cs += fabsf(X[i * 256 + t]);
    red[t] = cs; __syncthreads();
    for (int st = 128; st; st >>= 1) { if (t < st) red[t] = fmaxf(red[t], red[t + st]); __syncthreads(); }
    float rowv = red[0];
    float inv = 1.f / (colv * rowv);
    for (int e = t; e < 65536; e += 256) {
        int i = e >> 8, j = e & 255;
        z[((size_t)h << 16) + e] = X[j * 256 + i] * inv;
    }
}

// ---------------- flash-style a3v partials: per (h, 32-landmark block, t-chunk)
__global__ __launch_bounds__(256) void a3v_part_k(
    const float* __restrict__ ql, const float* __restrict__ qkvb,
    float* __restrict__ opart, float* __restrict__ mpart, float* __restrict__ lpart)
{
    int pb = blockIdx.x;
    int h = pb >> 3, ib = pb & 7;
    int tc = blockIdx.y;
    __shared__ __align__(16) float qc[32][66];
    __shared__ __align__(16) float ktT[64][68];
    __shared__ __align__(16) float vt[64][68];
    __shared__ float sb[32][65];
    __shared__ float pm[32][8];
    __shared__ float mrow[32], lrow[32], fac[32];
    int tid = threadIdx.x;
    for (int e = tid; e < 2048; e += 256) {
        int r = e >> 6, d = e & 63;
        qc[r][d] = ql[((size_t)(h << 8) + (ib << 5) + r) * 64 + d];
    }
    if (tid < 32) { mrow[tid] = -3e38f; lrow[tid] = 0.f; }
    int tx = tid & 15, ty = tid >> 4;
    int m0 = ty * 2, n0 = tx * 4;
    float oa0[4] = {}, oa1[4] = {};
    __syncthreads();
    for (int tile = tc * 26; tile < tc * 26 + 26; ++tile) {
        int t0 = tile * 64;
        for (int e = tid; e < 4096; e += 256) {
            int tt = e >> 6, d = e & 63;
            size_t ga = (size_t)(t0 + tt) * QKVW + 512 + (h << 6) + d;
            ktT[d][tt] = qkvb[ga];
            vt[tt][d] = qkvb[ga + 512];
        }
        __syncthreads();
        {
            float c0[4] = {}, c1[4] = {};
#pragma unroll 16
            for (int kk = 0; kk < 64; ++kk) {
                float a0 = qc[m0][kk], a1 = qc[m0 + 1][kk];
                float4 b4 = *(const float4*)&ktT[kk][n0];
                c0[0] += a0 * b4.x; c0[1] += a0 * b4.y; c0[2] += a0 * b4.z; c0[3] += a0 * b4.w;
                c1[0] += a1 * b4.x; c1[1] += a1 * b4.y; c1[2] += a1 * b4.z; c1[3] += a1 * b4.w;
            }
#pragma unroll
            for (int j = 0; j < 4; ++j) { sb[m0][n0 + j] = c0[j]; sb[m0 + 1][n0 + j] = c1[j]; }
        }
        __syncthreads();
        int r_ = tid >> 3, seg = tid & 7;
        float lmax = -3e38f;
#pragma unroll
        for (int q = 0; q < 8; ++q) lmax = fmaxf(lmax, sb[r_][seg * 8 + q]);
        pm[r_][seg] = lmax;
        __syncthreads();
        if (tid < 32) {
            float mt = pm[tid][0];
#pragma unroll
            for (int s2 = 1; s2 < 8; ++s2) mt = fmaxf(mt, pm[tid][s2]);
            float mn = fmaxf(mrow[tid], mt);
            fac[tid] = __expf(mrow[tid] - mn);
            mrow[tid] = mn;
        }
        __syncthreads();
        float lsum = 0.f;
#pragma unroll
        for (int q = 0; q < 8; ++q) {
            float p = __expf(sb[r_][seg * 8 + q] - mrow[r_]);
            sb[r_][seg * 8 + q] = p;
            lsum += p;
        }
        pm[r_][seg] = lsum;
        __syncthreads();
        if (tid < 32) {
            float s_ = 0.f;
#pragma unroll
            for (int s2 = 0; s2 < 8; ++s2) s_ += pm[tid][s2];
            lrow[tid] = lrow[tid] * fac[tid] + s_;
        }
        float f0 = fac[m0], f1 = fac[m0 + 1];
#pragma unroll
        for (int j = 0; j < 4; ++j) { oa0[j] *= f0; oa1[j] *= f1; }
#pragma unroll 16
        for (int kk = 0; kk < 64; ++kk) {
            float a0 = sb[m0][kk], a1 = sb[m0 + 1][kk];
            float4 b4 = *(const float4*)&vt[kk][n0];
            oa0[0] += a0 * b4.x; oa0[1] += a0 * b4.y; oa0[2] += a0 * b4.z; oa0[3] += a0 * b4.w;
            oa1[0] += a1 * b4.x; oa1[1] += a1 * b4.y; oa1[2] += a1 * b4.z; oa1[3] += a1 * b4.w;
        }
        __syncthreads();
    }
    size_t base = ((size_t)pb * A3V_TC + tc) * 2048;
    *(float4*)&opart[base + (size_t)m0 * 64 + n0] = make_float4(oa0[0], oa0[1], oa0[2], oa0[3]);
    *(float4*)&opart[base + (size_t)(m0 + 1) * 64 + n0] = make_float4(oa1[0], oa1[1], oa1[2], oa1[3]);
    if (tid < 32) {
        mpart[((size_t)pb * A3V_TC + tc) * 32 + tid] = mrow[tid];
        lpart[((size_t)pb * A3V_TC + tc) * 32 + tid] = lrow[tid];
    }
}

__global__ __launch_bounds__(64) void a3v_comb_k(const float* __restrict__ opart,
    const float* __restrict__ mpart, const float* __restrict__ lpart, float* __restrict__ a3v)
{
    int pb = blockIdx.x, d = threadIdx.x;
    for (int r = 0; r < 32; ++r) {
        float M = -3e38f;
        for (int tc = 0; tc < A3V_TC; ++tc)
            M = fmaxf(M, mpart[((size_t)pb * A3V_TC + tc) * 32 + r]);
        float L = 0.f, od = 0.f;
        for (int tc = 0; tc < A3V_TC; ++tc) {
            float w = __expf(mpart[((size_t)pb * A3V_TC + tc) * 32 + r] - M);
            L += lpart[((size_t)pb * A3V_TC + tc) * 32 + r] * w;
            od += w * opart[((size_t)pb * A3V_TC + tc) * 2048 + (size_t)r * 64 + d];
        }
        a3v[((size_t)pb * 32 + r) * 64 + d] = od / L;
    }
}

// ---------------- MFMA fused sim1-softmax @ Wm.
// Block = 64 query rows x 1 head; 2 waves x 32 rows. S in regs (exact softmax),
// P -> swizzled wave-private LDS (bf16), PV via mfma with wmT16 (global, L2).
__global__ __launch_bounds__(128) void attnout_mfma_k(
    const float* __restrict__ qkvb, const __hip_bfloat16* __restrict__ kl16,
    const __hip_bfloat16* __restrict__ wmT16, float* __restrict__ o)
{
    int h = blockIdx.y;
    int rbase = (blockIdx.x << 6) + ((threadIdx.x >> 6) << 5);
    int lane = threadIdx.x & 63;
    int rA = lane & 15;            // frag row index
    int g = lane >> 4;             // k-pack group
    int kp = g << 3;
    __shared__ __align__(16) __hip_bfloat16 Plds[2][32 * 256];
    char* P = (char*)&Plds[threadIdx.x >> 6][0];

    // q a-frags (scaled), from fp32 global
    bf16x8 qa[2][2];
#pragma unroll
    for (int m = 0; m < 2; ++m)
#pragma unroll
        for (int ks = 0; ks < 2; ++ks) {
            const float* qp = qkvb + (size_t)(rbase + m * 16 + rA) * QKVW + (h << 6) + ks * 32 + kp;
            float4 v0 = *(const float4*)qp;
            float4 v1 = *(const float4*)(qp + 4);
            union { __hip_bfloat16 hh[8]; bf16x8 v; } cv;
            cv.hh[0] = __float2bfloat16(v0.x * 0.125f); cv.hh[1] = __float2bfloat16(v0.y * 0.125f);
            cv.hh[2] = __float2bfloat16(v0.z * 0.125f); cv.hh[3] = __float2bfloat16(v0.w * 0.125f);
            cv.hh[4] = __float2bfloat16(v1.x * 0.125f); cv.hh[5] = __float2bfloat16(v1.y * 0.125f);
            cv.hh[6] = __float2bfloat16(v1.z * 0.125f); cv.hh[7] = __float2bfloat16(v1.w * 0.125f);
            qa[m][ks] = cv.v;
        }

    // scores S[2m][16n]: q @ kl^T
    const __hip_bfloat16* klh = kl16 + ((size_t)h << 14);
    f32x4 S[2][16] = {};
#pragma unroll
    for (int n = 0; n < 16; ++n) {
#pragma unroll
        for (int ks = 0; ks < 2; ++ks) {
            bf16x8 kb = *(const bf16x8*)(klh + (size_t)((n << 4) + rA) * 64 + ks * 32 + kp);
            S[0][n] = __builtin_amdgcn_mfma_f32_16x16x32_bf16(qa[0][ks], kb, S[0][n], 0, 0, 0);
            S[1][n] = __builtin_amdgcn_mfma_f32_16x16x32_bf16(qa[1][ks], kb, S[1][n], 0, 0, 0);
        }
    }

    // exact softmax per row; write unnormalized P (bf16) to swizzled LDS
    float lsum[2][4];
#pragma unroll
    for (int m = 0; m < 2; ++m)
#pragma unroll
        for (int i = 0; i < 4; ++i) {
            float mx = -3e38f;
#pragma unroll
            for (int n = 0; n < 16; ++n) mx = fmaxf(mx, S[m][n][i]);
#pragma unroll
            for (int msk = 8; msk; msk >>= 1) mx = fmaxf(mx, __shfl_xor(mx, msk));
            float sum = 0.f;
            int r = (m << 4) + (g << 2) + i;
            int swz = (r & 7) << 4;
#pragma unroll
            for (int n = 0; n < 16; ++n) {
                float p = __expf(S[m][n][i] - mx);
                sum += p;
                int byte = (r << 9) + (((n << 4) + rA) << 1);
                *(__hip_bfloat16*)(P + (byte ^ swz)) = __float2bfloat16(p);
            }
#pragma unroll
            for (int msk = 8; msk; msk >>= 1) sum += __shfl_xor(sum, msk);
            lsum[m][i] = sum;
        }

    // PV: O[2m][4n] = P(32x256) @ Wm(256x64), B-frags from wmT16 (global/L2)
    const __hip_bfloat16* wmh = wmT16 + ((size_t)h << 14);
    f32x4 O[2][4] = {};
#pragma unroll
    for (int kc = 0; kc < 8; ++kc) {
        bf16x8 pa[2];
#pragma unroll
        for (int m = 0; m < 2; ++m) {
            int rr = (m << 4) + rA;
            int byte = (rr << 9) + (((kc << 5) + kp) << 1);
            pa[m] = *(const bf16x8*)(P + (byte ^ ((rr & 7) << 4)));
        }
#pragma unroll
        for (int n = 0; n < 4; ++n) {
            bf16x8 wb = *(const bf16x8*)(wmh + (size_t)((n << 4) + rA) * 256 + (kc << 5) + kp);
#pragma unroll
            for (int m = 0; m < 2; ++m)
                O[m][n] = __builtin_amdgcn_mfma_f32_16x16x32_bf16(pa[m], wb, O[m][n], 0, 0, 0);
        }
    }
#pragma unroll
    for (int m = 0; m < 2; ++m)
#pragma unroll
        for (int i = 0; i < 4; ++i) {
            float inv = 1.f / lsum[m][i];
            int gm = rbase + (m << 4) + (g << 2) + i;
#pragma unroll
            for (int n = 0; n < 4; ++n)
                o[(size_t)gm * DIMF + (h << 6) + (n << 4) + rA] = O[m][n][i] * inv;
        }
}

// ---------------- resconv (33-tap along seq) + convert to bf16: out = oin + conv
__global__ __launch_bounds__(256) void resconv_tile_k(const float* __restrict__ qkvb,
    const float* __restrict__ rw, const float* __restrict__ oin,
    __hip_bfloat16* __restrict__ oout)
{
    int cg = blockIdx.y;
    int t0 = blockIdx.x << 7;
    int tid = threadIdx.x;
    int lane = tid & 63, w = tid >> 6;
    __shared__ float vt[160][64];
    __shared__ float wr[33];
    if (tid < 33) wr[tid] = rw[cg * 33 + tid];
    for (int e = tid; e < 160 * 64; e += 256) {
        int tt = e >> 6, l = e & 63;
        int t = t0 - 16 + tt;
        vt[tt][l] = (t >= 0 && t < NP) ? qkvb[(size_t)t * QKVW + 1024 + (cg << 6) + l] : 0.f;
    }
    __syncthreads();
    for (int i = 0; i < 32; ++i) {
        int tl = (w << 5) + i;
        float acc = 0.f;
#pragma unroll
        for (int ky = 0; ky < 33; ++ky) acc += wr[ky] * vt[tl + ky][lane];
        size_t oi = (size_t)(t0 + tl) * DIMF + (cg << 6) + lane;
        oout[oi] = __float2bfloat16(oin[oi] + acc);
    }
}

// ---------------- LDS-tiled PPEG
__global__ __launch_bounds__(256) void ppeg_tile_k(const float* __restrict__ x,
    const float* __restrict__ w7, const float* __restrict__ b7,
    const float* __restrict__ w5, const float* __restrict__ b5,
    const float* __restrict__ w3, const float* __restrict__ b3,
    float* __restrict__ tmp)
{
    int cg = blockIdx.y;
    int ty0 = (blockIdx.x >> 4) << 3, tx0 = (blockIdx.x & 15) << 3;
    int tid = threadIdx.x;
    int lane = tid & 63, w = tid >> 6;
    int cl = lane & 31, xh = lane >> 5;
    int c = (cg << 5) + cl;
    const float* feat = x + DIMF;
    __shared__ float tile[196][32];
    __shared__ float w7s[49 * 32];
    __shared__ float w5s[25 * 32];
    __shared__ float w3s[9 * 32];
    for (int e = tid; e < 49 * 32; e += 256) w7s[e] = w7[cg * (49 * 32) + e];
    for (int e = tid; e < 25 * 32; e += 256) w5s[e] = w5[cg * (25 * 32) + e];
    for (int e = tid; e < 9 * 32; e += 256)  w3s[e] = w3[cg * (9 * 32) + e];
    for (int e = tid; e < 196 * 32; e += 256) {
        int sp = e >> 5, l = e & 31;
        int yy = ty0 - 3 + sp / 14, xc = tx0 - 3 + sp % 14;
        float v = 0.f;
        if ((unsigned)yy < 128u && (unsigned)xc < 128u)
            v = feat[(size_t)(yy * 128 + xc) * DIMF + (cg << 5) + l];
        tile[sp][l] = v;
    }
    __syncthreads();
    float bsum = b7[c] + b5[c] + b3[c];
    int xo = (w << 1) + xh;
    for (int yb = 0; yb < 8; yb += 4) {
        float acc[4];
#pragma unroll
        for (int oidx = 0; oidx < 4; ++oidx)
            acc[oidx] = tile[(yb + oidx + 3) * 14 + xo + 3][cl] + bsum;
#pragma unroll
        for (int kx = 0; kx < 7; ++kx) {
            float wc[7];
#pragma unroll
            for (int j = 0; j < 7; ++j) wc[j] = w7s[cl * 49 + j * 7 + kx];
#pragma unroll
            for (int r = 0; r < 10; ++r) {
                float v = tile[(yb + r) * 14 + xo + kx][cl];
#pragma unroll
                for (int oidx = 0; oidx < 4; ++oidx) {
                    int ky = r - oidx;
                    if (ky >= 0 && ky < 7) acc[oidx] += wc[ky] * v;
                }
            }
        }
#pragma unroll
        for (int kx = 0; kx < 5; ++kx) {
            float wc[5];
#pragma unroll
            for (int j = 0; j < 5; ++j) wc[j] = w5s[cl * 25 + j * 5 + kx];
#pragma unroll
            for (int r = 0; r < 8; ++r) {
                float v = tile[(yb + 1 + r) * 14 + xo + 1 + kx][cl];
#pragma unroll
                for (int oidx = 0; oidx < 4; ++oidx) {
                    int ky = r - oidx;
                    if (ky >= 0 && ky < 5) acc[oidx] += wc[ky] * v;
                }
            }
        }
#pragma unroll
        for (int kx = 0; kx < 3; ++kx) {
            float wc[3];
#pragma unroll
            for (int j = 0; j < 3; ++j) wc[j] = w3s[cl * 9 + j * 3 + kx];
#pragma unroll
            for (int r = 0; r < 6; ++r) {
                float v = tile[(yb + 2 + r) * 14 + xo + 2 + kx][cl];
#pragma unroll
                for (int oidx = 0; oidx < 4; ++oidx) {
                    int ky = r - oidx;
                    if (ky >= 0 && ky < 3) acc[oidx] += wc[ky] * v;
                }
            }
        }
#pragma unroll
        for (int oidx = 0; oidx < 4; ++oidx)
            tmp[(size_t)((ty0 + yb + oidx) * 128 + tx0 + xo) * DIMF + c] = acc[oidx];
    }
}

// ---------------- final LN(row0) + 2-class head + softmax + argmax
__global__ __launch_bounds__(64) void head_k(const float* __restrict__ x,
    const float* __restrict__ g, const float* __restrict__ b,
    const float* __restrict__ w, const float* __restrict__ bias, float* __restrict__ out)
{
    int lane = threadIdx.x;
    float v[8], s = 0.f;
#pragma unroll
    for (int i = 0; i < 8; ++i) { v[i] = x[i * 64 + lane]; s += v[i]; }
#pragma unroll
    for (int off = 32; off; off >>= 1) s += __shfl_xor(s, off);
    float mu = s * (1.f / 512.f);
    float vs = 0.f;
#pragma unroll
    for (int i = 0; i < 8; ++i) { float d = v[i] - mu; vs += d * d; }
#pragma unroll
    for (int off = 32; off; off >>= 1) vs += __shfl_xor(vs, off);
    float rstd = rsqrtf(vs * (1.f / 512.f) + 1e-5f);
    float l0 = 0.f, l1 = 0.f;
#pragma unroll
    for (int i = 0; i < 8; ++i) {
        int d = i * 64 + lane;
        float hn = (v[i] - mu) * rstd * g[d] + b[d];
        l0 += hn * w[d * 2];
        l1 += hn * w[d * 2 + 1];
    }
#pragma unroll
    for (int off = 32; off; off >>= 1) { l0 += __shfl_xor(l0, off); l1 += __shfl_xor(l1, off); }
    if (lane == 0) {
        l0 += bias[0]; l1 += bias[1];
        float m = fmaxf(l0, l1);
        float e0 = __expf(l0 - m), e1 = __expf(l1 - m);
        float ss = e0 + e1;
        out[0] = l0; out[1] = l1;
        out[2] = e0 / ss; out[3] = e1 / ss;
        out[4] = (l1 > l0) ? 1.f : 0.f;
    }
}

extern "C" void kernel_launch(void* const* d_in, const int* in_sizes, int n_in,
                              void* d_out, int out_size, void* d_ws, size_t ws_size,
                              hipStream_t stream)
{
    (void)in_sizes; (void)n_in; (void)out_size; (void)ws_size;
    const float* data   = (const float*)d_in[0];
    const float* fc1_w  = (const float*)d_in[1];
    const float* fc1_b  = (const float*)d_in[2];
    const float* cls    = (const float*)d_in[3];
    const float* l1_ng  = (const float*)d_in[4];
    const float* l1_nb  = (const float*)d_in[5];
    const float* l1_qkv = (const float*)d_in[6];
    const float* l1_ow  = (const float*)d_in[7];
    const float* l1_ob  = (const float*)d_in[8];
    const float* l1_rw  = (const float*)d_in[9];
    const float* l2_ng  = (const float*)d_in[10];
    const float* l2_nb  = (const float*)d_in[11];
    const float* l2_qkv = (const float*)d_in[12];
    const float* l2_ow  = (const float*)d_in[13];
    const float* l2_ob  = (const float*)d_in[14];
    const float* l2_rw  = (const float*)d_in[15];
    const float* p_w7   = (const float*)d_in[16];
    const float* p_b7   = (const float*)d_in[17];
    const float* p_w5   = (const float*)d_in[18];
    const float* p_b5   = (const float*)d_in[19];
    const float* p_w3   = (const float*)d_in[20];
    const float* p_b3   = (const float*)d_in[21];
    const float* n_g    = (const float*)d_in[22];
    const float* n_b    = (const float*)d_in[23];
    const float* fc2_w  = (const float*)d_in[24];
    const float* fc2_b  = (const float*)d_in[25];

    char* base = (char*)d_ws;
    auto carve = [&](size_t bytes) { char* p = base; base += (bytes + 255) & ~(size_t)255; return p; };
    float* x              = (float*)carve((size_t)NT * DIMF * 4);
    __hip_bfloat16* xp16  = (__hip_bfloat16*)carve((size_t)NP * DIMF * 2);   // aliased as obuf2
    float* qkvb           = (float*)carve((size_t)NP * QKVW * 4);            // aliased as data16 in stem
    float* obuf           = (float*)carve((size_t)NP * DIMF * 4);
    __hip_bfloat16* wT    = (__hip_bfloat16*)carve((size_t)QKVW * DIMF * 2);
    float* ql    = (float*)carve(131072 * 4);
    float* kl    = (float*)carve(131072 * 4);
    __hip_bfloat16* kl16  = (__hip_bfloat16*)carve(131072 * 2);
    __hip_bfloat16* wmT16 = (__hip_bfloat16*)carve(131072 * 2);
    float* a2    = (float*)carve(524288 * 4);
    float* zb    = (float*)carve(524288 * 4);
    float* z2    = (float*)carve(524288 * 4);
    float* xz    = (float*)carve(524288 * 4);
    float* ta    = (float*)carve(524288 * 4);
    float* tb    = (float*)carve(524288 * 4);
    float* a3v   = (float*)carve(131072 * 4);
    float* wm    = (float*)carve(131072 * 4);
    float* opart = (float*)carve((size_t)64 * A3V_TC * 2048 * 4);
    float* mpart = (float*)carve((size_t)64 * A3V_TC * 32 * 4);
    float* lpart = (float*)carve((size_t)64 * A3V_TC * 32 * 4);
    __hip_bfloat16* obuf2 = xp16;                     // lifetime-disjoint alias
    __hip_bfloat16* data16 = (__hip_bfloat16*)qkvb;   // stem-only alias

    // ---- stem: x[0]=cls; x[1..] = relu(data @ fc1_w + fc1_b), via bf16 MFMA
    cvt_k<<<(16384 * 1024 / 4 + 255) / 256, 256, 0, stream>>>(
        (const float4*)data, (ushort4*)data16, 16384 * 1024 / 4);
    transcvt_k<<<(DIMF / 32) * (1024 / 32), 256, 0, stream>>>(fc1_w, wT, 1024, DIMF);
    gemm_bf16_k<<<dim3(DIMF / 128, 16384 / 128), 256, 0, stream>>>(
        data16, wT, fc1_b, nullptr, x + DIMF, 16384, DIMF, 1024, 16384, 1);
    hipMemcpyAsync(x, cls, DIMF * sizeof(float), hipMemcpyDeviceToDevice, stream);

    auto layer = [&](const float* ng, const float* nb, const float* qw,
                     const float* ow, const float* ob, const float* rw) {
        hipMemsetAsync(xp16, 0, (size_t)PADR * DIMF * 2, stream);
        ln_k<<<NT, 64, 0, stream>>>(x, ng, nb, xp16 + (size_t)PADR * DIMF, NT);
        transcvt_k<<<(QKVW / 32) * (DIMF / 32), 256, 0, stream>>>(qw, wT, DIMF, QKVW);
        gemm_bf16_k<<<dim3(QKVW / 128, NP / 128), 256, 0, stream>>>(
            xp16, wT, nullptr, nullptr, qkvb, NP, QKVW, DIMF, NP, 0);
        landmark_k<<<NHEAD * NLM, 64, 0, stream>>>(qkvb, ql, kl, kl16);
        a2_k<<<NHEAD * NLM, 256, 0, stream>>>(ql, kl, a2);
        zinit_k<<<NHEAD, 256, 0, stream>>>(a2, zb);
        float* zc = zb; float* zn = z2;
        for (int it = 0; it < 6; ++it) {
            mm256_k<<<dim3(4, 4, NHEAD), 256, 0, stream>>>(a2, zc, xz, nullptr, 256, 0.f, -1.f, 0.f);
            mm256_k<<<dim3(4, 4, NHEAD), 256, 0, stream>>>(xz, xz, ta, nullptr, 256, 7.f, -1.f, 15.f);
            mm256_k<<<dim3(4, 4, NHEAD), 256, 0, stream>>>(xz, ta, tb, nullptr, 256, 0.f, 1.f, 13.f);
            mm256_k<<<dim3(4, 4, NHEAD), 256, 0, stream>>>(zc, tb, zn, nullptr, 256, 0.f, -0.25f, 0.f);
            float* sw = zc; zc = zn; zn = sw;
        }
        a3v_part_k<<<dim3(64, A3V_TC), 256, 0, stream>>>(ql, qkvb, opart, mpart, lpart);
        a3v_comb_k<<<64, 64, 0, stream>>>(opart, mpart, lpart, a3v);
        // wmT16[h][d][j] = bf16( (pinv @ a3v)^T )
        mm256_k<<<dim3(1, 4, NHEAD), 256, 0, stream>>>(zc, a3v, wm, wmT16, 64, 0.f, -1.f, 0.f);
        attnout_mfma_k<<<dim3(NP / 64, NHEAD), 128, 0, stream>>>(qkvb, kl16, wmT16, obuf);
        resconv_tile_k<<<dim3(NP / 128, NHEAD), 256, 0, stream>>>(qkvb, rw, obuf, obuf2);
        transcvt_k<<<(DIMF / 32) * (DIMF / 32), 256, 0, stream>>>(ow, wT, DIMF, DIMF);
        gemm_bf16_k<<<dim3(DIMF / 128, (NT + 127) / 128), 256, 0, stream>>>(
            obuf2 + (size_t)PADR * DIMF, wT, ob, x, x, NT, DIMF, DIMF, NT, 0);
    };

    layer(l1_ng, l1_nb, l1_qkv, l1_ow, l1_ob, l1_rw);

    ppeg_tile_k<<<dim3(256, 16), 256, 0, stream>>>(x, p_w7, p_b7, p_w5, p_b5, p_w3, p_b3, obuf);
    hipMemcpyAsync(x + DIMF, obuf, (size_t)16384 * DIMF * sizeof(float),
                   hipMemcpyDeviceToDevice, stream);

    layer(l2_ng, l2_nb, l2_qkv, l2_ow, l2_ob, l2_rw);

    head_k<<<1, 64, 0, stream>>>(x, n_g, n_b, fc2_w, fc2_b, (float*)d_out);
}

// Round 5
// 1932.065 us; speedup vs baseline: 3.5635x; 1.1792x over previous
//
#include <hip/hip_runtime.h>
#include <hip/hip_bf16.h>

// TransMIL forward. Round 5: MFMA flash a3v (replaces VALU a3v_part),
// bf16 qkv buffer end-to-end, MFMA attnout, bf16 MFMA big GEMMs, fp32 pinv.

#define NT 16385
#define NP 16640
#define PADR 255
#define DIMF 512
#define QKVW 1536
#define NHEAD 8
#define DH 64
#define NLM 256
#define LSEG 65
#define A3V_TC 20   // t-chunks (260 tiles / 20 = 13 per chunk)

typedef short bf16x8 __attribute__((ext_vector_type(8)));
typedef float f32x4 __attribute__((ext_vector_type(4)));

__device__ __forceinline__ void gload_lds16(const void* g, void* l) {
    __builtin_amdgcn_global_load_lds(
        (const __attribute__((address_space(1))) void*)g,
        (__attribute__((address_space(3))) void*)l, 16, 0, 0);
}

// ---------------- bf16 MFMA GEMM: C = A[MxK]@BT[NxK]^T + bias (+Cacc)(+relu)
// Output fp32 C, or bf16 C16 if non-null.
__global__ __launch_bounds__(256) void gemm_bf16_k(
    const __hip_bfloat16* __restrict__ A, const __hip_bfloat16* __restrict__ BT,
    const float* __restrict__ bias, const float* __restrict__ Cacc,
    float* __restrict__ C, __hip_bfloat16* __restrict__ C16,
    int M, int N, int K, int MA, int relu)
{
    __shared__ __align__(16) __hip_bfloat16 Asl[128 * 64];
    __shared__ __align__(16) __hip_bfloat16 Bsl[128 * 64];
    int tid = threadIdx.x;
    int wid = tid >> 6, lane = tid & 63;
    int m0 = blockIdx.y << 7, n0 = blockIdx.x << 7;
    int wr = (wid >> 1) << 6, wc = (wid & 1) << 6;
    f32x4 acc[4][4] = {};
    int lr = lane >> 3, lk = (lane & 7) << 3;
    for (int kt = 0; kt < K; kt += 64) {
#pragma unroll
        for (int i = 0; i < 4; ++i) {
            int ch = wid * 4 + i;
            int rowA = m0 + ch * 8 + lr;
            rowA = rowA < MA ? rowA : (MA - 1);
            gload_lds16(A + (size_t)rowA * K + kt + lk, &Asl[ch * 512]);
            int rowB = n0 + ch * 8 + lr;
            gload_lds16(BT + (size_t)rowB * K + kt + lk, &Bsl[ch * 512]);
        }
        __syncthreads();
#pragma unroll
        for (int ks = 0; ks < 2; ++ks) {
            int kb = ks * 32 + (lane >> 4) * 8;
            bf16x8 af[4], bfr[4];
#pragma unroll
            for (int m = 0; m < 4; ++m)
                af[m] = *(const bf16x8*)&Asl[(wr + m * 16 + (lane & 15)) * 64 + kb];
#pragma unroll
            for (int n = 0; n < 4; ++n)
                bfr[n] = *(const bf16x8*)&Bsl[(wc + n * 16 + (lane & 15)) * 64 + kb];
#pragma unroll
            for (int m = 0; m < 4; ++m)
#pragma unroll
                for (int n = 0; n < 4; ++n)
                    acc[m][n] = __builtin_amdgcn_mfma_f32_16x16x32_bf16(
                        af[m], bfr[n], acc[m][n], 0, 0, 0);
        }
        __syncthreads();
    }
    int cr = (lane >> 4) << 2, cc = lane & 15;
#pragma unroll
    for (int m = 0; m < 4; ++m) {
#pragma unroll
        for (int i = 0; i < 4; ++i) {
            int gm = m0 + wr + m * 16 + cr + i;
            if (gm >= M) continue;
#pragma unroll
            for (int n = 0; n < 4; ++n) {
                int gn = n0 + wc + n * 16 + cc;
                float v = acc[m][n][i];
                if (bias) v += bias[gn];
                if (Cacc) v += Cacc[(size_t)gm * N + gn];
                if (relu) v = fmaxf(v, 0.f);
                if (C16) C16[(size_t)gm * N + gn] = __float2bfloat16(v);
                else C[(size_t)gm * N + gn] = v;
            }
        }
    }
}

// ---------------- fp32 [KxN] -> bf16 [NxK] tiled transpose-convert
__global__ __launch_bounds__(256) void transcvt_k(const float* __restrict__ W,
    __hip_bfloat16* __restrict__ WT, int K, int N)
{
    __shared__ float t[32][33];
    int nt = N >> 5;
    int n0 = (blockIdx.x % nt) << 5, k0 = (blockIdx.x / nt) << 5;
    int tx = threadIdx.x & 31, ty = threadIdx.x >> 5;
    for (int r = ty; r < 32; r += 8) t[r][tx] = W[(size_t)(k0 + r) * N + n0 + tx];
    __syncthreads();
    for (int r = ty; r < 32; r += 8)
        WT[(size_t)(n0 + r) * K + k0 + tx] = __float2bfloat16(t[tx][r]);
}

// ---------------- fp32 -> bf16 convert (vectorized)
__global__ __launch_bounds__(256) void cvt_k(const float4* __restrict__ in,
    ushort4* __restrict__ out, int n4)
{
    int i = blockIdx.x * 256 + threadIdx.x;
    if (i >= n4) return;
    float4 v = in[i];
    union { __hip_bfloat16 h[4]; ushort4 u; } cv;
    cv.h[0] = __float2bfloat16(v.x); cv.h[1] = __float2bfloat16(v.y);
    cv.h[2] = __float2bfloat16(v.z); cv.h[3] = __float2bfloat16(v.w);
    out[i] = cv.u;
}

// ---------------- v transpose: vT16[h][d][t] = qkvb16[t][1024+h*64+d]
__global__ __launch_bounds__(256) void vtrans_k(const __hip_bfloat16* __restrict__ qkvb16,
    __hip_bfloat16* __restrict__ vT16)
{
    int h = blockIdx.y;
    int t0 = blockIdx.x << 6;
    __shared__ float tile[64][65];
    int tid = threadIdx.x;
    for (int e = tid; e < 512; e += 256) {
        int r = e >> 3, c8 = (e & 7) << 3;
        union { bf16x8 v; __hip_bfloat16 hh[8]; } u;
        u.v = *(const bf16x8*)(qkvb16 + (size_t)(t0 + r) * QKVW + 1024 + (h << 6) + c8);
#pragma unroll
        for (int j = 0; j < 8; ++j) tile[r][c8 + j] = __bfloat162float(u.hh[j]);
    }
    __syncthreads();
    for (int e = tid; e < 512; e += 256) {
        int d = e >> 3, t8 = (e & 7) << 3;
        union { bf16x8 v; __hip_bfloat16 hh[8]; } u;
#pragma unroll
        for (int j = 0; j < 8; ++j) u.hh[j] = __float2bfloat16(tile[t8 + j][d]);
        *(bf16x8*)(vT16 + ((size_t)(h << 6) + d) * NP + t0 + t8) = u.v;
    }
}

// ---------------- batched per-head GEMM: D = alpha*(c1*A - A@B) + delta*I
// If DT non-null: store bf16 transposed DT[h][gc*256+gr] (for wmT16).
__global__ __launch_bounds__(256) void mm256_k(
    const float* __restrict__ A, const float* __restrict__ B, float* __restrict__ D,
    __hip_bfloat16* __restrict__ DT, int N, float c1, float alpha, float delta)
{
    __shared__ __align__(16) float As[16][68];
    __shared__ __align__(16) float Bs[16][64];
    int h = blockIdx.z;
    const float* Ah = A + ((size_t)h << 16);
    const float* Bh = B + (size_t)h * 256 * N;
    float* Dh = D + (size_t)h * 256 * N;
    int tx = threadIdx.x & 15, ty = threadIdx.x >> 4;
    int m0 = blockIdx.y << 6, n0 = blockIdx.x << 6;
    int lb_n = threadIdx.x & 63, lb_k = threadIdx.x >> 6;
    float acc[4][4] = {};
    for (int kt = 0; kt < 256; kt += 16) {
#pragma unroll
        for (int i = 0; i < 4; ++i)
            As[tx][ty + 16 * i] = Ah[(size_t)(m0 + ty + 16 * i) * 256 + kt + tx];
#pragma unroll
        for (int i = 0; i < 4; ++i)
            Bs[lb_k + 4 * i][lb_n] = Bh[(size_t)(kt + lb_k + 4 * i) * N + n0 + lb_n];
        __syncthreads();
#pragma unroll
        for (int kk = 0; kk < 16; ++kk) {
            float4 av = *(const float4*)&As[kk][ty * 4];
            float4 bv = *(const float4*)&Bs[kk][tx * 4];
            float a_[4] = { av.x, av.y, av.z, av.w };
            float b_[4] = { bv.x, bv.y, bv.z, bv.w };
#pragma unroll
            for (int i = 0; i < 4; ++i)
#pragma unroll
                for (int j = 0; j < 4; ++j) acc[i][j] += a_[i] * b_[j];
        }
        __syncthreads();
    }
#pragma unroll
    for (int i = 0; i < 4; ++i)
#pragma unroll
        for (int j = 0; j < 4; ++j) {
            int gr = m0 + ty * 4 + i, gc = n0 + tx * 4 + j;
            float cv = -alpha * acc[i][j];
            if (c1 != 0.f) cv += alpha * c1 * Ah[(size_t)gr * 256 + gc];
            if (gr == gc) cv += delta;
            if (DT) DT[((size_t)h << 14) + (size_t)gc * 256 + gr] = __float2bfloat16(cv);
            else Dh[(size_t)gr * N + gc] = cv;
        }
}

// ---------------- LayerNorm per row (512) -> bf16 out, one wave per row
__global__ __launch_bounds__(64) void ln_k(const float* __restrict__ in,
    const float* __restrict__ g, const float* __restrict__ b,
    __hip_bfloat16* __restrict__ out, int rows)
{
    int r = blockIdx.x;
    if (r >= rows) return;
    int lane = threadIdx.x;
    const float* xr = in + (size_t)r * DIMF;
    float v[8], s = 0.f;
#pragma unroll
    for (int i = 0; i < 8; ++i) { v[i] = xr[i * 64 + lane]; s += v[i]; }
#pragma unroll
    for (int off = 32; off; off >>= 1) s += __shfl_xor(s, off);
    float mu = s * (1.f / 512.f);
    float vs = 0.f;
#pragma unroll
    for (int i = 0; i < 8; ++i) { float d = v[i] - mu; vs += d * d; }
#pragma unroll
    for (int off = 32; off; off >>= 1) vs += __shfl_xor(vs, off);
    float rstd = rsqrtf(vs * (1.f / 512.f) + 1e-5f);
    __hip_bfloat16* orow = out + (size_t)r * DIMF;
#pragma unroll
    for (int i = 0; i < 8; ++i) {
        int d = i * 64 + lane;
        orow[d] = __float2bfloat16((v[i] - mu) * rstd * g[d] + b[d]);
    }
}

// ---------------- landmark means from bf16 qkv; ql scaled by 0.125
__global__ __launch_bounds__(64) void landmark_k(const __hip_bfloat16* __restrict__ qkvb16,
    float* __restrict__ ql, float* __restrict__ kl,
    __hip_bfloat16* __restrict__ ql16, __hip_bfloat16* __restrict__ kl16)
{
    int bx = blockIdx.x;
    int h = bx >> 8, j = bx & 255;
    int d = threadIdx.x;
    float qs = 0.f, ks = 0.f;
    for (int u = 0; u < LSEG; ++u) {
        size_t addr = (size_t)(j * LSEG + u) * QKVW + (h << 6) + d;
        qs += __bfloat162float(qkvb16[addr]);
        ks += __bfloat162float(qkvb16[addr + 512]);
    }
    float qm = qs * (1.f / 65.f) * 0.125f;
    float km = ks * (1.f / 65.f);
    ql[(size_t)bx * 64 + d] = qm;
    kl[(size_t)bx * 64 + d] = km;
    ql16[(size_t)bx * 64 + d] = __float2bfloat16(qm);
    kl16[(size_t)bx * 64 + d] = __float2bfloat16(km);
}

// ---------------- a2 = softmax(q_l @ k_l^T) rows; block per (h,i)
__global__ __launch_bounds__(256) void a2_k(const float* __restrict__ ql,
    const float* __restrict__ kl, float* __restrict__ a2)
{
    int h = blockIdx.x >> 8, i = blockIdx.x & 255;
    int j = threadIdx.x;
    __shared__ float qs[64];
    __shared__ float red[256];
    if (j < 64) qs[j] = ql[((size_t)(h << 8) + i) * 64 + j];
    __syncthreads();
    const float* kr = kl + ((size_t)(h << 8) + j) * 64;
    float s = 0.f;
#pragma unroll 8
    for (int d = 0; d < 64; ++d) s += qs[d] * kr[d];
    red[j] = s; __syncthreads();
    for (int st = 128; st; st >>= 1) { if (j < st) red[j] = fmaxf(red[j], red[j + st]); __syncthreads(); }
    float mx = red[0]; __syncthreads();
    float p = __expf(s - mx);
    red[j] = p; __syncthreads();
    for (int st = 128; st; st >>= 1) { if (j < st) red[j] += red[j + st]; __syncthreads(); }
    a2[((size_t)h << 16) + i * 256 + j] = p / red[0];
}

// ---------------- pinv init: z = a2^T / (max_rowsum * max_colsum), per head
__global__ __launch_bounds__(256) void zinit_k(const float* __restrict__ a2, float* __restrict__ z)
{
    int h = blockIdx.x, t = threadIdx.x;
    const float* X = a2 + ((size_t)h << 16);
    __shared__ float red[256];
    float rs = 0.f;
    for (int j = 0; j < 256; ++j) rs += fabsf(X[t * 256 + j]);
    red[t] = rs; __syncthreads();
    for (int st = 128; st; st >>= 1) { if (t < st) red[t] = fmaxf(red[t], red[t + st]); __syncthreads(); }
    float colv = red[0]; __syncthreads();
    float cs = 0.f;
    for (int i = 0; i < 256; ++i) cs += fabsf(X[i * 256 + t]);
    red[t] = cs; __syncthreads();
    for (int st = 128; st; st >>= 1) { if (t < st) red[t] = fmaxf(red[t], red[t + st]); __syncthreads(); }
    float rowv = red[0];
    float inv = 1.f / (colv * rowv);
    for (int e = t; e < 65536; e += 256) {
        int i = e >> 8, j = e & 255;
        z[((size_t)h << 16) + e] = X[j * 256 + i] * inv;
    }
}

// ---------------- MFMA flash a3v partials: softmax(q_l @ k^T) @ v, online.
// Block = (h, 64-landmark group) x t-chunk; 2 waves x 32 queries.
// K B-frags direct from qkvb16 (K[t][d] == BT layout); V B-frags from vT16.
__global__ __launch_bounds__(128) void a3v_flash_k(
    const __hip_bfloat16* __restrict__ ql16, const __hip_bfloat16* __restrict__ qkvb16,
    const __hip_bfloat16* __restrict__ vT16,
    float* __restrict__ opart, float* __restrict__ mpart, float* __restrict__ lpart)
{
    int bx = blockIdx.x;            // h*4 + qb
    int h = bx >> 2, qb = bx & 3;
    int tc = blockIdx.y;
    int wv = threadIdx.x >> 6;
    int lane = threadIdx.x & 63;
    int rA = lane & 15, g = lane >> 4, kp = g << 3;
    __shared__ __align__(16) __hip_bfloat16 Plds[2][32 * 64];
    char* P = (char*)&Plds[wv][0];

    bf16x8 qa[2][2];
    const __hip_bfloat16* qlh = ql16 + ((size_t)h << 14);
#pragma unroll
    for (int m = 0; m < 2; ++m)
#pragma unroll
        for (int ks = 0; ks < 2; ++ks)
            qa[m][ks] = *(const bf16x8*)(qlh +
                (size_t)((qb << 6) + (wv << 5) + (m << 4) + rA) * 64 + ks * 32 + kp);

    const __hip_bfloat16* kg = qkvb16 + 512 + (h << 6);
    const __hip_bfloat16* vg = vT16 + ((size_t)(h << 6)) * NP;

    f32x4 O[2][4] = {};
    float m_[2][4], l_[2][4];
#pragma unroll
    for (int m = 0; m < 2; ++m)
#pragma unroll
        for (int i = 0; i < 4; ++i) { m_[m][i] = -3e38f; l_[m][i] = 0.f; }

    for (int tile = tc * 13; tile < tc * 13 + 13; ++tile) {
        int t0 = tile << 6;
        f32x4 S[2][4] = {};
#pragma unroll
        for (int n = 0; n < 4; ++n)
#pragma unroll
            for (int ks = 0; ks < 2; ++ks) {
                bf16x8 kb = *(const bf16x8*)(kg + (size_t)(t0 + (n << 4) + rA) * QKVW + ks * 32 + kp);
                S[0][n] = __builtin_amdgcn_mfma_f32_16x16x32_bf16(qa[0][ks], kb, S[0][n], 0, 0, 0);
                S[1][n] = __builtin_amdgcn_mfma_f32_16x16x32_bf16(qa[1][ks], kb, S[1][n], 0, 0, 0);
            }
        float f_[2][4];
#pragma unroll
        for (int m = 0; m < 2; ++m)
#pragma unroll
            for (int i = 0; i < 4; ++i) {
                float mx = fmaxf(fmaxf(S[m][0][i], S[m][1][i]), fmaxf(S[m][2][i], S[m][3][i]));
#pragma unroll
                for (int msk = 8; msk; msk >>= 1) mx = fmaxf(mx, __shfl_xor(mx, msk));
                float mn = fmaxf(m_[m][i], mx);
                float f = __expf(m_[m][i] - mn);
                int r = (m << 4) + (g << 2) + i;
                int swz = (r & 7) << 4;
                float sum = 0.f;
#pragma unroll
                for (int n = 0; n < 4; ++n) {
                    float p = __expf(S[m][n][i] - mn);
                    sum += p;
                    int byte = (r << 7) + (((n << 4) + rA) << 1);
                    *(__hip_bfloat16*)(P + (byte ^ swz)) = __float2bfloat16(p);
                }
#pragma unroll
                for (int msk = 8; msk; msk >>= 1) sum += __shfl_xor(sum, msk);
                l_[m][i] = l_[m][i] * f + sum;
                m_[m][i] = mn;
                f_[m][i] = f;
            }
#pragma unroll
        for (int m = 0; m < 2; ++m)
#pragma unroll
            for (int i = 0; i < 4; ++i) {
                float f = f_[m][i];
#pragma unroll
                for (int n = 0; n < 4; ++n) O[m][n][i] *= f;
            }
#pragma unroll
        for (int ks2 = 0; ks2 < 2; ++ks2) {
            bf16x8 pa[2];
#pragma unroll
            for (int m = 0; m < 2; ++m) {
                int rr = (m << 4) + rA;
                int byte = (rr << 7) + ((ks2 * 32 + kp) << 1);
                pa[m] = *(const bf16x8*)(P + (byte ^ ((rr & 7) << 4)));
            }
#pragma unroll
            for (int n = 0; n < 4; ++n) {
                bf16x8 vb = *(const bf16x8*)(vg + (size_t)((n << 4) + rA) * NP + t0 + ks2 * 32 + kp);
                O[0][n] = __builtin_amdgcn_mfma_f32_16x16x32_bf16(pa[0], vb, O[0][n], 0, 0, 0);
                O[1][n] = __builtin_amdgcn_mfma_f32_16x16x32_bf16(pa[1], vb, O[1][n], 0, 0, 0);
            }
        }
    }
    int pb2 = (bx << 1) | wv;
    size_t obase = ((size_t)pb2 * A3V_TC + tc) * 2048;
#pragma unroll
    for (int m = 0; m < 2; ++m)
#pragma unroll
        for (int i = 0; i < 4; ++i) {
            int r = (m << 4) + (g << 2) + i;
#pragma unroll
            for (int n = 0; n < 4; ++n)
                opart[obase + (size_t)r * 64 + (n << 4) + rA] = O[m][n][i];
            if (rA == 0) {
                mpart[((size_t)pb2 * A3V_TC + tc) * 32 + r] = m_[m][i];
                lpart[((size_t)pb2 * A3V_TC + tc) * 32 + r] = l_[m][i];
            }
        }
}

__global__ __launch_bounds__(64) void a3v_comb_k(const float* __restrict__ opart,
    const float* __restrict__ mpart, const float* __restrict__ lpart, float* __restrict__ a3v)
{
    int pb = blockIdx.x, d = threadIdx.x;
    for (int r = 0; r < 32; ++r) {
        float M = -3e38f;
        for (int tc = 0; tc < A3V_TC; ++tc)
            M = fmaxf(M, mpart[((size_t)pb * A3V_TC + tc) * 32 + r]);
        float L = 0.f, od = 0.f;
        for (int tc = 0; tc < A3V_TC; ++tc) {
            float w = __expf(mpart[((size_t)pb * A3V_TC + tc) * 32 + r] - M);
            L += lpart[((size_t)pb * A3V_TC + tc) * 32 + r] * w;
            od += w * opart[((size_t)pb * A3V_TC + tc) * 2048 + (size_t)r * 64 + d];
        }
        a3v[((size_t)pb * 32 + r) * 64 + d] = od / L;
    }
}

// ---------------- MFMA fused sim1-softmax @ Wm (bf16 q input; S scaled 0.125)
__global__ __launch_bounds__(128) void attnout_mfma_k(
    const __hip_bfloat16* __restrict__ qkvb16, const __hip_bfloat16* __restrict__ kl16,
    const __hip_bfloat16* __restrict__ wmT16, float* __restrict__ o)
{
    int h = blockIdx.y;
    int rbase = (blockIdx.x << 6) + ((threadIdx.x >> 6) << 5);
    int lane = threadIdx.x & 63;
    int rA = lane & 15;
    int g = lane >> 4;
    int kp = g << 3;
    __shared__ __align__(16) __hip_bfloat16 Plds[2][32 * 256];
    char* P = (char*)&Plds[threadIdx.x >> 6][0];

    bf16x8 qa[2][2];
#pragma unroll
    for (int m = 0; m < 2; ++m)
#pragma unroll
        for (int ks = 0; ks < 2; ++ks)
            qa[m][ks] = *(const bf16x8*)(qkvb16 +
                (size_t)(rbase + m * 16 + rA) * QKVW + (h << 6) + ks * 32 + kp);

    const __hip_bfloat16* klh = kl16 + ((size_t)h << 14);
    f32x4 S[2][16] = {};
#pragma unroll
    for (int n = 0; n < 16; ++n) {
#pragma unroll
        for (int ks = 0; ks < 2; ++ks) {
            bf16x8 kb = *(const bf16x8*)(klh + (size_t)((n << 4) + rA) * 64 + ks * 32 + kp);
            S[0][n] = __builtin_amdgcn_mfma_f32_16x16x32_bf16(qa[0][ks], kb, S[0][n], 0, 0, 0);
            S[1][n] = __builtin_amdgcn_mfma_f32_16x16x32_bf16(qa[1][ks], kb, S[1][n], 0, 0, 0);
        }
    }
#pragma unroll
    for (int m = 0; m < 2; ++m)
#pragma unroll
        for (int n = 0; n < 16; ++n) S[m][n] *= 0.125f;

    float lsum[2][4];
#pragma unroll
    for (int m = 0; m < 2; ++m)
#pragma unroll
        for (int i = 0; i < 4; ++i) {
            float mx = -3e38f;
#pragma unroll
            for (int n = 0; n < 16; ++n) mx = fmaxf(mx, S[m][n][i]);
#pragma unroll
            for (int msk = 8; msk; msk >>= 1) mx = fmaxf(mx, __shfl_xor(mx, msk));
            float sum = 0.f;
            int r = (m << 4) + (g << 2) + i;
            int swz = (r & 7) << 4;
#pragma unroll
            for (int n = 0; n < 16; ++n) {
                float p = __expf(S[m][n][i] - mx);
                sum += p;
                int byte = (r << 9) + (((n << 4) + rA) << 1);
                *(__hip_bfloat16*)(P + (byte ^ swz)) = __float2bfloat16(p);
            }
#pragma unroll
            for (int msk = 8; msk; msk >>= 1) sum += __shfl_xor(sum, msk);
            lsum[m][i] = sum;
        }

    const __hip_bfloat16* wmh = wmT16 + ((size_t)h << 14);
    f32x4 O[2][4] = {};
#pragma unroll
    for (int kc = 0; kc < 8; ++kc) {
        bf16x8 pa[2];
#pragma unroll
        for (int m = 0; m < 2; ++m) {
            int rr = (m << 4) + rA;
            int byte = (rr << 9) + (((kc << 5) + kp) << 1);
            pa[m] = *(const bf16x8*)(P + (byte ^ ((rr & 7) << 4)));
        }
#pragma unroll
        for (int n = 0; n < 4; ++n) {
            bf16x8 wb = *(const bf16x8*)(wmh + (size_t)((n << 4) + rA) * 256 + (kc << 5) + kp);
#pragma unroll
            for (int m = 0; m < 2; ++m)
                O[m][n] = __builtin_amdgcn_mfma_f32_16x16x32_bf16(pa[m], wb, O[m][n], 0, 0, 0);
        }
    }
#pragma unroll
    for (int m = 0; m < 2; ++m)
#pragma unroll
        for (int i = 0; i < 4; ++i) {
            float inv = 1.f / lsum[m][i];
            int gm = rbase + (m << 4) + (g << 2) + i;
#pragma unroll
            for (int n = 0; n < 4; ++n)
                o[(size_t)gm * DIMF + (h << 6) + (n << 4) + rA] = O[m][n][i] * inv;
        }
}

// ---------------- resconv (33-tap along seq) + convert to bf16: out = oin + conv
__global__ __launch_bounds__(256) void resconv_tile_k(const __hip_bfloat16* __restrict__ qkvb16,
    const float* __restrict__ rw, const float* __restrict__ oin,
    __hip_bfloat16* __restrict__ oout)
{
    int cg = blockIdx.y;
    int t0 = blockIdx.x << 7;
    int tid = threadIdx.x;
    int lane = tid & 63, w = tid >> 6;
    __shared__ float vt[160][64];
    __shared__ float wr[33];
    if (tid < 33) wr[tid] = rw[cg * 33 + tid];
    for (int e = tid; e < 160 * 64; e += 256) {
        int tt = e >> 6, l = e & 63;
        int t = t0 - 16 + tt;
        vt[tt][l] = (t >= 0 && t < NP)
            ? __bfloat162float(qkvb16[(size_t)t * QKVW + 1024 + (cg << 6) + l]) : 0.f;
    }
    __syncthreads();
    for (int i = 0; i < 32; ++i) {
        int tl = (w << 5) + i;
        float acc = 0.f;
#pragma unroll
        for (int ky = 0; ky < 33; ++ky) acc += wr[ky] * vt[tl + ky][lane];
        size_t oi = (size_t)(t0 + tl) * DIMF + (cg << 6) + lane;
        oout[oi] = __float2bfloat16(oin[oi] + acc);
    }
}

// ---------------- LDS-tiled PPEG
__global__ __launch_bounds__(256) void ppeg_tile_k(const float* __restrict__ x,
    const float* __restrict__ w7, const float* __restrict__ b7,
    const float* __restrict__ w5, const float* __restrict__ b5,
    const float* __restrict__ w3, const float* __restrict__ b3,
    float* __restrict__ tmp)
{
    int cg = blockIdx.y;
    int ty0 = (blockIdx.x >> 4) << 3, tx0 = (blockIdx.x & 15) << 3;
    int tid = threadIdx.x;
    int lane = tid & 63, w = tid >> 6;
    int cl = lane & 31, xh = lane >> 5;
    int c = (cg << 5) + cl;
    const float* feat = x + DIMF;
    __shared__ float tile[196][32];
    __shared__ float w7s[49 * 32];
    __shared__ float w5s[25 * 32];
    __shared__ float w3s[9 * 32];
    for (int e = tid; e < 49 * 32; e += 256) w7s[e] = w7[cg * (49 * 32) + e];
    for (int e = tid; e < 25 * 32; e += 256) w5s[e] = w5[cg * (25 * 32) + e];
    for (int e = tid; e < 9 * 32; e += 256)  w3s[e] = w3[cg * (9 * 32) + e];
    for (int e = tid; e < 196 * 32; e += 256) {
        int sp = e >> 5, l = e & 31;
        int yy = ty0 - 3 + sp / 14, xc = tx0 - 3 + sp % 14;
        float v = 0.f;
        if ((unsigned)yy < 128u && (unsigned)xc < 128u)
            v = feat[(size_t)(yy * 128 + xc) * DIMF + (cg << 5) + l];
        tile[sp][l] = v;
    }
    __syncthreads();
    float bsum = b7[c] + b5[c] + b3[c];
    int xo = (w << 1) + xh;
    for (int yb = 0; yb < 8; yb += 4) {
        float acc[4];
#pragma unroll
        for (int oidx = 0; oidx < 4; ++oidx)
            acc[oidx] = tile[(yb + oidx + 3) * 14 + xo + 3][cl] + bsum;
#pragma unroll
        for (int kx = 0; kx < 7; ++kx) {
            float wc[7];
#pragma unroll
            for (int j = 0; j < 7; ++j) wc[j] = w7s[cl * 49 + j * 7 + kx];
#pragma unroll
            for (int r = 0; r < 10; ++r) {
                float v = tile[(yb + r) * 14 + xo + kx][cl];
#pragma unroll
                for (int oidx = 0; oidx < 4; ++oidx) {
                    int ky = r - oidx;
                    if (ky >= 0 && ky < 7) acc[oidx] += wc[ky] * v;
                }
            }
        }
#pragma unroll
        for (int kx = 0; kx < 5; ++kx) {
            float wc[5];
#pragma unroll
            for (int j = 0; j < 5; ++j) wc[j] = w5s[cl * 25 + j * 5 + kx];
#pragma unroll
            for (int r = 0; r < 8; ++r) {
                float v = tile[(yb + 1 + r) * 14 + xo + 1 + kx][cl];
#pragma unroll
                for (int oidx = 0; oidx < 4; ++oidx) {
                    int ky = r - oidx;
                    if (ky >= 0 && ky < 5) acc[oidx] += wc[ky] * v;
                }
            }
        }
#pragma unroll
        for (int kx = 0; kx < 3; ++kx) {
            float wc[3];
#pragma unroll
            for (int j = 0; j < 3; ++j) wc[j] = w3s[cl * 9 + j * 3 + kx];
#pragma unroll
            for (int r = 0; r < 6; ++r) {
                float v = tile[(yb + 2 + r) * 14 + xo + 2 + kx][cl];
#pragma unroll
                for (int oidx = 0; oidx < 4; ++oidx) {
                    int ky = r - oidx;
                    if (ky >= 0 && ky < 3) acc[oidx] += wc[ky] * v;
                }
            }
        }
#pragma unroll
        for (int oidx = 0; oidx < 4; ++oidx)
            tmp[(size_t)((ty0 + yb + oidx) * 128 + tx0 + xo) * DIMF + c] = acc[oidx];
    }
}

// ---------------- final LN(row0) + 2-class head + softmax + argmax
__global__ __launch_bounds__(64) void head_k(const float* __restrict__ x,
    const float* __restrict__ g, const float* __restrict__ b,
    const float* __restrict__ w, const float* __restrict__ bias, float* __restrict__ out)
{
    int lane = threadIdx.x;
    float v[8], s = 0.f;
#pragma unroll
    for (int i = 0; i < 8; ++i) { v[i] = x[i * 64 + lane]; s += v[i]; }
#pragma unroll
    for (int off = 32; off; off >>= 1) s += __shfl_xor(s, off);
    float mu = s * (1.f / 512.f);
    float vs = 0.f;
#pragma unroll
    for (int i = 0; i < 8; ++i) { float d = v[i] - mu; vs += d * d; }
#pragma unroll
    for (int off = 32; off; off >>= 1) vs += __shfl_xor(vs, off);
    float rstd = rsqrtf(vs * (1.f / 512.f) + 1e-5f);
    float l0 = 0.f, l1 = 0.f;
#pragma unroll
    for (int i = 0; i < 8; ++i) {
        int d = i * 64 + lane;
        float hn = (v[i] - mu) * rstd * g[d] + b[d];
        l0 += hn * w[d * 2];
        l1 += hn * w[d * 2 + 1];
    }
#pragma unroll
    for (int off = 32; off; off >>= 1) { l0 += __shfl_xor(l0, off); l1 += __shfl_xor(l1, off); }
    if (lane == 0) {
        l0 += bias[0]; l1 += bias[1];
        float m = fmaxf(l0, l1);
        float e0 = __expf(l0 - m), e1 = __expf(l1 - m);
        float ss = e0 + e1;
        out[0] = l0; out[1] = l1;
        out[2] = e0 / ss; out[3] = e1 / ss;
        out[4] = (l1 > l0) ? 1.f : 0.f;
    }
}

extern "C" void kernel_launch(void* const* d_in, const int* in_sizes, int n_in,
                              void* d_out, int out_size, void* d_ws, size_t ws_size,
                              hipStream_t stream)
{
    (void)in_sizes; (void)n_in; (void)out_size; (void)ws_size;
    const float* data   = (const float*)d_in[0];
    const float* fc1_w  = (const float*)d_in[1];
    const float* fc1_b  = (const float*)d_in[2];
    const float* cls    = (const float*)d_in[3];
    const float* l1_ng  = (const float*)d_in[4];
    const float* l1_nb  = (const float*)d_in[5];
    const float* l1_qkv = (const float*)d_in[6];
    const float* l1_ow  = (const float*)d_in[7];
    const float* l1_ob  = (const float*)d_in[8];
    const float* l1_rw  = (const float*)d_in[9];
    const float* l2_ng  = (const float*)d_in[10];
    const float* l2_nb  = (const float*)d_in[11];
    const float* l2_qkv = (const float*)d_in[12];
    const float* l2_ow  = (const float*)d_in[13];
    const float* l2_ob  = (const float*)d_in[14];
    const float* l2_rw  = (const float*)d_in[15];
    const float* p_w7   = (const float*)d_in[16];
    const float* p_b7   = (const float*)d_in[17];
    const float* p_w5   = (const float*)d_in[18];
    const float* p_b5   = (const float*)d_in[19];
    const float* p_w3   = (const float*)d_in[20];
    const float* p_b3   = (const float*)d_in[21];
    const float* n_g    = (const float*)d_in[22];
    const float* n_b    = (const float*)d_in[23];
    const float* fc2_w  = (const float*)d_in[24];
    const float* fc2_b  = (const float*)d_in[25];

    char* base = (char*)d_ws;
    auto carve = [&](size_t bytes) { char* p = base; base += (bytes + 255) & ~(size_t)255; return p; };
    float* x              = (float*)carve((size_t)NT * DIMF * 4);
    __hip_bfloat16* xp16  = (__hip_bfloat16*)carve((size_t)NP * DIMF * 2);   // alias: obuf2
    __hip_bfloat16* qkvb16 = (__hip_bfloat16*)carve((size_t)NP * QKVW * 2);  // alias: data16 (stem)
    __hip_bfloat16* vT16  = (__hip_bfloat16*)carve((size_t)NHEAD * DH * NP * 2);
    float* obuf           = (float*)carve((size_t)NP * DIMF * 4);
    __hip_bfloat16* wT    = (__hip_bfloat16*)carve((size_t)QKVW * DIMF * 2);
    float* ql    = (float*)carve(131072 * 4);
    float* kl    = (float*)carve(131072 * 4);
    __hip_bfloat16* ql16  = (__hip_bfloat16*)carve(131072 * 2);
    __hip_bfloat16* kl16  = (__hip_bfloat16*)carve(131072 * 2);
    __hip_bfloat16* wmT16 = (__hip_bfloat16*)carve(131072 * 2);
    float* a2    = (float*)carve(524288 * 4);
    float* zb    = (float*)carve(524288 * 4);
    float* z2    = (float*)carve(524288 * 4);
    float* xz    = (float*)carve(524288 * 4);
    float* ta    = (float*)carve(524288 * 4);
    float* tb    = (float*)carve(524288 * 4);
    float* a3v   = (float*)carve(131072 * 4);
    float* wm    = (float*)carve(131072 * 4);
    float* opart = (float*)carve((size_t)64 * A3V_TC * 2048 * 4);
    float* mpart = (float*)carve((size_t)64 * A3V_TC * 32 * 4);
    float* lpart = (float*)carve((size_t)64 * A3V_TC * 32 * 4);
    __hip_bfloat16* obuf2 = xp16;                       // lifetime-disjoint alias
    __hip_bfloat16* data16 = qkvb16;                    // stem-only alias

    // ---- stem: x[0]=cls; x[1..] = relu(data @ fc1_w + fc1_b), via bf16 MFMA
    cvt_k<<<(16384 * 1024 / 4 + 255) / 256, 256, 0, stream>>>(
        (const float4*)data, (ushort4*)data16, 16384 * 1024 / 4);
    transcvt_k<<<(DIMF / 32) * (1024 / 32), 256, 0, stream>>>(fc1_w, wT, 1024, DIMF);
    gemm_bf16_k<<<dim3(DIMF / 128, 16384 / 128), 256, 0, stream>>>(
        data16, wT, fc1_b, nullptr, x + DIMF, nullptr, 16384, DIMF, 1024, 16384, 1);
    hipMemcpyAsync(x, cls, DIMF * sizeof(float), hipMemcpyDeviceToDevice, stream);

    auto layer = [&](const float* ng, const float* nb, const float* qw,
                     const float* ow, const float* ob, const float* rw) {
        hipMemsetAsync(xp16, 0, (size_t)PADR * DIMF * 2, stream);
        ln_k<<<NT, 64, 0, stream>>>(x, ng, nb, xp16 + (size_t)PADR * DIMF, NT);
        transcvt_k<<<(QKVW / 32) * (DIMF / 32), 256, 0, stream>>>(qw, wT, DIMF, QKVW);
        gemm_bf16_k<<<dim3(QKVW / 128, NP / 128), 256, 0, stream>>>(
            xp16, wT, nullptr, nullptr, nullptr, qkvb16, NP, QKVW, DIMF, NP, 0);
        vtrans_k<<<dim3(NP / 64, NHEAD), 256, 0, stream>>>(qkvb16, vT16);
        landmark_k<<<NHEAD * NLM, 64, 0, stream>>>(qkvb16, ql, kl, ql16, kl16);
        a2_k<<<NHEAD * NLM, 256, 0, stream>>>(ql, kl, a2);
        zinit_k<<<NHEAD, 256, 0, stream>>>(a2, zb);
        float* zc = zb; float* zn = z2;
        for (int it = 0; it < 6; ++it) {
            mm256_k<<<dim3(4, 4, NHEAD), 256, 0, stream>>>(a2, zc, xz, nullptr, 256, 0.f, -1.f, 0.f);
            mm256_k<<<dim3(4, 4, NHEAD), 256, 0, stream>>>(xz, xz, ta, nullptr, 256, 7.f, -1.f, 15.f);
            mm256_k<<<dim3(4, 4, NHEAD), 256, 0, stream>>>(xz, ta, tb, nullptr, 256, 0.f, 1.f, 13.f);
            mm256_k<<<dim3(4, 4, NHEAD), 256, 0, stream>>>(zc, tb, zn, nullptr, 256, 0.f, -0.25f, 0.f);
            float* sw = zc; zc = zn; zn = sw;
        }
        a3v_flash_k<<<dim3(32, A3V_TC), 128, 0, stream>>>(ql16, qkvb16, vT16, opart, mpart, lpart);
        a3v_comb_k<<<64, 64, 0, stream>>>(opart, mpart, lpart, a3v);
        mm256_k<<<dim3(1, 4, NHEAD), 256, 0, stream>>>(zc, a3v, wm, wmT16, 64, 0.f, -1.f, 0.f);
        attnout_mfma_k<<<dim3(NP / 64, NHEAD), 128, 0, stream>>>(qkvb16, kl16, wmT16, obuf);
        resconv_tile_k<<<dim3(NP / 128, NHEAD), 256, 0, stream>>>(qkvb16, rw, obuf, obuf2);
        transcvt_k<<<(DIMF / 32) * (DIMF / 32), 256, 0, stream>>>(ow, wT, DIMF, DIMF);
        gemm_bf16_k<<<dim3(DIMF / 128, (NT + 127) / 128), 256, 0, stream>>>(
            obuf2 + (size_t)PADR * DIMF, wT, ob, x, x, nullptr, NT, DIMF, DIMF, NT, 0);
    };

    layer(l1_ng, l1_nb, l1_qkv, l1_ow, l1_ob, l1_rw);

    ppeg_tile_k<<<dim3(256, 16), 256, 0, stream>>>(x, p_w7, p_b7, p_w5, p_b5, p_w3, p_b3, obuf);
    hipMemcpyAsync(x + DIMF, obuf, (size_t)16384 * DIMF * sizeof(float),
                   hipMemcpyDeviceToDevice, stream);

    layer(l2_ng, l2_nb, l2_qkv, l2_ow, l2_ob, l2_rw);

    head_k<<<1, 64, 0, stream>>>(x, n_g, n_b, fc2_w, fc2_b, (float*)d_out);
}

// Round 6
// 1432.891 us; speedup vs baseline: 4.8049x; 1.3484x over previous
//
#include <hip/hip_runtime.h>
#include <hip/hip_bf16.h>

// TransMIL forward. Round 6: bf16-MFMA pinv Newton chain (2 dispatches/iter),
// vectorized bf16-LDS PPEG, MFMA flash a3v + attnout, bf16 MFMA big GEMMs.

#define NT 16385
#define NP 16640
#define PADR 255
#define DIMF 512
#define QKVW 1536
#define NHEAD 8
#define DH 64
#define NLM 256
#define LSEG 65
#define A3V_TC 20

typedef short bf16x8 __attribute__((ext_vector_type(8)));
typedef short bf16x4 __attribute__((ext_vector_type(4)));
typedef float f32x4 __attribute__((ext_vector_type(4)));

__device__ __forceinline__ void gload_lds16(const void* g, void* l) {
    __builtin_amdgcn_global_load_lds(
        (const __attribute__((address_space(1))) void*)g,
        (__attribute__((address_space(3))) void*)l, 16, 0, 0);
}

__device__ __forceinline__ float4 b4f(const __hip_bfloat16* p) {
    ushort4 u = *(const ushort4*)p;
    float4 r;
    r.x = __uint_as_float((unsigned)u.x << 16);
    r.y = __uint_as_float((unsigned)u.y << 16);
    r.z = __uint_as_float((unsigned)u.z << 16);
    r.w = __uint_as_float((unsigned)u.w << 16);
    return r;
}

__device__ __forceinline__ bf16x4 f4b(float a, float b, float c, float d) {
    union { bf16x4 v; __hip_bfloat16 h[4]; } u;
    u.h[0] = __float2bfloat16(a); u.h[1] = __float2bfloat16(b);
    u.h[2] = __float2bfloat16(c); u.h[3] = __float2bfloat16(d);
    return u.v;
}

// ---------------- bf16 MFMA GEMM: C = A[MxK]@BT[NxK]^T + bias (+Cacc)(+relu)
__global__ __launch_bounds__(256) void gemm_bf16_k(
    const __hip_bfloat16* __restrict__ A, const __hip_bfloat16* __restrict__ BT,
    const float* __restrict__ bias, const float* __restrict__ Cacc,
    float* __restrict__ C, __hip_bfloat16* __restrict__ C16,
    int M, int N, int K, int MA, int relu)
{
    __shared__ __align__(16) __hip_bfloat16 Asl[128 * 64];
    __shared__ __align__(16) __hip_bfloat16 Bsl[128 * 64];
    int tid = threadIdx.x;
    int wid = tid >> 6, lane = tid & 63;
    int m0 = blockIdx.y << 7, n0 = blockIdx.x << 7;
    int wr = (wid >> 1) << 6, wc = (wid & 1) << 6;
    f32x4 acc[4][4] = {};
    int lr = lane >> 3, lk = (lane & 7) << 3;
    for (int kt = 0; kt < K; kt += 64) {
#pragma unroll
        for (int i = 0; i < 4; ++i) {
            int ch = wid * 4 + i;
            int rowA = m0 + ch * 8 + lr;
            rowA = rowA < MA ? rowA : (MA - 1);
            gload_lds16(A + (size_t)rowA * K + kt + lk, &Asl[ch * 512]);
            int rowB = n0 + ch * 8 + lr;
            gload_lds16(BT + (size_t)rowB * K + kt + lk, &Bsl[ch * 512]);
        }
        __syncthreads();
#pragma unroll
        for (int ks = 0; ks < 2; ++ks) {
            int kb = ks * 32 + (lane >> 4) * 8;
            bf16x8 af[4], bfr[4];
#pragma unroll
            for (int m = 0; m < 4; ++m)
                af[m] = *(const bf16x8*)&Asl[(wr + m * 16 + (lane & 15)) * 64 + kb];
#pragma unroll
            for (int n = 0; n < 4; ++n)
                bfr[n] = *(const bf16x8*)&Bsl[(wc + n * 16 + (lane & 15)) * 64 + kb];
#pragma unroll
            for (int m = 0; m < 4; ++m)
#pragma unroll
                for (int n = 0; n < 4; ++n)
                    acc[m][n] = __builtin_amdgcn_mfma_f32_16x16x32_bf16(
                        af[m], bfr[n], acc[m][n], 0, 0, 0);
        }
        __syncthreads();
    }
    int cr = (lane >> 4) << 2, cc = lane & 15;
#pragma unroll
    for (int m = 0; m < 4; ++m) {
#pragma unroll
        for (int i = 0; i < 4; ++i) {
            int gm = m0 + wr + m * 16 + cr + i;
            if (gm >= M) continue;
#pragma unroll
            for (int n = 0; n < 4; ++n) {
                int gn = n0 + wc + n * 16 + cc;
                float v = acc[m][n][i];
                if (bias) v += bias[gn];
                if (Cacc) v += Cacc[(size_t)gm * N + gn];
                if (relu) v = fmaxf(v, 0.f);
                if (C16) C16[(size_t)gm * N + gn] = __float2bfloat16(v);
                else C[(size_t)gm * N + gn] = v;
            }
        }
    }
}

// ---------------- fp32 [KxN] -> bf16 [NxK] tiled transpose-convert
__global__ __launch_bounds__(256) void transcvt_k(const float* __restrict__ W,
    __hip_bfloat16* __restrict__ WT, int K, int N)
{
    __shared__ float t[32][33];
    int nt = N >> 5;
    int n0 = (blockIdx.x % nt) << 5, k0 = (blockIdx.x / nt) << 5;
    int tx = threadIdx.x & 31, ty = threadIdx.x >> 5;
    for (int r = ty; r < 32; r += 8) t[r][tx] = W[(size_t)(k0 + r) * N + n0 + tx];
    __syncthreads();
    for (int r = ty; r < 32; r += 8)
        WT[(size_t)(n0 + r) * K + k0 + tx] = __float2bfloat16(t[tx][r]);
}

// ---------------- fp32 -> bf16 convert (vectorized)
__global__ __launch_bounds__(256) void cvt_k(const float4* __restrict__ in,
    ushort4* __restrict__ out, int n4)
{
    int i = blockIdx.x * 256 + threadIdx.x;
    if (i >= n4) return;
    float4 v = in[i];
    union { __hip_bfloat16 h[4]; ushort4 u; } cv;
    cv.h[0] = __float2bfloat16(v.x); cv.h[1] = __float2bfloat16(v.y);
    cv.h[2] = __float2bfloat16(v.z); cv.h[3] = __float2bfloat16(v.w);
    out[i] = cv.u;
}

// ---------------- v transpose: vT16[h][d][t]
__global__ __launch_bounds__(256) void vtrans_k(const __hip_bfloat16* __restrict__ qkvb16,
    __hip_bfloat16* __restrict__ vT16)
{
    int h = blockIdx.y;
    int t0 = blockIdx.x << 6;
    __shared__ float tile[64][65];
    int tid = threadIdx.x;
    for (int e = tid; e < 512; e += 256) {
        int r = e >> 3, c8 = (e & 7) << 3;
        union { bf16x8 v; __hip_bfloat16 hh[8]; } u;
        u.v = *(const bf16x8*)(qkvb16 + (size_t)(t0 + r) * QKVW + 1024 + (h << 6) + c8);
#pragma unroll
        for (int j = 0; j < 8; ++j) tile[r][c8 + j] = __bfloat162float(u.hh[j]);
    }
    __syncthreads();
    for (int e = tid; e < 512; e += 256) {
        int d = e >> 3, t8 = (e & 7) << 3;
        union { bf16x8 v; __hip_bfloat16 hh[8]; } u;
#pragma unroll
        for (int j = 0; j < 8; ++j) u.hh[j] = __float2bfloat16(tile[t8 + j][d]);
        *(bf16x8*)(vT16 + ((size_t)(h << 6) + d) * NP + t0 + t8) = u.v;
    }
}

// ---------------- LayerNorm per row (512) -> bf16 out
__global__ __launch_bounds__(64) void ln_k(const float* __restrict__ in,
    const float* __restrict__ g, const float* __restrict__ b,
    __hip_bfloat16* __restrict__ out, int rows)
{
    int r = blockIdx.x;
    if (r >= rows) return;
    int lane = threadIdx.x;
    const float* xr = in + (size_t)r * DIMF;
    float v[8], s = 0.f;
#pragma unroll
    for (int i = 0; i < 8; ++i) { v[i] = xr[i * 64 + lane]; s += v[i]; }
#pragma unroll
    for (int off = 32; off; off >>= 1) s += __shfl_xor(s, off);
    float mu = s * (1.f / 512.f);
    float vs = 0.f;
#pragma unroll
    for (int i = 0; i < 8; ++i) { float d = v[i] - mu; vs += d * d; }
#pragma unroll
    for (int off = 32; off; off >>= 1) vs += __shfl_xor(vs, off);
    float rstd = rsqrtf(vs * (1.f / 512.f) + 1e-5f);
    __hip_bfloat16* orow = out + (size_t)r * DIMF;
#pragma unroll
    for (int i = 0; i < 8; ++i) {
        int d = i * 64 + lane;
        orow[d] = __float2bfloat16((v[i] - mu) * rstd * g[d] + b[d]);
    }
}

// ---------------- landmark means from bf16 qkv
__global__ __launch_bounds__(64) void landmark_k(const __hip_bfloat16* __restrict__ qkvb16,
    float* __restrict__ ql, float* __restrict__ kl,
    __hip_bfloat16* __restrict__ ql16, __hip_bfloat16* __restrict__ kl16)
{
    int bx = blockIdx.x;
    int h = bx >> 8, j = bx & 255;
    int d = threadIdx.x;
    float qs = 0.f, ks = 0.f;
    for (int u = 0; u < LSEG; ++u) {
        size_t addr = (size_t)(j * LSEG + u) * QKVW + (h << 6) + d;
        qs += __bfloat162float(qkvb16[addr]);
        ks += __bfloat162float(qkvb16[addr + 512]);
    }
    float qm = qs * (1.f / 65.f) * 0.125f;
    float km = ks * (1.f / 65.f);
    ql[(size_t)bx * 64 + d] = qm;
    kl[(size_t)bx * 64 + d] = km;
    ql16[(size_t)bx * 64 + d] = __float2bfloat16(qm);
    kl16[(size_t)bx * 64 + d] = __float2bfloat16(km);
}

// ---------------- a2 = softmax(q_l @ k_l^T); writes fp32 + bf16 row-major
__global__ __launch_bounds__(256) void a2_k(const float* __restrict__ ql,
    const float* __restrict__ kl, float* __restrict__ a2, __hip_bfloat16* __restrict__ a2_16)
{
    int h = blockIdx.x >> 8, i = blockIdx.x & 255;
    int j = threadIdx.x;
    __shared__ float qs[64];
    __shared__ float red[256];
    if (j < 64) qs[j] = ql[((size_t)(h << 8) + i) * 64 + j];
    __syncthreads();
    const float* kr = kl + ((size_t)(h << 8) + j) * 64;
    float s = 0.f;
#pragma unroll 8
    for (int d = 0; d < 64; ++d) s += qs[d] * kr[d];
    red[j] = s; __syncthreads();
    for (int st = 128; st; st >>= 1) { if (j < st) red[j] = fmaxf(red[j], red[j + st]); __syncthreads(); }
    float mx = red[0]; __syncthreads();
    float p = __expf(s - mx);
    red[j] = p; __syncthreads();
    for (int st = 128; st; st >>= 1) { if (j < st) red[j] += red[j + st]; __syncthreads(); }
    float v = p / red[0];
    a2[((size_t)h << 16) + i * 256 + j] = v;
    a2_16[((size_t)h << 16) + i * 256 + j] = __float2bfloat16(v);
}

// ---------------- pinv init: z = a2^T/(maxrow*maxcol); bf16 row + transposed
__global__ __launch_bounds__(256) void zinit_k(const float* __restrict__ a2,
    __hip_bfloat16* __restrict__ zr16, __hip_bfloat16* __restrict__ zT16)
{
    int h = blockIdx.x, t = threadIdx.x;
    const float* X = a2 + ((size_t)h << 16);
    __shared__ float red[256];
    float rs = 0.f;
    for (int j = 0; j < 256; ++j) rs += fabsf(X[t * 256 + j]);
    red[t] = rs; __syncthreads();
    for (int st = 128; st; st >>= 1) { if (t < st) red[t] = fmaxf(red[t], red[t + st]); __syncthreads(); }
    float colv = red[0]; __syncthreads();
    float cs = 0.f;
    for (int i = 0; i < 256; ++i) cs += fabsf(X[i * 256 + t]);
    red[t] = cs; __syncthreads();
    for (int st = 128; st; st >>= 1) { if (t < st) red[t] = fmaxf(red[t], red[t + st]); __syncthreads(); }
    float rowv = red[0];
    float inv = 1.f / (colv * rowv);
    for (int e = t; e < 65536; e += 256) {
        int i = e >> 8, j = e & 255;
        zr16[((size_t)h << 16) + e] = __float2bfloat16(X[j * 256 + i] * inv);  // z row-major
        zT16[((size_t)h << 16) + e] = __float2bfloat16(X[e] * inv);            // z^T rows
    }
}

// ---------------- pinv G1: xz = a2 @ Z (B via zT16). Writes xz16 + t1T16=7I-xz^T.
__global__ __launch_bounds__(256) void pgemm1_k(
    const __hip_bfloat16* __restrict__ a2_16, const __hip_bfloat16* __restrict__ zT16,
    __hip_bfloat16* __restrict__ xz16, __hip_bfloat16* __restrict__ t1T16)
{
    int h = blockIdx.y, n0 = blockIdx.x << 6;
    int lane = threadIdx.x & 63;
    int r0 = (threadIdx.x >> 6) << 6;
    int rA = lane & 15, g = lane >> 4, kp = g << 3;
    const __hip_bfloat16* Ah = a2_16 + ((size_t)h << 16);
    const __hip_bfloat16* Bh = zT16 + ((size_t)h << 16);
    f32x4 acc[4][4] = {};
    for (int ks = 0; ks < 8; ++ks) {
        bf16x8 af[4], bfr[4];
#pragma unroll
        for (int m = 0; m < 4; ++m)
            af[m] = *(const bf16x8*)&Ah[(size_t)(r0 + m * 16 + rA) * 256 + ks * 32 + kp];
#pragma unroll
        for (int n = 0; n < 4; ++n)
            bfr[n] = *(const bf16x8*)&Bh[(size_t)(n0 + n * 16 + rA) * 256 + ks * 32 + kp];
#pragma unroll
        for (int m = 0; m < 4; ++m)
#pragma unroll
            for (int n = 0; n < 4; ++n)
                acc[m][n] = __builtin_amdgcn_mfma_f32_16x16x32_bf16(af[m], bfr[n], acc[m][n], 0, 0, 0);
    }
    __hip_bfloat16* xzh = xz16 + ((size_t)h << 16);
    __hip_bfloat16* t1h = t1T16 + ((size_t)h << 16);
#pragma unroll
    for (int m = 0; m < 4; ++m)
#pragma unroll
        for (int i = 0; i < 4; ++i) {
            int gr = r0 + m * 16 + (g << 2) + i;
#pragma unroll
            for (int n = 0; n < 4; ++n) {
                int gc = n0 + n * 16 + rA;
                float v = acc[m][n][i];
                xzh[(size_t)gr * 256 + gc] = __float2bfloat16(v);
                t1h[(size_t)gc * 256 + gr] = __float2bfloat16((gr == gc ? 7.f : 0.f) - v);
            }
        }
}

// ---------------- pinv G2+G3+G4 fused per column-stripe:
// ta=15I-xz@t1 -> tb=13I-xz@ta -> Zn=0.25*Z@tb. Stripe lives in LDS.
__global__ __launch_bounds__(256) void pgemm3_k(
    const __hip_bfloat16* __restrict__ xz16, const __hip_bfloat16* __restrict__ t1T16,
    const __hip_bfloat16* __restrict__ zr16,
    __hip_bfloat16* __restrict__ znr16, __hip_bfloat16* __restrict__ znT16)
{
    __shared__ __align__(16) __hip_bfloat16 tA[64][264];
    __shared__ __align__(16) __hip_bfloat16 tB[64][264];
    int h = blockIdx.y, n0 = blockIdx.x << 6;
    int lane = threadIdx.x & 63;
    int r0 = (threadIdx.x >> 6) << 6;
    int rA = lane & 15, g = lane >> 4, kp = g << 3;
    const __hip_bfloat16* Xh = xz16 + ((size_t)h << 16);
    const __hip_bfloat16* T1h = t1T16 + ((size_t)h << 16);
    // G2
    {
        f32x4 acc[4][4] = {};
        for (int ks = 0; ks < 8; ++ks) {
            bf16x8 af[4], bfr[4];
#pragma unroll
            for (int m = 0; m < 4; ++m)
                af[m] = *(const bf16x8*)&Xh[(size_t)(r0 + m * 16 + rA) * 256 + ks * 32 + kp];
#pragma unroll
            for (int n = 0; n < 4; ++n)
                bfr[n] = *(const bf16x8*)&T1h[(size_t)(n0 + n * 16 + rA) * 256 + ks * 32 + kp];
#pragma unroll
            for (int m = 0; m < 4; ++m)
#pragma unroll
                for (int n = 0; n < 4; ++n)
                    acc[m][n] = __builtin_amdgcn_mfma_f32_16x16x32_bf16(af[m], bfr[n], acc[m][n], 0, 0, 0);
        }
#pragma unroll
        for (int m = 0; m < 4; ++m)
#pragma unroll
            for (int n = 0; n < 4; ++n) {
                int gr0 = r0 + m * 16 + (g << 2);
                int cl = n * 16 + rA;
                *(bf16x4*)&tA[cl][gr0] = f4b(
                    ((gr0 + 0 == n0 + cl) ? 15.f : 0.f) - acc[m][n][0],
                    ((gr0 + 1 == n0 + cl) ? 15.f : 0.f) - acc[m][n][1],
                    ((gr0 + 2 == n0 + cl) ? 15.f : 0.f) - acc[m][n][2],
                    ((gr0 + 3 == n0 + cl) ? 15.f : 0.f) - acc[m][n][3]);
            }
    }
    __syncthreads();
    // G3
    {
        f32x4 acc[4][4] = {};
        for (int ks = 0; ks < 8; ++ks) {
            bf16x8 af[4], bfr[4];
#pragma unroll
            for (int m = 0; m < 4; ++m)
                af[m] = *(const bf16x8*)&Xh[(size_t)(r0 + m * 16 + rA) * 256 + ks * 32 + kp];
#pragma unroll
            for (int n = 0; n < 4; ++n)
                bfr[n] = *(const bf16x8*)&tA[n * 16 + rA][ks * 32 + kp];
#pragma unroll
            for (int m = 0; m < 4; ++m)
#pragma unroll
                for (int n = 0; n < 4; ++n)
                    acc[m][n] = __builtin_amdgcn_mfma_f32_16x16x32_bf16(af[m], bfr[n], acc[m][n], 0, 0, 0);
        }
#pragma unroll
        for (int m = 0; m < 4; ++m)
#pragma unroll
            for (int n = 0; n < 4; ++n) {
                int gr0 = r0 + m * 16 + (g << 2);
                int cl = n * 16 + rA;
                *(bf16x4*)&tB[cl][gr0] = f4b(
                    ((gr0 + 0 == n0 + cl) ? 13.f : 0.f) - acc[m][n][0],
                    ((gr0 + 1 == n0 + cl) ? 13.f : 0.f) - acc[m][n][1],
                    ((gr0 + 2 == n0 + cl) ? 13.f : 0.f) - acc[m][n][2],
                    ((gr0 + 3 == n0 + cl) ? 13.f : 0.f) - acc[m][n][3]);
            }
    }
    __syncthreads();
    // G4
    {
        const __hip_bfloat16* Zh = zr16 + ((size_t)h << 16);
        f32x4 acc[4][4] = {};
        for (int ks = 0; ks < 8; ++ks) {
            bf16x8 af[4], bfr[4];
#pragma unroll
            for (int m = 0; m < 4; ++m)
                af[m] = *(const bf16x8*)&Zh[(size_t)(r0 + m * 16 + rA) * 256 + ks * 32 + kp];
#pragma unroll
            for (int n = 0; n < 4; ++n)
                bfr[n] = *(const bf16x8*)&tB[n * 16 + rA][ks * 32 + kp];
#pragma unroll
            for (int m = 0; m < 4; ++m)
#pragma unroll
                for (int n = 0; n < 4; ++n)
                    acc[m][n] = __builtin_amdgcn_mfma_f32_16x16x32_bf16(af[m], bfr[n], acc[m][n], 0, 0, 0);
        }
        __hip_bfloat16* zrh = znr16 + ((size_t)h << 16);
        __hip_bfloat16* zth = znT16 + ((size_t)h << 16);
#pragma unroll
        for (int m = 0; m < 4; ++m)
#pragma unroll
            for (int i = 0; i < 4; ++i) {
                int gr = r0 + m * 16 + (g << 2) + i;
#pragma unroll
                for (int n = 0; n < 4; ++n) {
                    int gc = n0 + n * 16 + rA;
                    float v = 0.25f * acc[m][n][i];
                    zrh[(size_t)gr * 256 + gc] = __float2bfloat16(v);
                    zth[(size_t)gc * 256 + gr] = __float2bfloat16(v);
                }
            }
    }
}

// ---------------- wm = Zfinal @ a3v -> wmT16 (transposed bf16)
__global__ __launch_bounds__(256) void wm_k(
    const __hip_bfloat16* __restrict__ zr16, const __hip_bfloat16* __restrict__ a3vT16,
    __hip_bfloat16* __restrict__ wmT16)
{
    int h = blockIdx.x;
    int lane = threadIdx.x & 63;
    int r0 = (threadIdx.x >> 6) << 6;
    int rA = lane & 15, g = lane >> 4, kp = g << 3;
    const __hip_bfloat16* Zh = zr16 + ((size_t)h << 16);
    const __hip_bfloat16* Bh = a3vT16 + ((size_t)h << 14);
    f32x4 acc[4][4] = {};
    for (int ks = 0; ks < 8; ++ks) {
        bf16x8 af[4], bfr[4];
#pragma unroll
        for (int m = 0; m < 4; ++m)
            af[m] = *(const bf16x8*)&Zh[(size_t)(r0 + m * 16 + rA) * 256 + ks * 32 + kp];
#pragma unroll
        for (int n = 0; n < 4; ++n)
            bfr[n] = *(const bf16x8*)&Bh[(size_t)(n * 16 + rA) * 256 + ks * 32 + kp];
#pragma unroll
        for (int m = 0; m < 4; ++m)
#pragma unroll
            for (int n = 0; n < 4; ++n)
                acc[m][n] = __builtin_amdgcn_mfma_f32_16x16x32_bf16(af[m], bfr[n], acc[m][n], 0, 0, 0);
    }
    __hip_bfloat16* Wh = wmT16 + ((size_t)h << 14);
#pragma unroll
    for (int m = 0; m < 4; ++m)
#pragma unroll
        for (int i = 0; i < 4; ++i) {
            int gr = r0 + m * 16 + (g << 2) + i;
#pragma unroll
            for (int n = 0; n < 4; ++n)
                Wh[(size_t)(n * 16 + rA) * 256 + gr] = __float2bfloat16(acc[m][n][i]);
        }
}

// ---------------- MFMA flash a3v partials
__global__ __launch_bounds__(128) void a3v_flash_k(
    const __hip_bfloat16* __restrict__ ql16, const __hip_bfloat16* __restrict__ qkvb16,
    const __hip_bfloat16* __restrict__ vT16,
    float* __restrict__ opart, float* __restrict__ mpart, float* __restrict__ lpart)
{
    int bx = blockIdx.x;
    int h = bx >> 2, qb = bx & 3;
    int tc = blockIdx.y;
    int wv = threadIdx.x >> 6;
    int lane = threadIdx.x & 63;
    int rA = lane & 15, g = lane >> 4, kp = g << 3;
    __shared__ __align__(16) __hip_bfloat16 Plds[2][32 * 64];
    char* P = (char*)&Plds[wv][0];

    bf16x8 qa[2][2];
    const __hip_bfloat16* qlh = ql16 + ((size_t)h << 14);
#pragma unroll
    for (int m = 0; m < 2; ++m)
#pragma unroll
        for (int ks = 0; ks < 2; ++ks)
            qa[m][ks] = *(const bf16x8*)(qlh +
                (size_t)((qb << 6) + (wv << 5) + (m << 4) + rA) * 64 + ks * 32 + kp);

    const __hip_bfloat16* kg = qkvb16 + 512 + (h << 6);
    const __hip_bfloat16* vg = vT16 + ((size_t)(h << 6)) * NP;

    f32x4 O[2][4] = {};
    float m_[2][4], l_[2][4];
#pragma unroll
    for (int m = 0; m < 2; ++m)
#pragma unroll
        for (int i = 0; i < 4; ++i) { m_[m][i] = -3e38f; l_[m][i] = 0.f; }

    for (int tile = tc * 13; tile < tc * 13 + 13; ++tile) {
        int t0 = tile << 6;
        f32x4 S[2][4] = {};
#pragma unroll
        for (int n = 0; n < 4; ++n)
#pragma unroll
            for (int ks = 0; ks < 2; ++ks) {
                bf16x8 kb = *(const bf16x8*)(kg + (size_t)(t0 + (n << 4) + rA) * QKVW + ks * 32 + kp);
                S[0][n] = __builtin_amdgcn_mfma_f32_16x16x32_bf16(qa[0][ks], kb, S[0][n], 0, 0, 0);
                S[1][n] = __builtin_amdgcn_mfma_f32_16x16x32_bf16(qa[1][ks], kb, S[1][n], 0, 0, 0);
            }
        float f_[2][4];
#pragma unroll
        for (int m = 0; m < 2; ++m)
#pragma unroll
            for (int i = 0; i < 4; ++i) {
                float mx = fmaxf(fmaxf(S[m][0][i], S[m][1][i]), fmaxf(S[m][2][i], S[m][3][i]));
#pragma unroll
                for (int msk = 8; msk; msk >>= 1) mx = fmaxf(mx, __shfl_xor(mx, msk));
                float mn = fmaxf(m_[m][i], mx);
                float f = __expf(m_[m][i] - mn);
                int r = (m << 4) + (g << 2) + i;
                int swz = (r & 7) << 4;
                float sum = 0.f;
#pragma unroll
                for (int n = 0; n < 4; ++n) {
                    float p = __expf(S[m][n][i] - mn);
                    sum += p;
                    int byte = (r << 7) + (((n << 4) + rA) << 1);
                    *(__hip_bfloat16*)(P + (byte ^ swz)) = __float2bfloat16(p);
                }
#pragma unroll
                for (int msk = 8; msk; msk >>= 1) sum += __shfl_xor(sum, msk);
                l_[m][i] = l_[m][i] * f + sum;
                m_[m][i] = mn;
                f_[m][i] = f;
            }
#pragma unroll
        for (int m = 0; m < 2; ++m)
#pragma unroll
            for (int i = 0; i < 4; ++i) {
                float f = f_[m][i];
#pragma unroll
                for (int n = 0; n < 4; ++n) O[m][n][i] *= f;
            }
#pragma unroll
        for (int ks2 = 0; ks2 < 2; ++ks2) {
            bf16x8 pa[2];
#pragma unroll
            for (int m = 0; m < 2; ++m) {
                int rr = (m << 4) + rA;
                int byte = (rr << 7) + ((ks2 * 32 + kp) << 1);
                pa[m] = *(const bf16x8*)(P + (byte ^ ((rr & 7) << 4)));
            }
#pragma unroll
            for (int n = 0; n < 4; ++n) {
                bf16x8 vb = *(const bf16x8*)(vg + (size_t)((n << 4) + rA) * NP + t0 + ks2 * 32 + kp);
                O[0][n] = __builtin_amdgcn_mfma_f32_16x16x32_bf16(pa[0], vb, O[0][n], 0, 0, 0);
                O[1][n] = __builtin_amdgcn_mfma_f32_16x16x32_bf16(pa[1], vb, O[1][n], 0, 0, 0);
            }
        }
    }
    int pb2 = (bx << 1) | wv;
    size_t obase = ((size_t)pb2 * A3V_TC + tc) * 2048;
#pragma unroll
    for (int m = 0; m < 2; ++m)
#pragma unroll
        for (int i = 0; i < 4; ++i) {
            int r = (m << 4) + (g << 2) + i;
#pragma unroll
            for (int n = 0; n < 4; ++n)
                opart[obase + (size_t)r * 64 + (n << 4) + rA] = O[m][n][i];
            if (rA == 0) {
                mpart[((size_t)pb2 * A3V_TC + tc) * 32 + r] = m_[m][i];
                lpart[((size_t)pb2 * A3V_TC + tc) * 32 + r] = l_[m][i];
            }
        }
}

// ---------------- a3v combine -> a3vT16[h][d][j] bf16
__global__ __launch_bounds__(64) void a3v_comb_k(const float* __restrict__ opart,
    const float* __restrict__ mpart, const float* __restrict__ lpart,
    __hip_bfloat16* __restrict__ a3vT16)
{
    int pb = blockIdx.x, d = threadIdx.x;
    int h = pb >> 3;
    for (int r = 0; r < 32; ++r) {
        float M = -3e38f;
        for (int tc = 0; tc < A3V_TC; ++tc)
            M = fmaxf(M, mpart[((size_t)pb * A3V_TC + tc) * 32 + r]);
        float L = 0.f, od = 0.f;
        for (int tc = 0; tc < A3V_TC; ++tc) {
            float w = __expf(mpart[((size_t)pb * A3V_TC + tc) * 32 + r] - M);
            L += lpart[((size_t)pb * A3V_TC + tc) * 32 + r] * w;
            od += w * opart[((size_t)pb * A3V_TC + tc) * 2048 + (size_t)r * 64 + d];
        }
        int j = ((pb & 7) << 5) + r;
        a3vT16[((size_t)((h << 6) + d) << 8) + j] = __float2bfloat16(od / L);
    }
}

// ---------------- MFMA fused sim1-softmax @ Wm
__global__ __launch_bounds__(128) void attnout_mfma_k(
    const __hip_bfloat16* __restrict__ qkvb16, const __hip_bfloat16* __restrict__ kl16,
    const __hip_bfloat16* __restrict__ wmT16, float* __restrict__ o)
{
    int h = blockIdx.y;
    int rbase = (blockIdx.x << 6) + ((threadIdx.x >> 6) << 5);
    int lane = threadIdx.x & 63;
    int rA = lane & 15;
    int g = lane >> 4;
    int kp = g << 3;
    __shared__ __align__(16) __hip_bfloat16 Plds[2][32 * 256];
    char* P = (char*)&Plds[threadIdx.x >> 6][0];

    bf16x8 qa[2][2];
#pragma unroll
    for (int m = 0; m < 2; ++m)
#pragma unroll
        for (int ks = 0; ks < 2; ++ks)
            qa[m][ks] = *(const bf16x8*)(qkvb16 +
                (size_t)(rbase + m * 16 + rA) * QKVW + (h << 6) + ks * 32 + kp);

    const __hip_bfloat16* klh = kl16 + ((size_t)h << 14);
    f32x4 S[2][16] = {};
#pragma unroll
    for (int n = 0; n < 16; ++n) {
#pragma unroll
        for (int ks = 0; ks < 2; ++ks) {
            bf16x8 kb = *(const bf16x8*)(klh + (size_t)((n << 4) + rA) * 64 + ks * 32 + kp);
            S[0][n] = __builtin_amdgcn_mfma_f32_16x16x32_bf16(qa[0][ks], kb, S[0][n], 0, 0, 0);
            S[1][n] = __builtin_amdgcn_mfma_f32_16x16x32_bf16(qa[1][ks], kb, S[1][n], 0, 0, 0);
        }
    }
#pragma unroll
    for (int m = 0; m < 2; ++m)
#pragma unroll
        for (int n = 0; n < 16; ++n) S[m][n] *= 0.125f;

    float lsum[2][4];
#pragma unroll
    for (int m = 0; m < 2; ++m)
#pragma unroll
        for (int i = 0; i < 4; ++i) {
            float mx = -3e38f;
#pragma unroll
            for (int n = 0; n < 16; ++n) mx = fmaxf(mx, S[m][n][i]);
#pragma unroll
            for (int msk = 8; msk; msk >>= 1) mx = fmaxf(mx, __shfl_xor(mx, msk));
            float sum = 0.f;
            int r = (m << 4) + (g << 2) + i;
            int swz = (r & 7) << 4;
#pragma unroll
            for (int n = 0; n < 16; ++n) {
                float p = __expf(S[m][n][i] - mx);
                sum += p;
                int byte = (r << 9) + (((n << 4) + rA) << 1);
                *(__hip_bfloat16*)(P + (byte ^ swz)) = __float2bfloat16(p);
            }
#pragma unroll
            for (int msk = 8; msk; msk >>= 1) sum += __shfl_xor(sum, msk);
            lsum[m][i] = sum;
        }

    const __hip_bfloat16* wmh = wmT16 + ((size_t)h << 14);
    f32x4 O[2][4] = {};
#pragma unroll
    for (int kc = 0; kc < 8; ++kc) {
        bf16x8 pa[2];
#pragma unroll
        for (int m = 0; m < 2; ++m) {
            int rr = (m << 4) + rA;
            int byte = (rr << 9) + (((kc << 5) + kp) << 1);
            pa[m] = *(const bf16x8*)(P + (byte ^ ((rr & 7) << 4)));
        }
#pragma unroll
        for (int n = 0; n < 4; ++n) {
            bf16x8 wb = *(const bf16x8*)(wmh + (size_t)((n << 4) + rA) * 256 + (kc << 5) + kp);
#pragma unroll
            for (int m = 0; m < 2; ++m)
                O[m][n] = __builtin_amdgcn_mfma_f32_16x16x32_bf16(pa[m], wb, O[m][n], 0, 0, 0);
        }
    }
#pragma unroll
    for (int m = 0; m < 2; ++m)
#pragma unroll
        for (int i = 0; i < 4; ++i) {
            float inv = 1.f / lsum[m][i];
            int gm = rbase + (m << 4) + (g << 2) + i;
#pragma unroll
            for (int n = 0; n < 4; ++n)
                o[(size_t)gm * DIMF + (h << 6) + (n << 4) + rA] = O[m][n][i] * inv;
        }
}

// ---------------- resconv (33-tap along seq) + convert to bf16
__global__ __launch_bounds__(256) void resconv_tile_k(const __hip_bfloat16* __restrict__ qkvb16,
    const float* __restrict__ rw, const float* __restrict__ oin,
    __hip_bfloat16* __restrict__ oout)
{
    int cg = blockIdx.y;
    int t0 = blockIdx.x << 7;
    int tid = threadIdx.x;
    int lane = tid & 63, w = tid >> 6;
    __shared__ float vt[160][64];
    __shared__ float wr[33];
    if (tid < 33) wr[tid] = rw[cg * 33 + tid];
    for (int e = tid; e < 160 * 64; e += 256) {
        int tt = e >> 6, l = e & 63;
        int t = t0 - 16 + tt;
        vt[tt][l] = (t >= 0 && t < NP)
            ? __bfloat162float(qkvb16[(size_t)t * QKVW + 1024 + (cg << 6) + l]) : 0.f;
    }
    __syncthreads();
    for (int i = 0; i < 32; ++i) {
        int tl = (w << 5) + i;
        float acc = 0.f;
#pragma unroll
        for (int ky = 0; ky < 33; ++ky) acc += wr[ky] * vt[tl + ky][lane];
        size_t oi = (size_t)(t0 + tl) * DIMF + (cg << 6) + lane;
        oout[oi] = __float2bfloat16(oin[oi] + acc);
    }
}

// ---------------- PPEG v2: 4-channel float4 vectorized, bf16 LDS tile
// Block: 8x8 spatial x 64 ch. Identity+bias fp32 exact; conv taps bf16.
__global__ __launch_bounds__(256) void ppeg2_k(const float* __restrict__ x,
    const float* __restrict__ w7, const float* __restrict__ b7,
    const float* __restrict__ w5, const float* __restrict__ b5,
    const float* __restrict__ w3, const float* __restrict__ b3,
    float* __restrict__ outfeat)
{
    int cg = blockIdx.y;                       // 0..7 -> 64 channels
    int ty0 = (blockIdx.x >> 4) << 3, tx0 = (blockIdx.x & 15) << 3;
    int tid = threadIdx.x;
    int cgi = tid & 15;                        // ch quad
    int xo = (tid >> 4) & 7;
    int yb0 = (tid >> 7) << 2;                 // 0 or 4
    int c = (cg << 6) + (cgi << 2);
    const float* feat = x + DIMF;
    __shared__ __align__(16) __hip_bfloat16 tile[196][64];
    __shared__ __align__(16) __hip_bfloat16 ws7[49][64];
    __shared__ __align__(16) __hip_bfloat16 ws5[25][64];
    __shared__ __align__(16) __hip_bfloat16 ws3[9][64];
    for (int e = tid; e < 49 * 64; e += 256) {
        int t = e >> 6, cl = e & 63;
        ws7[t][cl] = __float2bfloat16(w7[(size_t)((cg << 6) + cl) * 49 + t]);
    }
    for (int e = tid; e < 25 * 64; e += 256) {
        int t = e >> 6, cl = e & 63;
        ws5[t][cl] = __float2bfloat16(w5[(size_t)((cg << 6) + cl) * 25 + t]);
    }
    for (int e = tid; e < 9 * 64; e += 256) {
        int t = e >> 6, cl = e & 63;
        ws3[t][cl] = __float2bfloat16(w3[(size_t)((cg << 6) + cl) * 9 + t]);
    }
    for (int e = tid; e < 196 * 16; e += 256) {
        int sp = e >> 4, cq = (e & 15) << 2;
        int yy = ty0 - 3 + sp / 14, xc = tx0 - 3 + sp % 14;
        float4 v = make_float4(0.f, 0.f, 0.f, 0.f);
        if ((unsigned)yy < 128u && (unsigned)xc < 128u)
            v = *(const float4*)&feat[(size_t)(yy * 128 + xc) * DIMF + (cg << 6) + cq];
        *(bf16x4*)&tile[sp][cq] = f4b(v.x, v.y, v.z, v.w);
    }
    __syncthreads();
    float4 bs7 = *(const float4*)&b7[c], bs5 = *(const float4*)&b5[c], bs3 = *(const float4*)&b3[c];
    float4 acc[4];
#pragma unroll
    for (int o = 0; o < 4; ++o) {
        float4 idv = *(const float4*)&feat[(size_t)((ty0 + yb0 + o) * 128 + tx0 + xo) * DIMF + c];
        acc[o].x = idv.x + bs7.x + bs5.x + bs3.x;
        acc[o].y = idv.y + bs7.y + bs5.y + bs3.y;
        acc[o].z = idv.z + bs7.z + bs5.z + bs3.z;
        acc[o].w = idv.w + bs7.w + bs5.w + bs3.w;
    }
    int c4 = cgi << 2;
#pragma unroll
    for (int kx = 0; kx < 7; ++kx) {
        float4 wc[7];
#pragma unroll
        for (int j = 0; j < 7; ++j) wc[j] = b4f(&ws7[j * 7 + kx][c4]);
#pragma unroll
        for (int r = 0; r < 10; ++r) {
            float4 v = b4f(&tile[(yb0 + r) * 14 + xo + kx][c4]);
#pragma unroll
            for (int o = 0; o < 4; ++o) {
                int ky = r - o;
                if (ky >= 0 && ky < 7) {
                    acc[o].x += wc[ky].x * v.x; acc[o].y += wc[ky].y * v.y;
                    acc[o].z += wc[ky].z * v.z; acc[o].w += wc[ky].w * v.w;
                }
            }
        }
    }
#pragma unroll
    for (int kx = 0; kx < 5; ++kx) {
        float4 wc[5];
#pragma unroll
        for (int j = 0; j < 5; ++j) wc[j] = b4f(&ws5[j * 5 + kx][c4]);
#pragma unroll
        for (int r = 0; r < 8; ++r) {
            float4 v = b4f(&tile[(yb0 + 1 + r) * 14 + xo + 1 + kx][c4]);
#pragma unroll
            for (int o = 0; o < 4; ++o) {
                int ky = r - o;
                if (ky >= 0 && ky < 5) {
                    acc[o].x += wc[ky].x * v.x; acc[o].y += wc[ky].y * v.y;
                    acc[o].z += wc[ky].z * v.z; acc[o].w += wc[ky].w * v.w;
                }
            }
        }
    }
#pragma unroll
    for (int kx = 0; kx < 3; ++kx) {
        float4 wc[3];
#pragma unroll
        for (int j = 0; j < 3; ++j) wc[j] = b4f(&ws3[j * 3 + kx][c4]);
#pragma unroll
        for (int r = 0; r < 6; ++r) {
            float4 v = b4f(&tile[(yb0 + 2 + r) * 14 + xo + 2 + kx][c4]);
#pragma unroll
            for (int o = 0; o < 4; ++o) {
                int ky = r - o;
                if (ky >= 0 && ky < 3) {
                    acc[o].x += wc[ky].x * v.x; acc[o].y += wc[ky].y * v.y;
                    acc[o].z += wc[ky].z * v.z; acc[o].w += wc[ky].w * v.w;
                }
            }
        }
    }
#pragma unroll
    for (int o = 0; o < 4; ++o)
        *(float4*)&outfeat[(size_t)((ty0 + yb0 + o) * 128 + tx0 + xo) * DIMF + c] = acc[o];
}

// ---------------- final LN(row0) + 2-class head + softmax + argmax
__global__ __launch_bounds__(64) void head_k(const float* __restrict__ x,
    const float* __restrict__ g, const float* __restrict__ b,
    const float* __restrict__ w, const float* __restrict__ bias, float* __restrict__ out)
{
    int lane = threadIdx.x;
    float v[8], s = 0.f;
#pragma unroll
    for (int i = 0; i < 8; ++i) { v[i] = x[i * 64 + lane]; s += v[i]; }
#pragma unroll
    for (int off = 32; off; off >>= 1) s += __shfl_xor(s, off);
    float mu = s * (1.f / 512.f);
    float vs = 0.f;
#pragma unroll
    for (int i = 0; i < 8; ++i) { float d = v[i] - mu; vs += d * d; }
#pragma unroll
    for (int off = 32; off; off >>= 1) vs += __shfl_xor(vs, off);
    float rstd = rsqrtf(vs * (1.f / 512.f) + 1e-5f);
    float l0 = 0.f, l1 = 0.f;
#pragma unroll
    for (int i = 0; i < 8; ++i) {
        int d = i * 64 + lane;
        float hn = (v[i] - mu) * rstd * g[d] + b[d];
        l0 += hn * w[d * 2];
        l1 += hn * w[d * 2 + 1];
    }
#pragma unroll
    for (int off = 32; off; off >>= 1) { l0 += __shfl_xor(l0, off); l1 += __shfl_xor(l1, off); }
    if (lane == 0) {
        l0 += bias[0]; l1 += bias[1];
        float m = fmaxf(l0, l1);
        float e0 = __expf(l0 - m), e1 = __expf(l1 - m);
        float ss = e0 + e1;
        out[0] = l0; out[1] = l1;
        out[2] = e0 / ss; out[3] = e1 / ss;
        out[4] = (l1 > l0) ? 1.f : 0.f;
    }
}

extern "C" void kernel_launch(void* const* d_in, const int* in_sizes, int n_in,
                              void* d_out, int out_size, void* d_ws, size_t ws_size,
                              hipStream_t stream)
{
    (void)in_sizes; (void)n_in; (void)out_size; (void)ws_size;
    const float* data   = (const float*)d_in[0];
    const float* fc1_w  = (const float*)d_in[1];
    const float* fc1_b  = (const float*)d_in[2];
    const float* cls    = (const float*)d_in[3];
    const float* l1_ng  = (const float*)d_in[4];
    const float* l1_nb  = (const float*)d_in[5];
    const float* l1_qkv = (const float*)d_in[6];
    const float* l1_ow  = (const float*)d_in[7];
    const float* l1_ob  = (const float*)d_in[8];
    const float* l1_rw  = (const float*)d_in[9];
    const float* l2_ng  = (const float*)d_in[10];
    const float* l2_nb  = (const float*)d_in[11];
    const float* l2_qkv = (const float*)d_in[12];
    const float* l2_ow  = (const float*)d_in[13];
    const float* l2_ob  = (const float*)d_in[14];
    const float* l2_rw  = (const float*)d_in[15];
    const float* p_w7   = (const float*)d_in[16];
    const float* p_b7   = (const float*)d_in[17];
    const float* p_w5   = (const float*)d_in[18];
    const float* p_b5   = (const float*)d_in[19];
    const float* p_w3   = (const float*)d_in[20];
    const float* p_b3   = (const float*)d_in[21];
    const float* n_g    = (const float*)d_in[22];
    const float* n_b    = (const float*)d_in[23];
    const float* fc2_w  = (const float*)d_in[24];
    const float* fc2_b  = (const float*)d_in[25];

    char* base = (char*)d_ws;
    auto carve = [&](size_t bytes) { char* p = base; base += (bytes + 255) & ~(size_t)255; return p; };
    float* x               = (float*)carve((size_t)NT * DIMF * 4);
    float* x2              = (float*)carve((size_t)NT * DIMF * 4);
    __hip_bfloat16* xp16   = (__hip_bfloat16*)carve((size_t)NP * DIMF * 2);   // alias: obuf2
    __hip_bfloat16* qkvb16 = (__hip_bfloat16*)carve((size_t)NP * QKVW * 2);   // alias: data16
    __hip_bfloat16* vT16   = (__hip_bfloat16*)carve((size_t)NHEAD * DH * NP * 2);
    float* obuf            = (float*)carve((size_t)NP * DIMF * 4);
    __hip_bfloat16* wT     = (__hip_bfloat16*)carve((size_t)QKVW * DIMF * 2);
    float* ql              = (float*)carve(131072 * 4);
    float* kl              = (float*)carve(131072 * 4);
    __hip_bfloat16* ql16   = (__hip_bfloat16*)carve(131072 * 2);
    __hip_bfloat16* kl16   = (__hip_bfloat16*)carve(131072 * 2);
    __hip_bfloat16* wmT16  = (__hip_bfloat16*)carve(131072 * 2);
    float* a2              = (float*)carve(524288 * 4);
    __hip_bfloat16* a2_16  = (__hip_bfloat16*)carve(524288 * 2);
    __hip_bfloat16* zrA    = (__hip_bfloat16*)carve(524288 * 2);
    __hip_bfloat16* zrB    = (__hip_bfloat16*)carve(524288 * 2);
    __hip_bfloat16* ztA    = (__hip_bfloat16*)carve(524288 * 2);
    __hip_bfloat16* ztB    = (__hip_bfloat16*)carve(524288 * 2);
    __hip_bfloat16* xz16   = (__hip_bfloat16*)carve(524288 * 2);
    __hip_bfloat16* t1T16  = (__hip_bfloat16*)carve(524288 * 2);
    __hip_bfloat16* a3vT16 = (__hip_bfloat16*)carve(131072 * 2);
    float* opart = (float*)carve((size_t)64 * A3V_TC * 2048 * 4);
    float* mpart = (float*)carve((size_t)64 * A3V_TC * 32 * 4);
    float* lpart = (float*)carve((size_t)64 * A3V_TC * 32 * 4);
    __hip_bfloat16* obuf2  = xp16;
    __hip_bfloat16* data16 = qkvb16;

    // ---- stem
    cvt_k<<<(16384 * 1024 / 4 + 255) / 256, 256, 0, stream>>>(
        (const float4*)data, (ushort4*)data16, 16384 * 1024 / 4);
    transcvt_k<<<(DIMF / 32) * (1024 / 32), 256, 0, stream>>>(fc1_w, wT, 1024, DIMF);
    gemm_bf16_k<<<dim3(DIMF / 128, 16384 / 128), 256, 0, stream>>>(
        data16, wT, fc1_b, nullptr, x + DIMF, nullptr, 16384, DIMF, 1024, 16384, 1);
    hipMemcpyAsync(x, cls, DIMF * sizeof(float), hipMemcpyDeviceToDevice, stream);

    auto layer = [&](float* xv, const float* ng, const float* nb, const float* qw,
                     const float* ow, const float* ob, const float* rw) {
        hipMemsetAsync(xp16, 0, (size_t)PADR * DIMF * 2, stream);
        ln_k<<<NT, 64, 0, stream>>>(xv, ng, nb, xp16 + (size_t)PADR * DIMF, NT);
        transcvt_k<<<(QKVW / 32) * (DIMF / 32), 256, 0, stream>>>(qw, wT, DIMF, QKVW);
        gemm_bf16_k<<<dim3(QKVW / 128, NP / 128), 256, 0, stream>>>(
            xp16, wT, nullptr, nullptr, nullptr, qkvb16, NP, QKVW, DIMF, NP, 0);
        vtrans_k<<<dim3(NP / 64, NHEAD), 256, 0, stream>>>(qkvb16, vT16);
        landmark_k<<<NHEAD * NLM, 64, 0, stream>>>(qkvb16, ql, kl, ql16, kl16);
        a2_k<<<NHEAD * NLM, 256, 0, stream>>>(ql, kl, a2, a2_16);
        zinit_k<<<NHEAD, 256, 0, stream>>>(a2, zrA, ztA);
        __hip_bfloat16 *zr = zrA, *zt = ztA, *zrN = zrB, *ztN = ztB;
        for (int it = 0; it < 6; ++it) {
            pgemm1_k<<<dim3(4, NHEAD), 256, 0, stream>>>(a2_16, zt, xz16, t1T16);
            pgemm3_k<<<dim3(4, NHEAD), 256, 0, stream>>>(xz16, t1T16, zr, zrN, ztN);
            __hip_bfloat16* t;
            t = zr; zr = zrN; zrN = t;
            t = zt; zt = ztN; ztN = t;
        }
        a3v_flash_k<<<dim3(32, A3V_TC), 128, 0, stream>>>(ql16, qkvb16, vT16, opart, mpart, lpart);
        a3v_comb_k<<<64, 64, 0, stream>>>(opart, mpart, lpart, a3vT16);
        wm_k<<<NHEAD, 256, 0, stream>>>(zr, a3vT16, wmT16);
        attnout_mfma_k<<<dim3(NP / 64, NHEAD), 128, 0, stream>>>(qkvb16, kl16, wmT16, obuf);
        resconv_tile_k<<<dim3(NP / 128, NHEAD), 256, 0, stream>>>(qkvb16, rw, obuf, obuf2);
        transcvt_k<<<(DIMF / 32) * (DIMF / 32), 256, 0, stream>>>(ow, wT, DIMF, DIMF);
        gemm_bf16_k<<<dim3(DIMF / 128, (NT + 127) / 128), 256, 0, stream>>>(
            obuf2 + (size_t)PADR * DIMF, wT, ob, xv, xv, nullptr, NT, DIMF, DIMF, NT, 0);
    };

    layer(x, l1_ng, l1_nb, l1_qkv, l1_ow, l1_ob, l1_rw);

    ppeg2_k<<<dim3(256, 8), 256, 0, stream>>>(x, p_w7, p_b7, p_w5, p_b5, p_w3, p_b3, x2 + DIMF);
    hipMemcpyAsync(x2, x, DIMF * sizeof(float), hipMemcpyDeviceToDevice, stream);

    layer(x2, l2_ng, l2_nb, l2_qkv, l2_ow, l2_ob, l2_rw);

    head_k<<<1, 64, 0, stream>>>(x2, n_g, n_b, fc2_w, fc2_b, (float*)d_out);
}

// Round 7
// 1344.130 us; speedup vs baseline: 5.1222x; 1.0660x over previous
//
#include <hip/hip_runtime.h>
#include <hip/hip_bf16.h>

// TransMIL forward. Round 7: conflict-free float2 PPEG, 4-wave landmark,
// LDS-tiled zinit; bf16-MFMA pinv chain, MFMA flash a3v + attnout, MFMA GEMMs.

#define NT 16385
#define NP 16640
#define PADR 255
#define DIMF 512
#define QKVW 1536
#define NHEAD 8
#define DH 64
#define NLM 256
#define LSEG 65
#define A3V_TC 20

typedef short bf16x8 __attribute__((ext_vector_type(8)));
typedef short bf16x4 __attribute__((ext_vector_type(4)));
typedef float f32x4 __attribute__((ext_vector_type(4)));

__device__ __forceinline__ void gload_lds16(const void* g, void* l) {
    __builtin_amdgcn_global_load_lds(
        (const __attribute__((address_space(1))) void*)g,
        (__attribute__((address_space(3))) void*)l, 16, 0, 0);
}

__device__ __forceinline__ float2 b2f(const __hip_bfloat16* p) {
    ushort2 u = *(const ushort2*)p;
    float2 r;
    r.x = __uint_as_float((unsigned)u.x << 16);
    r.y = __uint_as_float((unsigned)u.y << 16);
    return r;
}

__device__ __forceinline__ unsigned f2b16(float a, float b) {
    union { unsigned u; __hip_bfloat16 h[2]; } c;
    c.h[0] = __float2bfloat16(a); c.h[1] = __float2bfloat16(b);
    return c.u;
}

__device__ __forceinline__ bf16x4 f4b(float a, float b, float c, float d) {
    union { bf16x4 v; __hip_bfloat16 h[4]; } u;
    u.h[0] = __float2bfloat16(a); u.h[1] = __float2bfloat16(b);
    u.h[2] = __float2bfloat16(c); u.h[3] = __float2bfloat16(d);
    return u.v;
}

// ---------------- bf16 MFMA GEMM: C = A[MxK]@BT[NxK]^T + bias (+Cacc)(+relu)
__global__ __launch_bounds__(256) void gemm_bf16_k(
    const __hip_bfloat16* __restrict__ A, const __hip_bfloat16* __restrict__ BT,
    const float* __restrict__ bias, const float* __restrict__ Cacc,
    float* __restrict__ C, __hip_bfloat16* __restrict__ C16,
    int M, int N, int K, int MA, int relu)
{
    __shared__ __align__(16) __hip_bfloat16 Asl[128 * 64];
    __shared__ __align__(16) __hip_bfloat16 Bsl[128 * 64];
    int tid = threadIdx.x;
    int wid = tid >> 6, lane = tid & 63;
    int m0 = blockIdx.y << 7, n0 = blockIdx.x << 7;
    int wr = (wid >> 1) << 6, wc = (wid & 1) << 6;
    f32x4 acc[4][4] = {};
    int lr = lane >> 3, lk = (lane & 7) << 3;
    for (int kt = 0; kt < K; kt += 64) {
#pragma unroll
        for (int i = 0; i < 4; ++i) {
            int ch = wid * 4 + i;
            int rowA = m0 + ch * 8 + lr;
            rowA = rowA < MA ? rowA : (MA - 1);
            gload_lds16(A + (size_t)rowA * K + kt + lk, &Asl[ch * 512]);
            int rowB = n0 + ch * 8 + lr;
            gload_lds16(BT + (size_t)rowB * K + kt + lk, &Bsl[ch * 512]);
        }
        __syncthreads();
#pragma unroll
        for (int ks = 0; ks < 2; ++ks) {
            int kb = ks * 32 + (lane >> 4) * 8;
            bf16x8 af[4], bfr[4];
#pragma unroll
            for (int m = 0; m < 4; ++m)
                af[m] = *(const bf16x8*)&Asl[(wr + m * 16 + (lane & 15)) * 64 + kb];
#pragma unroll
            for (int n = 0; n < 4; ++n)
                bfr[n] = *(const bf16x8*)&Bsl[(wc + n * 16 + (lane & 15)) * 64 + kb];
#pragma unroll
            for (int m = 0; m < 4; ++m)
#pragma unroll
                for (int n = 0; n < 4; ++n)
                    acc[m][n] = __builtin_amdgcn_mfma_f32_16x16x32_bf16(
                        af[m], bfr[n], acc[m][n], 0, 0, 0);
        }
        __syncthreads();
    }
    int cr = (lane >> 4) << 2, cc = lane & 15;
#pragma unroll
    for (int m = 0; m < 4; ++m) {
#pragma unroll
        for (int i = 0; i < 4; ++i) {
            int gm = m0 + wr + m * 16 + cr + i;
            if (gm >= M) continue;
#pragma unroll
            for (int n = 0; n < 4; ++n) {
                int gn = n0 + wc + n * 16 + cc;
                float v = acc[m][n][i];
                if (bias) v += bias[gn];
                if (Cacc) v += Cacc[(size_t)gm * N + gn];
                if (relu) v = fmaxf(v, 0.f);
                if (C16) C16[(size_t)gm * N + gn] = __float2bfloat16(v);
                else C[(size_t)gm * N + gn] = v;
            }
        }
    }
}

// ---------------- fp32 [KxN] -> bf16 [NxK] tiled transpose-convert
__global__ __launch_bounds__(256) void transcvt_k(const float* __restrict__ W,
    __hip_bfloat16* __restrict__ WT, int K, int N)
{
    __shared__ float t[32][33];
    int nt = N >> 5;
    int n0 = (blockIdx.x % nt) << 5, k0 = (blockIdx.x / nt) << 5;
    int tx = threadIdx.x & 31, ty = threadIdx.x >> 5;
    for (int r = ty; r < 32; r += 8) t[r][tx] = W[(size_t)(k0 + r) * N + n0 + tx];
    __syncthreads();
    for (int r = ty; r < 32; r += 8)
        WT[(size_t)(n0 + r) * K + k0 + tx] = __float2bfloat16(t[tx][r]);
}

// ---------------- fp32 -> bf16 convert (vectorized)
__global__ __launch_bounds__(256) void cvt_k(const float4* __restrict__ in,
    ushort4* __restrict__ out, int n4)
{
    int i = blockIdx.x * 256 + threadIdx.x;
    if (i >= n4) return;
    float4 v = in[i];
    union { __hip_bfloat16 h[4]; ushort4 u; } cv;
    cv.h[0] = __float2bfloat16(v.x); cv.h[1] = __float2bfloat16(v.y);
    cv.h[2] = __float2bfloat16(v.z); cv.h[3] = __float2bfloat16(v.w);
    out[i] = cv.u;
}

// ---------------- v transpose: vT16[h][d][t]
__global__ __launch_bounds__(256) void vtrans_k(const __hip_bfloat16* __restrict__ qkvb16,
    __hip_bfloat16* __restrict__ vT16)
{
    int h = blockIdx.y;
    int t0 = blockIdx.x << 6;
    __shared__ float tile[64][65];
    int tid = threadIdx.x;
    for (int e = tid; e < 512; e += 256) {
        int r = e >> 3, c8 = (e & 7) << 3;
        union { bf16x8 v; __hip_bfloat16 hh[8]; } u;
        u.v = *(const bf16x8*)(qkvb16 + (size_t)(t0 + r) * QKVW + 1024 + (h << 6) + c8);
#pragma unroll
        for (int j = 0; j < 8; ++j) tile[r][c8 + j] = __bfloat162float(u.hh[j]);
    }
    __syncthreads();
    for (int e = tid; e < 512; e += 256) {
        int d = e >> 3, t8 = (e & 7) << 3;
        union { bf16x8 v; __hip_bfloat16 hh[8]; } u;
#pragma unroll
        for (int j = 0; j < 8; ++j) u.hh[j] = __float2bfloat16(tile[t8 + j][d]);
        *(bf16x8*)(vT16 + ((size_t)(h << 6) + d) * NP + t0 + t8) = u.v;
    }
}

// ---------------- LayerNorm per row (512) -> bf16 out
__global__ __launch_bounds__(64) void ln_k(const float* __restrict__ in,
    const float* __restrict__ g, const float* __restrict__ b,
    __hip_bfloat16* __restrict__ out, int rows)
{
    int r = blockIdx.x;
    if (r >= rows) return;
    int lane = threadIdx.x;
    const float* xr = in + (size_t)r * DIMF;
    float v[8], s = 0.f;
#pragma unroll
    for (int i = 0; i < 8; ++i) { v[i] = xr[i * 64 + lane]; s += v[i]; }
#pragma unroll
    for (int off = 32; off; off >>= 1) s += __shfl_xor(s, off);
    float mu = s * (1.f / 512.f);
    float vs = 0.f;
#pragma unroll
    for (int i = 0; i < 8; ++i) { float d = v[i] - mu; vs += d * d; }
#pragma unroll
    for (int off = 32; off; off >>= 1) vs += __shfl_xor(vs, off);
    float rstd = rsqrtf(vs * (1.f / 512.f) + 1e-5f);
    __hip_bfloat16* orow = out + (size_t)r * DIMF;
#pragma unroll
    for (int i = 0; i < 8; ++i) {
        int d = i * 64 + lane;
        orow[d] = __float2bfloat16((v[i] - mu) * rstd * g[d] + b[d]);
    }
}

// ---------------- landmark means, 4 waves split the 65-row sum
__global__ __launch_bounds__(256) void landmark_k(const __hip_bfloat16* __restrict__ qkvb16,
    float* __restrict__ ql, float* __restrict__ kl,
    __hip_bfloat16* __restrict__ ql16, __hip_bfloat16* __restrict__ kl16)
{
    int bx = blockIdx.x;
    int h = bx >> 8, j = bx & 255;
    int w = threadIdx.x >> 6, d = threadIdx.x & 63;
    __shared__ float pq[4][64], pk[4][64];
    float qs = 0.f, ks = 0.f;
    for (int u = w; u < LSEG; u += 4) {
        size_t addr = (size_t)(j * LSEG + u) * QKVW + (h << 6) + d;
        qs += __bfloat162float(qkvb16[addr]);
        ks += __bfloat162float(qkvb16[addr + 512]);
    }
    pq[w][d] = qs; pk[w][d] = ks;
    __syncthreads();
    if (threadIdx.x < 64) {
        float q = pq[0][d] + pq[1][d] + pq[2][d] + pq[3][d];
        float k = pk[0][d] + pk[1][d] + pk[2][d] + pk[3][d];
        float qm = q * (1.f / 65.f) * 0.125f;
        float km = k * (1.f / 65.f);
        ql[(size_t)bx * 64 + d] = qm;
        kl[(size_t)bx * 64 + d] = km;
        ql16[(size_t)bx * 64 + d] = __float2bfloat16(qm);
        kl16[(size_t)bx * 64 + d] = __float2bfloat16(km);
    }
}

// ---------------- a2 = softmax(q_l @ k_l^T); writes fp32 + bf16 row-major
__global__ __launch_bounds__(256) void a2_k(const float* __restrict__ ql,
    const float* __restrict__ kl, float* __restrict__ a2, __hip_bfloat16* __restrict__ a2_16)
{
    int h = blockIdx.x >> 8, i = blockIdx.x & 255;
    int j = threadIdx.x;
    __shared__ float qs[64];
    __shared__ float red[256];
    if (j < 64) qs[j] = ql[((size_t)(h << 8) + i) * 64 + j];
    __syncthreads();
    const float* kr = kl + ((size_t)(h << 8) + j) * 64;
    float s = 0.f;
#pragma unroll 8
    for (int d = 0; d < 64; ++d) s += qs[d] * kr[d];
    red[j] = s; __syncthreads();
    for (int st = 128; st; st >>= 1) { if (j < st) red[j] = fmaxf(red[j], red[j + st]); __syncthreads(); }
    float mx = red[0]; __syncthreads();
    float p = __expf(s - mx);
    red[j] = p; __syncthreads();
    for (int st = 128; st; st >>= 1) { if (j < st) red[j] += red[j + st]; __syncthreads(); }
    float v = p / red[0];
    a2[((size_t)h << 16) + i * 256 + j] = v;
    a2_16[((size_t)h << 16) + i * 256 + j] = __float2bfloat16(v);
}

// ---------------- pinv init: z = a2^T/(maxrow*maxcol); LDS-tiled transpose
__global__ __launch_bounds__(256) void zinit_k(const float* __restrict__ a2,
    __hip_bfloat16* __restrict__ zr16, __hip_bfloat16* __restrict__ zT16)
{
    int h = blockIdx.x, t = threadIdx.x;
    const float* X = a2 + ((size_t)h << 16);
    __shared__ float red[256];
    __shared__ float tl[64][65];
    // rowsum (vectorized float4), then max across rows
    float rs = 0.f;
    const float4* Xr = (const float4*)(X + (size_t)t * 256);
    for (int j = 0; j < 64; ++j) {
        float4 v = Xr[j];
        rs += fabsf(v.x) + fabsf(v.y) + fabsf(v.z) + fabsf(v.w);
    }
    red[t] = rs; __syncthreads();
    for (int st = 128; st; st >>= 1) { if (t < st) red[t] = fmaxf(red[t], red[t + st]); __syncthreads(); }
    float colv = red[0]; __syncthreads();
    // colsum (coalesced), then max
    float cs = 0.f;
    for (int i = 0; i < 256; ++i) cs += fabsf(X[i * 256 + t]);
    red[t] = cs; __syncthreads();
    for (int st = 128; st; st >>= 1) { if (t < st) red[t] = fmaxf(red[t], red[t + st]); __syncthreads(); }
    float rowv = red[0];
    float inv = 1.f / (colv * rowv);
    // tiled transpose + scale: zr16 = X^T*inv (transposed), zT16 = X*inv (direct)
    int cl = t & 63, rg = t >> 6;
    for (int tr = 0; tr < 4; ++tr)
        for (int tc = 0; tc < 4; ++tc) {
            __syncthreads();
#pragma unroll
            for (int k = 0; k < 16; ++k) {
                int rl = (k << 2) + rg;
                tl[rl][cl] = X[(size_t)(tr * 64 + rl) * 256 + tc * 64 + cl];
            }
            __syncthreads();
#pragma unroll
            for (int k = 0; k < 16; ++k) {
                int rl = (k << 2) + rg;
                zT16[((size_t)h << 16) + (size_t)(tr * 64 + rl) * 256 + tc * 64 + cl] =
                    __float2bfloat16(tl[rl][cl] * inv);
                zr16[((size_t)h << 16) + (size_t)(tc * 64 + rl) * 256 + tr * 64 + cl] =
                    __float2bfloat16(tl[cl][rl] * inv);
            }
        }
}

// ---------------- pinv G1: xz = a2 @ Z. Writes xz16 + t1T16=7I-xz^T.
__global__ __launch_bounds__(256) void pgemm1_k(
    const __hip_bfloat16* __restrict__ a2_16, const __hip_bfloat16* __restrict__ zT16,
    __hip_bfloat16* __restrict__ xz16, __hip_bfloat16* __restrict__ t1T16)
{
    int h = blockIdx.y, n0 = blockIdx.x << 6;
    int lane = threadIdx.x & 63;
    int r0 = (threadIdx.x >> 6) << 6;
    int rA = lane & 15, g = lane >> 4, kp = g << 3;
    const __hip_bfloat16* Ah = a2_16 + ((size_t)h << 16);
    const __hip_bfloat16* Bh = zT16 + ((size_t)h << 16);
    f32x4 acc[4][4] = {};
    for (int ks = 0; ks < 8; ++ks) {
        bf16x8 af[4], bfr[4];
#pragma unroll
        for (int m = 0; m < 4; ++m)
            af[m] = *(const bf16x8*)&Ah[(size_t)(r0 + m * 16 + rA) * 256 + ks * 32 + kp];
#pragma unroll
        for (int n = 0; n < 4; ++n)
            bfr[n] = *(const bf16x8*)&Bh[(size_t)(n0 + n * 16 + rA) * 256 + ks * 32 + kp];
#pragma unroll
        for (int m = 0; m < 4; ++m)
#pragma unroll
            for (int n = 0; n < 4; ++n)
                acc[m][n] = __builtin_amdgcn_mfma_f32_16x16x32_bf16(af[m], bfr[n], acc[m][n], 0, 0, 0);
    }
    __hip_bfloat16* xzh = xz16 + ((size_t)h << 16);
    __hip_bfloat16* t1h = t1T16 + ((size_t)h << 16);
#pragma unroll
    for (int m = 0; m < 4; ++m)
#pragma unroll
        for (int i = 0; i < 4; ++i) {
            int gr = r0 + m * 16 + (g << 2) + i;
#pragma unroll
            for (int n = 0; n < 4; ++n) {
                int gc = n0 + n * 16 + rA;
                float v = acc[m][n][i];
                xzh[(size_t)gr * 256 + gc] = __float2bfloat16(v);
                t1h[(size_t)gc * 256 + gr] = __float2bfloat16((gr == gc ? 7.f : 0.f) - v);
            }
        }
}

// ---------------- pinv G2+G3+G4 fused per column-stripe
__global__ __launch_bounds__(256) void pgemm3_k(
    const __hip_bfloat16* __restrict__ xz16, const __hip_bfloat16* __restrict__ t1T16,
    const __hip_bfloat16* __restrict__ zr16,
    __hip_bfloat16* __restrict__ znr16, __hip_bfloat16* __restrict__ znT16)
{
    __shared__ __align__(16) __hip_bfloat16 tA[64][264];
    __shared__ __align__(16) __hip_bfloat16 tB[64][264];
    int h = blockIdx.y, n0 = blockIdx.x << 6;
    int lane = threadIdx.x & 63;
    int r0 = (threadIdx.x >> 6) << 6;
    int rA = lane & 15, g = lane >> 4, kp = g << 3;
    const __hip_bfloat16* Xh = xz16 + ((size_t)h << 16);
    const __hip_bfloat16* T1h = t1T16 + ((size_t)h << 16);
    {
        f32x4 acc[4][4] = {};
        for (int ks = 0; ks < 8; ++ks) {
            bf16x8 af[4], bfr[4];
#pragma unroll
            for (int m = 0; m < 4; ++m)
                af[m] = *(const bf16x8*)&Xh[(size_t)(r0 + m * 16 + rA) * 256 + ks * 32 + kp];
#pragma unroll
            for (int n = 0; n < 4; ++n)
                bfr[n] = *(const bf16x8*)&T1h[(size_t)(n0 + n * 16 + rA) * 256 + ks * 32 + kp];
#pragma unroll
            for (int m = 0; m < 4; ++m)
#pragma unroll
                for (int n = 0; n < 4; ++n)
                    acc[m][n] = __builtin_amdgcn_mfma_f32_16x16x32_bf16(af[m], bfr[n], acc[m][n], 0, 0, 0);
        }
#pragma unroll
        for (int m = 0; m < 4; ++m)
#pragma unroll
            for (int n = 0; n < 4; ++n) {
                int gr0 = r0 + m * 16 + (g << 2);
                int cl = n * 16 + rA;
                *(bf16x4*)&tA[cl][gr0] = f4b(
                    ((gr0 + 0 == n0 + cl) ? 15.f : 0.f) - acc[m][n][0],
                    ((gr0 + 1 == n0 + cl) ? 15.f : 0.f) - acc[m][n][1],
                    ((gr0 + 2 == n0 + cl) ? 15.f : 0.f) - acc[m][n][2],
                    ((gr0 + 3 == n0 + cl) ? 15.f : 0.f) - acc[m][n][3]);
            }
    }
    __syncthreads();
    {
        f32x4 acc[4][4] = {};
        for (int ks = 0; ks < 8; ++ks) {
            bf16x8 af[4], bfr[4];
#pragma unroll
            for (int m = 0; m < 4; ++m)
                af[m] = *(const bf16x8*)&Xh[(size_t)(r0 + m * 16 + rA) * 256 + ks * 32 + kp];
#pragma unroll
            for (int n = 0; n < 4; ++n)
                bfr[n] = *(const bf16x8*)&tA[n * 16 + rA][ks * 32 + kp];
#pragma unroll
            for (int m = 0; m < 4; ++m)
#pragma unroll
                for (int n = 0; n < 4; ++n)
                    acc[m][n] = __builtin_amdgcn_mfma_f32_16x16x32_bf16(af[m], bfr[n], acc[m][n], 0, 0, 0);
        }
#pragma unroll
        for (int m = 0; m < 4; ++m)
#pragma unroll
            for (int n = 0; n < 4; ++n) {
                int gr0 = r0 + m * 16 + (g << 2);
                int cl = n * 16 + rA;
                *(bf16x4*)&tB[cl][gr0] = f4b(
                    ((gr0 + 0 == n0 + cl) ? 13.f : 0.f) - acc[m][n][0],
                    ((gr0 + 1 == n0 + cl) ? 13.f : 0.f) - acc[m][n][1],
                    ((gr0 + 2 == n0 + cl) ? 13.f : 0.f) - acc[m][n][2],
                    ((gr0 + 3 == n0 + cl) ? 13.f : 0.f) - acc[m][n][3]);
            }
    }
    __syncthreads();
    {
        const __hip_bfloat16* Zh = zr16 + ((size_t)h << 16);
        f32x4 acc[4][4] = {};
        for (int ks = 0; ks < 8; ++ks) {
            bf16x8 af[4], bfr[4];
#pragma unroll
            for (int m = 0; m < 4; ++m)
                af[m] = *(const bf16x8*)&Zh[(size_t)(r0 + m * 16 + rA) * 256 + ks * 32 + kp];
#pragma unroll
            for (int n = 0; n < 4; ++n)
                bfr[n] = *(const bf16x8*)&tB[n * 16 + rA][ks * 32 + kp];
#pragma unroll
            for (int m = 0; m < 4; ++m)
#pragma unroll
                for (int n = 0; n < 4; ++n)
                    acc[m][n] = __builtin_amdgcn_mfma_f32_16x16x32_bf16(af[m], bfr[n], acc[m][n], 0, 0, 0);
        }
        __hip_bfloat16* zrh = znr16 + ((size_t)h << 16);
        __hip_bfloat16* zth = znT16 + ((size_t)h << 16);
#pragma unroll
        for (int m = 0; m < 4; ++m)
#pragma unroll
            for (int i = 0; i < 4; ++i) {
                int gr = r0 + m * 16 + (g << 2) + i;
#pragma unroll
                for (int n = 0; n < 4; ++n) {
                    int gc = n0 + n * 16 + rA;
                    float v = 0.25f * acc[m][n][i];
                    zrh[(size_t)gr * 256 + gc] = __float2bfloat16(v);
                    zth[(size_t)gc * 256 + gr] = __float2bfloat16(v);
                }
            }
    }
}

// ---------------- wm = Zfinal @ a3v -> wmT16
__global__ __launch_bounds__(256) void wm_k(
    const __hip_bfloat16* __restrict__ zr16, const __hip_bfloat16* __restrict__ a3vT16,
    __hip_bfloat16* __restrict__ wmT16)
{
    int h = blockIdx.x;
    int lane = threadIdx.x & 63;
    int r0 = (threadIdx.x >> 6) << 6;
    int rA = lane & 15, g = lane >> 4, kp = g << 3;
    const __hip_bfloat16* Zh = zr16 + ((size_t)h << 16);
    const __hip_bfloat16* Bh = a3vT16 + ((size_t)h << 14);
    f32x4 acc[4][4] = {};
    for (int ks = 0; ks < 8; ++ks) {
        bf16x8 af[4], bfr[4];
#pragma unroll
        for (int m = 0; m < 4; ++m)
            af[m] = *(const bf16x8*)&Zh[(size_t)(r0 + m * 16 + rA) * 256 + ks * 32 + kp];
#pragma unroll
        for (int n = 0; n < 4; ++n)
            bfr[n] = *(const bf16x8*)&Bh[(size_t)(n * 16 + rA) * 256 + ks * 32 + kp];
#pragma unroll
        for (int m = 0; m < 4; ++m)
#pragma unroll
            for (int n = 0; n < 4; ++n)
                acc[m][n] = __builtin_amdgcn_mfma_f32_16x16x32_bf16(af[m], bfr[n], acc[m][n], 0, 0, 0);
    }
    __hip_bfloat16* Wh = wmT16 + ((size_t)h << 14);
#pragma unroll
    for (int m = 0; m < 4; ++m)
#pragma unroll
        for (int i = 0; i < 4; ++i) {
            int gr = r0 + m * 16 + (g << 2) + i;
#pragma unroll
            for (int n = 0; n < 4; ++n)
                Wh[(size_t)(n * 16 + rA) * 256 + gr] = __float2bfloat16(acc[m][n][i]);
        }
}

// ---------------- MFMA flash a3v partials
__global__ __launch_bounds__(128) void a3v_flash_k(
    const __hip_bfloat16* __restrict__ ql16, const __hip_bfloat16* __restrict__ qkvb16,
    const __hip_bfloat16* __restrict__ vT16,
    float* __restrict__ opart, float* __restrict__ mpart, float* __restrict__ lpart)
{
    int bx = blockIdx.x;
    int h = bx >> 2, qb = bx & 3;
    int tc = blockIdx.y;
    int wv = threadIdx.x >> 6;
    int lane = threadIdx.x & 63;
    int rA = lane & 15, g = lane >> 4, kp = g << 3;
    __shared__ __align__(16) __hip_bfloat16 Plds[2][32 * 64];
    char* P = (char*)&Plds[wv][0];

    bf16x8 qa[2][2];
    const __hip_bfloat16* qlh = ql16 + ((size_t)h << 14);
#pragma unroll
    for (int m = 0; m < 2; ++m)
#pragma unroll
        for (int ks = 0; ks < 2; ++ks)
            qa[m][ks] = *(const bf16x8*)(qlh +
                (size_t)((qb << 6) + (wv << 5) + (m << 4) + rA) * 64 + ks * 32 + kp);

    const __hip_bfloat16* kg = qkvb16 + 512 + (h << 6);
    const __hip_bfloat16* vg = vT16 + ((size_t)(h << 6)) * NP;

    f32x4 O[2][4] = {};
    float m_[2][4], l_[2][4];
#pragma unroll
    for (int m = 0; m < 2; ++m)
#pragma unroll
        for (int i = 0; i < 4; ++i) { m_[m][i] = -3e38f; l_[m][i] = 0.f; }

    for (int tile = tc * 13; tile < tc * 13 + 13; ++tile) {
        int t0 = tile << 6;
        f32x4 S[2][4] = {};
#pragma unroll
        for (int n = 0; n < 4; ++n)
#pragma unroll
            for (int ks = 0; ks < 2; ++ks) {
                bf16x8 kb = *(const bf16x8*)(kg + (size_t)(t0 + (n << 4) + rA) * QKVW + ks * 32 + kp);
                S[0][n] = __builtin_amdgcn_mfma_f32_16x16x32_bf16(qa[0][ks], kb, S[0][n], 0, 0, 0);
                S[1][n] = __builtin_amdgcn_mfma_f32_16x16x32_bf16(qa[1][ks], kb, S[1][n], 0, 0, 0);
            }
        float f_[2][4];
#pragma unroll
        for (int m = 0; m < 2; ++m)
#pragma unroll
            for (int i = 0; i < 4; ++i) {
                float mx = fmaxf(fmaxf(S[m][0][i], S[m][1][i]), fmaxf(S[m][2][i], S[m][3][i]));
#pragma unroll
                for (int msk = 8; msk; msk >>= 1) mx = fmaxf(mx, __shfl_xor(mx, msk));
                float mn = fmaxf(m_[m][i], mx);
                float f = __expf(m_[m][i] - mn);
                int r = (m << 4) + (g << 2) + i;
                int swz = (r & 7) << 4;
                float sum = 0.f;
#pragma unroll
                for (int n = 0; n < 4; ++n) {
                    float p = __expf(S[m][n][i] - mn);
                    sum += p;
                    int byte = (r << 7) + (((n << 4) + rA) << 1);
                    *(__hip_bfloat16*)(P + (byte ^ swz)) = __float2bfloat16(p);
                }
#pragma unroll
                for (int msk = 8; msk; msk >>= 1) sum += __shfl_xor(sum, msk);
                l_[m][i] = l_[m][i] * f + sum;
                m_[m][i] = mn;
                f_[m][i] = f;
            }
#pragma unroll
        for (int m = 0; m < 2; ++m)
#pragma unroll
            for (int i = 0; i < 4; ++i) {
                float f = f_[m][i];
#pragma unroll
                for (int n = 0; n < 4; ++n) O[m][n][i] *= f;
            }
#pragma unroll
        for (int ks2 = 0; ks2 < 2; ++ks2) {
            bf16x8 pa[2];
#pragma unroll
            for (int m = 0; m < 2; ++m) {
                int rr = (m << 4) + rA;
                int byte = (rr << 7) + ((ks2 * 32 + kp) << 1);
                pa[m] = *(const bf16x8*)(P + (byte ^ ((rr & 7) << 4)));
            }
#pragma unroll
            for (int n = 0; n < 4; ++n) {
                bf16x8 vb = *(const bf16x8*)(vg + (size_t)((n << 4) + rA) * NP + t0 + ks2 * 32 + kp);
                O[0][n] = __builtin_amdgcn_mfma_f32_16x16x32_bf16(pa[0], vb, O[0][n], 0, 0, 0);
                O[1][n] = __builtin_amdgcn_mfma_f32_16x16x32_bf16(pa[1], vb, O[1][n], 0, 0, 0);
            }
        }
    }
    int pb2 = (bx << 1) | wv;
    size_t obase = ((size_t)pb2 * A3V_TC + tc) * 2048;
#pragma unroll
    for (int m = 0; m < 2; ++m)
#pragma unroll
        for (int i = 0; i < 4; ++i) {
            int r = (m << 4) + (g << 2) + i;
#pragma unroll
            for (int n = 0; n < 4; ++n)
                opart[obase + (size_t)r * 64 + (n << 4) + rA] = O[m][n][i];
            if (rA == 0) {
                mpart[((size_t)pb2 * A3V_TC + tc) * 32 + r] = m_[m][i];
                lpart[((size_t)pb2 * A3V_TC + tc) * 32 + r] = l_[m][i];
            }
        }
}

// ---------------- a3v combine -> a3vT16[h][d][j] bf16
__global__ __launch_bounds__(64) void a3v_comb_k(const float* __restrict__ opart,
    const float* __restrict__ mpart, const float* __restrict__ lpart,
    __hip_bfloat16* __restrict__ a3vT16)
{
    int pb = blockIdx.x, d = threadIdx.x;
    int h = pb >> 3;
    for (int r = 0; r < 32; ++r) {
        float M = -3e38f;
        for (int tc = 0; tc < A3V_TC; ++tc)
            M = fmaxf(M, mpart[((size_t)pb * A3V_TC + tc) * 32 + r]);
        float L = 0.f, od = 0.f;
        for (int tc = 0; tc < A3V_TC; ++tc) {
            float w = __expf(mpart[((size_t)pb * A3V_TC + tc) * 32 + r] - M);
            L += lpart[((size_t)pb * A3V_TC + tc) * 32 + r] * w;
            od += w * opart[((size_t)pb * A3V_TC + tc) * 2048 + (size_t)r * 64 + d];
        }
        int j = ((pb & 7) << 5) + r;
        a3vT16[((size_t)((h << 6) + d) << 8) + j] = __float2bfloat16(od / L);
    }
}

// ---------------- MFMA fused sim1-softmax @ Wm
__global__ __launch_bounds__(128) void attnout_mfma_k(
    const __hip_bfloat16* __restrict__ qkvb16, const __hip_bfloat16* __restrict__ kl16,
    const __hip_bfloat16* __restrict__ wmT16, float* __restrict__ o)
{
    int h = blockIdx.y;
    int rbase = (blockIdx.x << 6) + ((threadIdx.x >> 6) << 5);
    int lane = threadIdx.x & 63;
    int rA = lane & 15;
    int g = lane >> 4;
    int kp = g << 3;
    __shared__ __align__(16) __hip_bfloat16 Plds[2][32 * 256];
    char* P = (char*)&Plds[threadIdx.x >> 6][0];

    bf16x8 qa[2][2];
#pragma unroll
    for (int m = 0; m < 2; ++m)
#pragma unroll
        for (int ks = 0; ks < 2; ++ks)
            qa[m][ks] = *(const bf16x8*)(qkvb16 +
                (size_t)(rbase + m * 16 + rA) * QKVW + (h << 6) + ks * 32 + kp);

    const __hip_bfloat16* klh = kl16 + ((size_t)h << 14);
    f32x4 S[2][16] = {};
#pragma unroll
    for (int n = 0; n < 16; ++n) {
#pragma unroll
        for (int ks = 0; ks < 2; ++ks) {
            bf16x8 kb = *(const bf16x8*)(klh + (size_t)((n << 4) + rA) * 64 + ks * 32 + kp);
            S[0][n] = __builtin_amdgcn_mfma_f32_16x16x32_bf16(qa[0][ks], kb, S[0][n], 0, 0, 0);
            S[1][n] = __builtin_amdgcn_mfma_f32_16x16x32_bf16(qa[1][ks], kb, S[1][n], 0, 0, 0);
        }
    }
#pragma unroll
    for (int m = 0; m < 2; ++m)
#pragma unroll
        for (int n = 0; n < 16; ++n) S[m][n] *= 0.125f;

    float lsum[2][4];
#pragma unroll
    for (int m = 0; m < 2; ++m)
#pragma unroll
        for (int i = 0; i < 4; ++i) {
            float mx = -3e38f;
#pragma unroll
            for (int n = 0; n < 16; ++n) mx = fmaxf(mx, S[m][n][i]);
#pragma unroll
            for (int msk = 8; msk; msk >>= 1) mx = fmaxf(mx, __shfl_xor(mx, msk));
            float sum = 0.f;
            int r = (m << 4) + (g << 2) + i;
            int swz = (r & 7) << 4;
#pragma unroll
            for (int n = 0; n < 16; ++n) {
                float p = __expf(S[m][n][i] - mx);
                sum += p;
                int byte = (r << 9) + (((n << 4) + rA) << 1);
                *(__hip_bfloat16*)(P + (byte ^ swz)) = __float2bfloat16(p);
            }
#pragma unroll
            for (int msk = 8; msk; msk >>= 1) sum += __shfl_xor(sum, msk);
            lsum[m][i] = sum;
        }

    const __hip_bfloat16* wmh = wmT16 + ((size_t)h << 14);
    f32x4 O[2][4] = {};
#pragma unroll
    for (int kc = 0; kc < 8; ++kc) {
        bf16x8 pa[2];
#pragma unroll
        for (int m = 0; m < 2; ++m) {
            int rr = (m << 4) + rA;
            int byte = (rr << 9) + (((kc << 5) + kp) << 1);
            pa[m] = *(const bf16x8*)(P + (byte ^ ((rr & 7) << 4)));
        }
#pragma unroll
        for (int n = 0; n < 4; ++n) {
            bf16x8 wb = *(const bf16x8*)(wmh + (size_t)((n << 4) + rA) * 256 + (kc << 5) + kp);
#pragma unroll
            for (int m = 0; m < 2; ++m)
                O[m][n] = __builtin_amdgcn_mfma_f32_16x16x32_bf16(pa[m], wb, O[m][n], 0, 0, 0);
        }
    }
#pragma unroll
    for (int m = 0; m < 2; ++m)
#pragma unroll
        for (int i = 0; i < 4; ++i) {
            float inv = 1.f / lsum[m][i];
            int gm = rbase + (m << 4) + (g << 2) + i;
#pragma unroll
            for (int n = 0; n < 4; ++n)
                o[(size_t)gm * DIMF + (h << 6) + (n << 4) + rA] = O[m][n][i] * inv;
        }
}

// ---------------- resconv (33-tap along seq) + convert to bf16
__global__ __launch_bounds__(256) void resconv_tile_k(const __hip_bfloat16* __restrict__ qkvb16,
    const float* __restrict__ rw, const float* __restrict__ oin,
    __hip_bfloat16* __restrict__ oout)
{
    int cg = blockIdx.y;
    int t0 = blockIdx.x << 7;
    int tid = threadIdx.x;
    int lane = tid & 63, w = tid >> 6;
    __shared__ float vt[160][64];
    __shared__ float wr[33];
    if (tid < 33) wr[tid] = rw[cg * 33 + tid];
    for (int e = tid; e < 160 * 64; e += 256) {
        int tt = e >> 6, l = e & 63;
        int t = t0 - 16 + tt;
        vt[tt][l] = (t >= 0 && t < NP)
            ? __bfloat162float(qkvb16[(size_t)t * QKVW + 1024 + (cg << 6) + l]) : 0.f;
    }
    __syncthreads();
    for (int i = 0; i < 32; ++i) {
        int tl = (w << 5) + i;
        float acc = 0.f;
#pragma unroll
        for (int ky = 0; ky < 33; ++ky) acc += wr[ky] * vt[tl + ky][lane];
        size_t oi = (size_t)(t0 + tl) * DIMF + (cg << 6) + lane;
        oout[oi] = __float2bfloat16(oin[oi] + acc);
    }
}

// ---------------- PPEG v3: 32 ch/block, float2/thread, conflict-free bf16 LDS
__global__ __launch_bounds__(256) void ppeg3_k(const float* __restrict__ x,
    const float* __restrict__ w7, const float* __restrict__ b7,
    const float* __restrict__ w5, const float* __restrict__ b5,
    const float* __restrict__ w3, const float* __restrict__ b3,
    float* __restrict__ outfeat)
{
    int cg = blockIdx.y;                       // 0..15 -> 32 channels
    int ty0 = (blockIdx.x >> 4) << 3, tx0 = (blockIdx.x & 15) << 3;
    int tid = threadIdx.x;
    int cgi = tid & 15;                        // channel pair
    int xo = (tid >> 4) & 7;
    int yb0 = (tid >> 7) << 2;                 // 0 or 4
    int c = (cg << 5) + (cgi << 1);
    const float* feat = x + DIMF;
    __shared__ __align__(16) __hip_bfloat16 tile[196][32];
    __shared__ __align__(16) __hip_bfloat16 ws7[49][32];
    __shared__ __align__(16) __hip_bfloat16 ws5[25][32];
    __shared__ __align__(16) __hip_bfloat16 ws3[9][32];
    for (int e = tid; e < 49 * 32; e += 256) {
        int t = e >> 5, cl = e & 31;
        ws7[t][cl] = __float2bfloat16(w7[(size_t)((cg << 5) + cl) * 49 + t]);
    }
    for (int e = tid; e < 25 * 32; e += 256) {
        int t = e >> 5, cl = e & 31;
        ws5[t][cl] = __float2bfloat16(w5[(size_t)((cg << 5) + cl) * 25 + t]);
    }
    for (int e = tid; e < 9 * 32; e += 256) {
        int t = e >> 5, cl = e & 31;
        ws3[t][cl] = __float2bfloat16(w3[(size_t)((cg << 5) + cl) * 9 + t]);
    }
    for (int e = tid; e < 196 * 16; e += 256) {
        int sp = e >> 4, cp = (e & 15) << 1;
        int yy = ty0 - 3 + sp / 14, xc = tx0 - 3 + sp % 14;
        float2 v = make_float2(0.f, 0.f);
        if ((unsigned)yy < 128u && (unsigned)xc < 128u)
            v = *(const float2*)&feat[(size_t)(yy * 128 + xc) * DIMF + (cg << 5) + cp];
        *(unsigned*)&tile[sp][cp] = f2b16(v.x, v.y);
    }
    __syncthreads();
    float2 bs7 = *(const float2*)&b7[c], bs5 = *(const float2*)&b5[c], bs3 = *(const float2*)&b3[c];
    float bsx = bs7.x + bs5.x + bs3.x, bsy = bs7.y + bs5.y + bs3.y;
    float2 acc[4];
#pragma unroll
    for (int o = 0; o < 4; ++o) {
        float2 idv = *(const float2*)&feat[(size_t)((ty0 + yb0 + o) * 128 + tx0 + xo) * DIMF + c];
        acc[o].x = idv.x + bsx;
        acc[o].y = idv.y + bsy;
    }
    int c2 = cgi << 1;
#pragma unroll
    for (int kx = 0; kx < 7; ++kx) {
        float2 wc[7];
#pragma unroll
        for (int j = 0; j < 7; ++j) wc[j] = b2f(&ws7[j * 7 + kx][c2]);
#pragma unroll
        for (int r = 0; r < 10; ++r) {
            float2 v = b2f(&tile[(yb0 + r) * 14 + xo + kx][c2]);
#pragma unroll
            for (int o = 0; o < 4; ++o) {
                int ky = r - o;
                if (ky >= 0 && ky < 7) {
                    acc[o].x += wc[ky].x * v.x; acc[o].y += wc[ky].y * v.y;
                }
            }
        }
    }
#pragma unroll
    for (int kx = 0; kx < 5; ++kx) {
        float2 wc[5];
#pragma unroll
        for (int j = 0; j < 5; ++j) wc[j] = b2f(&ws5[j * 5 + kx][c2]);
#pragma unroll
        for (int r = 0; r < 8; ++r) {
            float2 v = b2f(&tile[(yb0 + 1 + r) * 14 + xo + 1 + kx][c2]);
#pragma unroll
            for (int o = 0; o < 4; ++o) {
                int ky = r - o;
                if (ky >= 0 && ky < 5) {
                    acc[o].x += wc[ky].x * v.x; acc[o].y += wc[ky].y * v.y;
                }
            }
        }
    }
#pragma unroll
    for (int kx = 0; kx < 3; ++kx) {
        float2 wc[3];
#pragma unroll
        for (int j = 0; j < 3; ++j) wc[j] = b2f(&ws3[j * 3 + kx][c2]);
#pragma unroll
        for (int r = 0; r < 6; ++r) {
            float2 v = b2f(&tile[(yb0 + 2 + r) * 14 + xo + 2 + kx][c2]);
#pragma unroll
            for (int o = 0; o < 4; ++o) {
                int ky = r - o;
                if (ky >= 0 && ky < 3) {
                    acc[o].x += wc[ky].x * v.x; acc[o].y += wc[ky].y * v.y;
                }
            }
        }
    }
#pragma unroll
    for (int o = 0; o < 4; ++o)
        *(float2*)&outfeat[(size_t)((ty0 + yb0 + o) * 128 + tx0 + xo) * DIMF + c] = acc[o];
}

// ---------------- final LN(row0) + 2-class head + softmax + argmax
__global__ __launch_bounds__(64) void head_k(const float* __restrict__ x,
    const float* __restrict__ g, const float* __restrict__ b,
    const float* __restrict__ w, const float* __restrict__ bias, float* __restrict__ out)
{
    int lane = threadIdx.x;
    float v[8], s = 0.f;
#pragma unroll
    for (int i = 0; i < 8; ++i) { v[i] = x[i * 64 + lane]; s += v[i]; }
#pragma unroll
    for (int off = 32; off; off >>= 1) s += __shfl_xor(s, off);
    float mu = s * (1.f / 512.f);
    float vs = 0.f;
#pragma unroll
    for (int i = 0; i < 8; ++i) { float d = v[i] - mu; vs += d * d; }
#pragma unroll
    for (int off = 32; off; off >>= 1) vs += __shfl_xor(vs, off);
    float rstd = rsqrtf(vs * (1.f / 512.f) + 1e-5f);
    float l0 = 0.f, l1 = 0.f;
#pragma unroll
    for (int i = 0; i < 8; ++i) {
        int d = i * 64 + lane;
        float hn = (v[i] - mu) * rstd * g[d] + b[d];
        l0 += hn * w[d * 2];
        l1 += hn * w[d * 2 + 1];
    }
#pragma unroll
    for (int off = 32; off; off >>= 1) { l0 += __shfl_xor(l0, off); l1 += __shfl_xor(l1, off); }
    if (lane == 0) {
        l0 += bias[0]; l1 += bias[1];
        float m = fmaxf(l0, l1);
        float e0 = __expf(l0 - m), e1 = __expf(l1 - m);
        float ss = e0 + e1;
        out[0] = l0; out[1] = l1;
        out[2] = e0 / ss; out[3] = e1 / ss;
        out[4] = (l1 > l0) ? 1.f : 0.f;
    }
}

extern "C" void kernel_launch(void* const* d_in, const int* in_sizes, int n_in,
                              void* d_out, int out_size, void* d_ws, size_t ws_size,
                              hipStream_t stream)
{
    (void)in_sizes; (void)n_in; (void)out_size; (void)ws_size;
    const float* data   = (const float*)d_in[0];
    const float* fc1_w  = (const float*)d_in[1];
    const float* fc1_b  = (const float*)d_in[2];
    const float* cls    = (const float*)d_in[3];
    const float* l1_ng  = (const float*)d_in[4];
    const float* l1_nb  = (const float*)d_in[5];
    const float* l1_qkv = (const float*)d_in[6];
    const float* l1_ow  = (const float*)d_in[7];
    const float* l1_ob  = (const float*)d_in[8];
    const float* l1_rw  = (const float*)d_in[9];
    const float* l2_ng  = (const float*)d_in[10];
    const float* l2_nb  = (const float*)d_in[11];
    const float* l2_qkv = (const float*)d_in[12];
    const float* l2_ow  = (const float*)d_in[13];
    const float* l2_ob  = (const float*)d_in[14];
    const float* l2_rw  = (const float*)d_in[15];
    const float* p_w7   = (const float*)d_in[16];
    const float* p_b7   = (const float*)d_in[17];
    const float* p_w5   = (const float*)d_in[18];
    const float* p_b5   = (const float*)d_in[19];
    const float* p_w3   = (const float*)d_in[20];
    const float* p_b3   = (const float*)d_in[21];
    const float* n_g    = (const float*)d_in[22];
    const float* n_b    = (const float*)d_in[23];
    const float* fc2_w  = (const float*)d_in[24];
    const float* fc2_b  = (const float*)d_in[25];

    char* base = (char*)d_ws;
    auto carve = [&](size_t bytes) { char* p = base; base += (bytes + 255) & ~(size_t)255; return p; };
    float* x               = (float*)carve((size_t)NT * DIMF * 4);
    float* x2              = (float*)carve((size_t)NT * DIMF * 4);
    __hip_bfloat16* xp16   = (__hip_bfloat16*)carve((size_t)NP * DIMF * 2);   // alias: obuf2
    __hip_bfloat16* qkvb16 = (__hip_bfloat16*)carve((size_t)NP * QKVW * 2);   // alias: data16
    __hip_bfloat16* vT16   = (__hip_bfloat16*)carve((size_t)NHEAD * DH * NP * 2);
    float* obuf            = (float*)carve((size_t)NP * DIMF * 4);
    __hip_bfloat16* wT     = (__hip_bfloat16*)carve((size_t)QKVW * DIMF * 2);
    float* ql              = (float*)carve(131072 * 4);
    float* kl              = (float*)carve(131072 * 4);
    __hip_bfloat16* ql16   = (__hip_bfloat16*)carve(131072 * 2);
    __hip_bfloat16* kl16   = (__hip_bfloat16*)carve(131072 * 2);
    __hip_bfloat16* wmT16  = (__hip_bfloat16*)carve(131072 * 2);
    float* a2              = (float*)carve(524288 * 4);
    __hip_bfloat16* a2_16  = (__hip_bfloat16*)carve(524288 * 2);
    __hip_bfloat16* zrA    = (__hip_bfloat16*)carve(524288 * 2);
    __hip_bfloat16* zrB    = (__hip_bfloat16*)carve(524288 * 2);
    __hip_bfloat16* ztA    = (__hip_bfloat16*)carve(524288 * 2);
    __hip_bfloat16* ztB    = (__hip_bfloat16*)carve(524288 * 2);
    __hip_bfloat16* xz16   = (__hip_bfloat16*)carve(524288 * 2);
    __hip_bfloat16* t1T16  = (__hip_bfloat16*)carve(524288 * 2);
    __hip_bfloat16* a3vT16 = (__hip_bfloat16*)carve(131072 * 2);
    float* opart = (float*)carve((size_t)64 * A3V_TC * 2048 * 4);
    float* mpart = (float*)carve((size_t)64 * A3V_TC * 32 * 4);
    float* lpart = (float*)carve((size_t)64 * A3V_TC * 32 * 4);
    __hip_bfloat16* obuf2  = xp16;
    __hip_bfloat16* data16 = qkvb16;

    // ---- stem
    cvt_k<<<(16384 * 1024 / 4 + 255) / 256, 256, 0, stream>>>(
        (const float4*)data, (ushort4*)data16, 16384 * 1024 / 4);
    transcvt_k<<<(DIMF / 32) * (1024 / 32), 256, 0, stream>>>(fc1_w, wT, 1024, DIMF);
    gemm_bf16_k<<<dim3(DIMF / 128, 16384 / 128), 256, 0, stream>>>(
        data16, wT, fc1_b, nullptr, x + DIMF, nullptr, 16384, DIMF, 1024, 16384, 1);
    hipMemcpyAsync(x, cls, DIMF * sizeof(float), hipMemcpyDeviceToDevice, stream);

    auto layer = [&](float* xv, const float* ng, const float* nb, const float* qw,
                     const float* ow, const float* ob, const float* rw) {
        hipMemsetAsync(xp16, 0, (size_t)PADR * DIMF * 2, stream);
        ln_k<<<NT, 64, 0, stream>>>(xv, ng, nb, xp16 + (size_t)PADR * DIMF, NT);
        transcvt_k<<<(QKVW / 32) * (DIMF / 32), 256, 0, stream>>>(qw, wT, DIMF, QKVW);
        gemm_bf16_k<<<dim3(QKVW / 128, NP / 128), 256, 0, stream>>>(
            xp16, wT, nullptr, nullptr, nullptr, qkvb16, NP, QKVW, DIMF, NP, 0);
        vtrans_k<<<dim3(NP / 64, NHEAD), 256, 0, stream>>>(qkvb16, vT16);
        landmark_k<<<NHEAD * NLM, 256, 0, stream>>>(qkvb16, ql, kl, ql16, kl16);
        a2_k<<<NHEAD * NLM, 256, 0, stream>>>(ql, kl, a2, a2_16);
        zinit_k<<<NHEAD, 256, 0, stream>>>(a2, zrA, ztA);
        __hip_bfloat16 *zr = zrA, *zt = ztA, *zrN = zrB, *ztN = ztB;
        for (int it = 0; it < 6; ++it) {
            pgemm1_k<<<dim3(4, NHEAD), 256, 0, stream>>>(a2_16, zt, xz16, t1T16);
            pgemm3_k<<<dim3(4, NHEAD), 256, 0, stream>>>(xz16, t1T16, zr, zrN, ztN);
            __hip_bfloat16* t;
            t = zr; zr = zrN; zrN = t;
            t = zt; zt = ztN; ztN = t;
        }
        a3v_flash_k<<<dim3(32, A3V_TC), 128, 0, stream>>>(ql16, qkvb16, vT16, opart, mpart, lpart);
        a3v_comb_k<<<64, 64, 0, stream>>>(opart, mpart, lpart, a3vT16);
        wm_k<<<NHEAD, 256, 0, stream>>>(zr, a3vT16, wmT16);
        attnout_mfma_k<<<dim3(NP / 64, NHEAD), 128, 0, stream>>>(qkvb16, kl16, wmT16, obuf);
        resconv_tile_k<<<dim3(NP / 128, NHEAD), 256, 0, stream>>>(qkvb16, rw, obuf, obuf2);
        transcvt_k<<<(DIMF / 32) * (DIMF / 32), 256, 0, stream>>>(ow, wT, DIMF, DIMF);
        gemm_bf16_k<<<dim3(DIMF / 128, (NT + 127) / 128), 256, 0, stream>>>(
            obuf2 + (size_t)PADR * DIMF, wT, ob, xv, xv, nullptr, NT, DIMF, DIMF, NT, 0);
    };

    layer(x, l1_ng, l1_nb, l1_qkv, l1_ow, l1_ob, l1_rw);

    ppeg3_k<<<dim3(256, 16), 256, 0, stream>>>(x, p_w7, p_b7, p_w5, p_b5, p_w3, p_b3, x2 + DIMF);
    hipMemcpyAsync(x2, x, DIMF * sizeof(float), hipMemcpyDeviceToDevice, stream);

    layer(x2, l2_ng, l2_nb, l2_qkv, l2_ow, l2_ob, l2_rw);

    head_k<<<1, 64, 0, stream>>>(x2, n_g, n_b, fc2_w, fc2_b, (float*)d_out);
}